// Round 1
// baseline (1166.223 us; speedup 1.0000x reference)
//
#include <hip/hip_runtime.h>
#include <math.h>

// MambaLiteUNet — fp32 full-graph implementation, round 0 (correctness-first).
// B=4, C=256, N=1024, NB=4 mamba blocks (DM=64, DIN=128, DS=16), NH=8 heads (hd=32).

namespace {
constexpr int NB_ = 4, DM_ = 64, DIN_ = 128, DS_ = 16, DTR_ = 4;
constexpr int C_ = 256, N_ = 1024, B_ = 4, HD_ = 32;
}

// ---------- helpers ----------
__device__ __forceinline__ float2 blockReduce2(float a, float b, float* red) {
#pragma unroll
  for (int m = 1; m < 64; m <<= 1) {
    a += __shfl_xor(a, m, 64);
    b += __shfl_xor(b, m, 64);
  }
  int w = threadIdx.x >> 6;
  if ((threadIdx.x & 63) == 0) { red[2 * w] = a; red[2 * w + 1] = b; }
  __syncthreads();
  float ra = red[0] + red[2] + red[4] + red[6];
  float rb = red[1] + red[3] + red[5] + red[7];
  return make_float2(ra, rb);
}

__device__ __forceinline__ float siluf(float x) { return x / (1.f + expf(-x)); }
__device__ __forceinline__ float sigmf(float x) { return 1.f / (1.f + expf(-x)); }
__device__ __forceinline__ float softplusf(float x) {
  return fmaxf(x, 0.f) + log1pf(expf(-fabsf(x)));
}

// ---------- K1/K20a: layernorm over C of a (B,C,N) tensor -> (B,N,C); optional raw copy ----------
__global__ __launch_bounds__(256) void k_ln_t(const float* __restrict__ in,
                                              const float* __restrict__ w,
                                              const float* __restrict__ bias,
                                              float* __restrict__ out_ln,
                                              float* __restrict__ out_copy) {
  __shared__ float red[8];
  int bn = blockIdx.x;            // b*N + n
  int b = bn >> 10, n = bn & 1023;
  int c = threadIdx.x;
  float v = in[(b * C_ + c) * N_ + n];
  if (out_copy) out_copy[(long)bn * C_ + c] = v;
  float2 s = blockReduce2(v, v * v, red);
  float mu = s.x * (1.f / C_);
  float var = s.y * (1.f / C_) - mu * mu;
  float rs = rsqrtf(var + 1e-5f);
  out_ln[(long)bn * C_ + c] = (v - mu) * rs * w[c] + bias[c];
}

// ---------- K2: mamba in-proj  xz = xn_block @ inw^T  -> u, z ----------
__global__ __launch_bounds__(256) void k_inproj(const float* __restrict__ xn,
                                                const float* __restrict__ inw,
                                                float* __restrict__ U, float* __restrict__ Z) {
  __shared__ float xrows[4][64];
  int nb = blockIdx.y;
  int j = threadIdx.x;                       // output col 0..255
  const float* wp = inw + ((long)nb * 2 * DIN_ + j) * DM_;
  float wreg[64];
#pragma unroll
  for (int m = 0; m < 64; ++m) wreg[m] = wp[m];
  int row0 = blockIdx.x * 64;                // over B*N = 4096 rows
  for (int r0 = 0; r0 < 64; r0 += 4) {
    __syncthreads();
    {
      int rr = threadIdx.x >> 6, m = threadIdx.x & 63;
      xrows[rr][m] = xn[(long)(row0 + r0 + rr) * C_ + nb * DM_ + m];
    }
    __syncthreads();
    for (int rr = 0; rr < 4; ++rr) {
      float acc = 0.f;
#pragma unroll
      for (int m = 0; m < 64; ++m) acc += xrows[rr][m] * wreg[m];
      long row = (long)nb * (B_ * N_) + row0 + r0 + rr;
      if (j < DIN_) U[row * DIN_ + j] = acc;
      else          Z[row * DIN_ + (j - DIN_)] = acc;
    }
  }
}

// ---------- K3: causal depthwise conv (K=4) + silu, in-place on U ----------
__global__ __launch_bounds__(256) void k_causal(float* __restrict__ U,
                                                const float* __restrict__ cw,
                                                const float* __restrict__ cb) {
  __shared__ float row[N_];
  int blk = blockIdx.x;                      // nbb*DIN + d,  nbb = nb*B+b
  int d = blk & 127, nbb = blk >> 7, nb = nbb >> 2;
  float* base = U + (long)nbb * N_ * DIN_ + d;
  for (int n = threadIdx.x; n < N_; n += 256) row[n] = base[(long)n * DIN_];
  __syncthreads();
  float w0 = cw[(nb * DIN_ + d) * 4 + 0], w1 = cw[(nb * DIN_ + d) * 4 + 1];
  float w2 = cw[(nb * DIN_ + d) * 4 + 2], w3 = cw[(nb * DIN_ + d) * 4 + 3];
  float bias = cb[nb * DIN_ + d];
  for (int n = threadIdx.x; n < N_; n += 256) {
    float acc = bias + w3 * row[n];
    if (n >= 1) acc += w2 * row[n - 1];
    if (n >= 2) acc += w1 * row[n - 2];
    if (n >= 3) acc += w0 * row[n - 3];
    base[(long)n * DIN_] = siluf(acc);
  }
}

// ---------- K4: xdbc = u @ xpw^T ; dt = softplus(xdbc[:4] @ dtw^T + dtb); Bm, Cm ----------
__global__ __launch_bounds__(128) void k_xdbc(const float* __restrict__ U,
                                              const float* __restrict__ xpw,
                                              const float* __restrict__ dtw,
                                              const float* __restrict__ dtb,
                                              float* __restrict__ DT,
                                              float* __restrict__ BMb, float* __restrict__ CMb) {
  __shared__ float wl[36][129];
  __shared__ float urow[128];
  __shared__ float xd[36];
  int t = threadIdx.x;
  int nb = blockIdx.x >> 9;                  // 2048 blocks, 8 rows each; 4096 rows per nb
  for (int i = t; i < 36 * 128; i += 128) wl[i >> 7][i & 127] = xpw[nb * 36 * 128 + i];
  float dw0 = dtw[(nb * DIN_ + t) * 4 + 0], dw1 = dtw[(nb * DIN_ + t) * 4 + 1];
  float dw2 = dtw[(nb * DIN_ + t) * 4 + 2], dw3 = dtw[(nb * DIN_ + t) * 4 + 3];
  float dtbv = dtb[nb * DIN_ + t];
  for (int r8 = 0; r8 < 8; ++r8) {
    long row = (long)blockIdx.x * 8 + r8;
    __syncthreads();
    urow[t] = U[row * DIN_ + t];
    __syncthreads();
    if (t < 36) {
      float a = 0.f;
#pragma unroll 8
      for (int m = 0; m < 128; ++m) a += urow[m] * wl[t][m];
      xd[t] = a;
    }
    __syncthreads();
    if (t < 16) { BMb[row * DS_ + t] = xd[4 + t]; CMb[row * DS_ + t] = xd[20 + t]; }
    float a = dtbv + xd[0] * dw0 + xd[1] * dw1 + xd[2] * dw2 + xd[3] * dw3;
    DT[row * DIN_ + t] = softplusf(a);
  }
}

// ---------- K5: selective scan; writes y in-place over DT ----------
__global__ __launch_bounds__(256) void k_scan(float* __restrict__ DT,
                                              const float* __restrict__ U,
                                              const float* __restrict__ BMb,
                                              const float* __restrict__ CMb,
                                              const float* __restrict__ alog,
                                              const float* __restrict__ Dp) {
  __shared__ float dt_s[64][16], u_s[64][16], bm_s[64][16], cm_s[64][16];
  int blk = blockIdx.x;                      // nbb*8 + dchunk
  int dch = blk & 7, nbb = blk >> 3, nb = nbb >> 2;
  int t = threadIdx.x;
  int ch = t >> 4, s = t & 15;
  int d = dch * 16 + ch;
  float A = -expf(alog[(nb * DIN_ + d) * DS_ + s]);
  float Dv = Dp[nb * DIN_ + d];
  float h = 0.f;
  long base = (long)nbb * N_;
  for (int c0 = 0; c0 < N_; c0 += 64) {
    for (int i = t; i < 1024; i += 256) {
      int tt = i >> 4, cc = i & 15;
      long r = base + c0 + tt;
      dt_s[tt][cc] = DT[r * DIN_ + dch * 16 + cc];
      u_s[tt][cc]  = U [r * DIN_ + dch * 16 + cc];
      bm_s[tt][cc] = BMb[r * DS_ + cc];
      cm_s[tt][cc] = CMb[r * DS_ + cc];
    }
    __syncthreads();
    for (int tt = 0; tt < 64; ++tt) {
      float dtv = dt_s[tt][ch];
      float uv  = u_s[tt][ch];
      float dA = __expf(dtv * A);
      h = dA * h + dtv * uv * bm_s[tt][s];
      float p = h * cm_s[tt][s];
      p += __shfl_xor(p, 1, 16);
      p += __shfl_xor(p, 2, 16);
      p += __shfl_xor(p, 4, 16);
      p += __shfl_xor(p, 8, 16);
      if (s == 0) DT[(base + c0 + tt) * DIN_ + d] = p + Dv * uv;
    }
    __syncthreads();
  }
}

// ---------- K6: y2 = y*silu(z); xm = y2 @ outw^T + skip*xn -> concat layout (B,N,C) ----------
__global__ __launch_bounds__(256) void k_outproj(const float* __restrict__ Y,
                                                 const float* __restrict__ Z,
                                                 const float* __restrict__ outw,
                                                 const float* __restrict__ xn,
                                                 const float* __restrict__ skip,
                                                 float* __restrict__ XMC) {
  __shared__ float wL[64][129];
  __shared__ float y2r[16][128];
  int row0 = blockIdx.x * 16;                // over NB*B*N = 16384 rows
  int nb = row0 >> 12;
  for (int i = threadIdx.x; i < 64 * 128; i += 256) {
    int col = i >> 7, j = i & 127;
    wL[col][j] = outw[nb * DM_ * DIN_ + i];
  }
  for (int i = threadIdx.x; i < 16 * 128; i += 256) {
    int r = i >> 7, j = i & 127;
    long row = (long)row0 + r;
    float z = Z[row * DIN_ + j];
    y2r[r][j] = Y[row * DIN_ + j] * siluf(z);
  }
  __syncthreads();
  float sk = skip[0];
  int col = threadIdx.x & 63;
  int rbase = threadIdx.x >> 6;
  for (int ii = 0; ii < 4; ++ii) {
    int rr = rbase + ii * 4;
    float acc = 0.f;
#pragma unroll 8
    for (int j = 0; j < 128; ++j) acc += y2r[rr][j] * wL[col][j];
    int bn = (row0 + rr) & 4095;
    long oc = (long)bn * C_ + nb * DM_ + col;
    XMC[oc] = acc + sk * xn[oc];
  }
}

// ---------- K7: gate  g = sigmoid(pw(dw(xm_concat^T))) ----------
__global__ __launch_bounds__(256) void k_gate(const float* __restrict__ XMC,
                                              const float* __restrict__ qdw_w,
                                              const float* __restrict__ qdw_b,
                                              const float* __restrict__ qpw_w,
                                              const float* __restrict__ qpw_b,
                                              float* __restrict__ G) {
  int gid = blockIdx.x * 256 + threadIdx.x;  // b*N + n
  if (gid >= B_ * N_) return;
  int b = gid >> 10, n = gid & 1023;
  float q1[4];
  for (int p = 0; p < 4; ++p) {
    float a = qdw_b[p];
    for (int k = 0; k < 3; ++k) {
      int nn = n + k - 1;
      if (nn < 0 || nn >= N_) continue;
      const float* xr = XMC + ((long)b * N_ + nn) * C_ + p * 64;
      const float* wr = qdw_w + (p * 64) * 3 + k;
      float s = 0.f;
      for (int i = 0; i < 64; ++i) s += xr[i] * wr[i * 3];
      a += s;
    }
    q1[p] = a;
  }
  for (int o = 0; o < 4; ++o) {
    float a = qpw_b[o];
    for (int p = 0; p < 4; ++p) a += qpw_w[o * 4 + p] * q1[p];
    G[((long)b * 4 + o) * N_ + n] = sigmf(a);
  }
}

// ---------- K8: xg (B,C,N) = g * xm ----------
__global__ __launch_bounds__(256) void k_xg(const float* __restrict__ XMC,
                                            const float* __restrict__ G,
                                            float* __restrict__ XG) {
  long i = (long)blockIdx.x * 256 + threadIdx.x;  // B*C*N
  int n = i & 1023;
  long bc = i >> 10;
  int c = bc & 255, b = (int)(bc >> 8);
  float g = G[((long)b * 4 + (c >> 6)) * N_ + n];
  XG[i] = g * XMC[((long)b * N_ + n) * C_ + c];
}

// ---------- generic 3-tap depthwise conv over n, (B,nchan,N) layout ----------
__global__ __launch_bounds__(256) void k_dw3(const float* __restrict__ in,
                                             const float* __restrict__ w,
                                             const float* __restrict__ bias,
                                             float* __restrict__ out, int nchan) {
  long i = (long)blockIdx.x * 256 + threadIdx.x;
  if (i >= (long)B_ * nchan * N_) return;
  int n = i & 1023;
  int c = (int)((i >> 10) % nchan);
  const float* r = in + (i - n);
  float a = bias[c] + w[c * 3 + 1] * r[n];
  if (n > 0)      a += w[c * 3 + 0] * r[n - 1];
  if (n < N_ - 1) a += w[c * 3 + 2] * r[n + 1];
  out[i] = a;
}

// ---------- K9b: pointwise conv (GEMM) (B,CIN,N)->(B,256,N) with (B,C,N) residual ----------
template <int CIN, int NT>
__global__ __launch_bounds__(256) void k_pw(const float* __restrict__ in,
                                            const float* __restrict__ w,
                                            const float* __restrict__ bias,
                                            const float* __restrict__ resid,
                                            float* __restrict__ out) {
  __shared__ float tile[CIN][NT + 1];
  int nt = N_ / NT;
  int b = blockIdx.x / nt, n0 = (blockIdx.x % nt) * NT;
  for (int r = threadIdx.x; r < CIN; r += 256)
    for (int j = 0; j < NT; ++j)
      tile[r][j] = in[((long)b * CIN + r) * N_ + n0 + j];
  __syncthreads();
  int c = threadIdx.x;
  float acc[NT];
#pragma unroll
  for (int j = 0; j < NT; ++j) acc[j] = 0.f;
  const float* wr = w + (long)c * CIN;
  for (int r = 0; r < CIN; ++r) {
    float wv = wr[r];
#pragma unroll
    for (int j = 0; j < NT; ++j) acc[j] += wv * tile[r][j];
  }
  float bv = bias[c];
  for (int j = 0; j < NT; ++j) {
    long o = ((long)b * C_ + c) * N_ + n0 + j;
    float v = acc[j] + bv;
    if (resid) v += resid[o];
    out[o] = v;
  }
}

// ---------- K10: depthwise conv over virtual cat = [xs^T ; R] (B,512,N) ----------
__global__ __launch_bounds__(256) void k_fdw(const float* __restrict__ XS,
                                             const float* __restrict__ RB,
                                             const float* __restrict__ w,
                                             const float* __restrict__ bias,
                                             float* __restrict__ YDW) {
  long i = (long)blockIdx.x * 256 + threadIdx.x;  // B*512*N
  int n = i & 1023;
  long bc = i >> 10;
  int cc = bc & 511, b = (int)(bc >> 9);
  float v0 = 0.f, v1, v2 = 0.f;
  if (cc < C_) {
    const float* p = XS + (long)b * N_ * C_ + cc;
    v1 = p[(long)n * C_];
    if (n > 0)      v0 = p[(long)(n - 1) * C_];
    if (n < N_ - 1) v2 = p[(long)(n + 1) * C_];
  } else {
    const float* p = RB + ((long)b * C_ + (cc - C_)) * N_;
    v1 = p[n];
    if (n > 0)      v0 = p[n - 1];
    if (n < N_ - 1) v2 = p[n + 1];
  }
  YDW[i] = bias[cc] + w[cc * 3] * v0 + w[cc * 3 + 1] * v1 + w[cc * 3 + 2] * v2;
}

// ---------- K11: fpw pointwise (B,512,N)->(B,N,C) + xs residual ----------
__global__ __launch_bounds__(256) void k_fpw(const float* __restrict__ YDW,
                                             const float* __restrict__ w,
                                             const float* __restrict__ bias,
                                             const float* __restrict__ XS,
                                             float* __restrict__ XM2) {
  __shared__ float tile[512][17];
  int nt = N_ / 16;
  int b = blockIdx.x / nt, n0 = (blockIdx.x % nt) * 16;
  for (int i = threadIdx.x; i < 512 * 16; i += 256) {
    int r = i >> 4, j = i & 15;
    tile[r][j] = YDW[((long)b * 512 + r) * N_ + n0 + j];
  }
  __syncthreads();
  int c = threadIdx.x;
  float acc[16];
#pragma unroll
  for (int j = 0; j < 16; ++j) acc[j] = 0.f;
  const float* wr = w + (long)c * 512;
  for (int r = 0; r < 512; ++r) {
    float wv = wr[r];
#pragma unroll
    for (int j = 0; j < 16; ++j) acc[j] += wv * tile[r][j];
  }
  float bv = bias[c];
  for (int j = 0; j < 16; ++j) {
    long o = ((long)b * N_ + n0 + j) * C_ + c;
    XM2[o] = acc[j] + bv + XS[o];
  }
}

// ---------- K12: x_local depthwise over n in (B,N,C) layout ----------
__global__ __launch_bounds__(256) void k_lc(const float* __restrict__ XM2,
                                            const float* __restrict__ w,
                                            const float* __restrict__ bias,
                                            float* __restrict__ XL) {
  long i = (long)blockIdx.x * 256 + threadIdx.x;  // B*N*C, c fastest
  int c = i & 255;
  long bn = i >> 8;
  int n = bn & 1023, b = (int)(bn >> 10);
  const float* p = XM2 + (long)b * N_ * C_ + c;
  float a = bias[c] + w[c * 3 + 1] * p[(long)n * C_];
  if (n > 0)      a += w[c * 3 + 0] * p[(long)(n - 1) * C_];
  if (n < N_ - 1) a += w[c * 3 + 2] * p[(long)(n + 1) * C_];
  XL[i] = a;
}

// ---------- row GEMM: out[r, c] = in[r,:KD] . W[c,:KD] + bias  (rows = B*N) ----------
template <int KD, int NCOL>
__global__ __launch_bounds__(256) void k_rowgemm(const float* __restrict__ in,
                                                 const float* __restrict__ w,
                                                 const float* __restrict__ bias,
                                                 float* __restrict__ out, int Cout) {
  __shared__ float tile[16][KD + 1];
  long r0 = (long)blockIdx.x * 16;
  for (int i = threadIdx.x; i < 16 * KD; i += 256) {
    int r = i / KD, k = i % KD;
    tile[r][k] = in[(r0 + r) * KD + k];
  }
  __syncthreads();
  int t = threadIdx.x;
  float acc[NCOL][16];
#pragma unroll
  for (int q = 0; q < NCOL; ++q)
#pragma unroll
    for (int r = 0; r < 16; ++r) acc[q][r] = 0.f;
  for (int k = 0; k < KD; ++k) {
    float xv[16];
#pragma unroll
    for (int r = 0; r < 16; ++r) xv[r] = tile[r][k];
#pragma unroll
    for (int q = 0; q < NCOL; ++q) {
      float wv = w[(long)(t + 256 * q) * KD + k];
#pragma unroll
      for (int r = 0; r < 16; ++r) acc[q][r] += wv * xv[r];
    }
  }
  for (int q = 0; q < NCOL; ++q) {
    int c = t + 256 * q;
    float bv = bias[c];
    for (int r = 0; r < 16; ++r) out[(r0 + r) * Cout + c] = acc[q][r] + bv;
  }
}

// ---------- K16: fc over concat[XL, XGL] ----------
__global__ __launch_bounds__(256) void k_fc(const float* __restrict__ XL,
                                            const float* __restrict__ XGL,
                                            const float* __restrict__ w,
                                            const float* __restrict__ bias,
                                            float* __restrict__ out) {
  __shared__ float tile[16][513];
  long r0 = (long)blockIdx.x * 16;
  for (int i = threadIdx.x; i < 16 * 256; i += 256) {
    int r = i >> 8, k = i & 255;
    tile[r][k] = XL[(r0 + r) * C_ + k];
    tile[r][256 + k] = XGL[(r0 + r) * C_ + k];
  }
  __syncthreads();
  int t = threadIdx.x;
  float acc[16];
#pragma unroll
  for (int r = 0; r < 16; ++r) acc[r] = 0.f;
  const float* wr = w + (long)t * 512;
  for (int k = 0; k < 512; ++k) {
    float wv = wr[k];
#pragma unroll
    for (int r = 0; r < 16; ++r) acc[r] += wv * tile[r][k];
  }
  float bv = bias[t];
  for (int r = 0; r < 16; ++r) out[(r0 + r) * C_ + t] = acc[r] + bv;
}

// ---------- K14: flash attention, 1 thread per query row ----------
__global__ __launch_bounds__(256) void k_attn(const float* __restrict__ qkv,
                                              float* __restrict__ O) {
  __shared__ float ks[64][32];
  __shared__ float vs[64][32];
  int bh = blockIdx.x >> 2;
  int rt = blockIdx.x & 3;
  int b = bh >> 3, h = bh & 7;
  int row = rt * 256 + threadIdx.x;
  const float scale = 0.17677669529663687f;  // 1/sqrt(32)
  float q[32];
  const float* qp = qkv + ((long)b * N_ + row) * 768 + h * HD_;
#pragma unroll
  for (int j = 0; j < 32; ++j) q[j] = qp[j] * scale;
  float m = -1e30f, l = 0.f;
  float acc[32];
#pragma unroll
  for (int j = 0; j < 32; ++j) acc[j] = 0.f;
  for (int k0 = 0; k0 < N_; k0 += 64) {
    __syncthreads();
    for (int i = threadIdx.x; i < 64 * 32; i += 256) {
      int kk = i >> 5, j = i & 31;
      const float* kp = qkv + ((long)b * N_ + k0 + kk) * 768 + C_ + h * HD_ + j;
      ks[kk][j] = kp[0];
      vs[kk][j] = kp[256];
    }
    __syncthreads();
    for (int kk = 0; kk < 64; ++kk) {
      float s = 0.f;
#pragma unroll
      for (int j = 0; j < 32; ++j) s += q[j] * ks[kk][j];
      float mn = fmaxf(m, s);
      float corr = __expf(m - mn);
      float p = __expf(s - mn);
      l = l * corr + p;
#pragma unroll
      for (int j = 0; j < 32; ++j) acc[j] = acc[j] * corr + p * vs[kk][j];
      m = mn;
    }
  }
  float inv = 1.f / l;
  float* op = O + ((long)b * N_ + row) * C_ + h * HD_;
#pragma unroll
  for (int j = 0; j < 32; ++j) op[j] = acc[j] * inv;
}

// ---------- K17: LN(lgn) + exact GELU -> (B,C,N) layout ----------
__global__ __launch_bounds__(256) void k_lngelu(const float* __restrict__ XO,
                                                const float* __restrict__ lw,
                                                const float* __restrict__ lb,
                                                float* __restrict__ XI) {
  __shared__ float red[8];
  int bn = blockIdx.x;
  int b = bn >> 10, n = bn & 1023;
  int c = threadIdx.x;
  float v = XO[(long)bn * C_ + c];
  float2 s = blockReduce2(v, v * v, red);
  float mu = s.x * (1.f / C_);
  float rs = rsqrtf(s.y * (1.f / C_) - mu * mu + 1e-5f);
  float x = (v - mu) * rs * lw[c] + lb[c];
  float ge = 0.5f * x * (1.f + erff(x * 0.70710678118654752f));
  XI[((long)b * C_ + c) * N_ + n] = ge;
}

// ---------- K18: ln over (H,W) per (b,c), in place, no affine ----------
__global__ __launch_bounds__(256) void k_lnhw(float* __restrict__ XI) {
  __shared__ float red[8];
  long base = (long)blockIdx.x * N_;  // b*C + c
  float a = 0.f, b2 = 0.f;
  for (int i = threadIdx.x; i < N_; i += 256) {
    float v = XI[base + i];
    a += v; b2 += v * v;
  }
  float2 s = blockReduce2(a, b2, red);
  float mu = s.x * (1.f / N_);
  float rs = rsqrtf(s.y * (1.f / N_) - mu * mu + 1e-5f);
  for (int i = threadIdx.x; i < N_; i += 256) XI[base + i] = (XI[base + i] - mu) * rs;
}

// ---------- K19: depthwise 3x3 conv on (B,C,32,32), pad 1 ----------
__global__ __launch_bounds__(256) void k_dwc(const float* __restrict__ XI,
                                             const float* __restrict__ w,
                                             const float* __restrict__ bias,
                                             float* __restrict__ XD) {
  long i = (long)blockIdx.x * 256 + threadIdx.x;  // B*C*1024
  int hw = i & 1023;
  int wq = hw & 31, hq = hw >> 5;
  int c = (int)((i >> 10) & 255);
  const float* p = XI + (i - hw);
  const float* wk = w + c * 9;
  float a = bias[c];
#pragma unroll
  for (int kh = 0; kh < 3; ++kh) {
    int h2 = hq + kh - 1;
    if (h2 < 0 || h2 >= 32) continue;
#pragma unroll
    for (int kw = 0; kw < 3; ++kw) {
      int w2 = wq + kw - 1;
      if (w2 < 0 || w2 >= 32) continue;
      a += wk[kh * 3 + kw] * p[h2 * 32 + w2];
    }
  }
  XD[i] = a;
}

// ---------- K20b: final proj with transposed write (B,N,C)->(B,COUT,N) ----------
__global__ __launch_bounds__(256) void k_rowgemm_t(const float* __restrict__ in,
                                                   const float* __restrict__ w,
                                                   const float* __restrict__ bias,
                                                   float* __restrict__ out) {
  __shared__ float tile[16][257];
  long r0 = (long)blockIdx.x * 16;
  for (int i = threadIdx.x; i < 16 * 256; i += 256) {
    int r = i >> 8, k = i & 255;
    tile[r][k] = in[(r0 + r) * C_ + k];
  }
  __syncthreads();
  int t = threadIdx.x;
  float acc[16];
#pragma unroll
  for (int r = 0; r < 16; ++r) acc[r] = 0.f;
  const float* wr = w + (long)t * C_;
  for (int k = 0; k < C_; ++k) {
    float wv = wr[k];
#pragma unroll
    for (int r = 0; r < 16; ++r) acc[r] += wv * tile[r][k];
  }
  float bv = bias[t];
  for (int r = 0; r < 16; ++r) {
    long row = r0 + r;          // b*N + n
    int b = (int)(row >> 10), n = (int)(row & 1023);
    out[((long)b * C_ + t) * N_ + n] = acc[r] + bv;
  }
}

extern "C" void kernel_launch(void* const* d_in, const int* in_sizes, int n_in,
                              void* d_out, int out_size, void* d_ws, size_t ws_size,
                              hipStream_t stream) {
  const float* x        = (const float*)d_in[0];
  const float* norm_w   = (const float*)d_in[1];
  const float* norm_b   = (const float*)d_in[2];
  const float* skip     = (const float*)d_in[3];
  const float* m_inw    = (const float*)d_in[4];
  const float* m_convw  = (const float*)d_in[5];
  const float* m_convb  = (const float*)d_in[6];
  const float* m_xpw    = (const float*)d_in[7];
  const float* m_dtw    = (const float*)d_in[8];
  const float* m_dtb    = (const float*)d_in[9];
  const float* m_alog   = (const float*)d_in[10];
  const float* m_d      = (const float*)d_in[11];
  const float* m_outw   = (const float*)d_in[12];
  const float* qdw_w    = (const float*)d_in[13];
  const float* qdw_b    = (const float*)d_in[14];
  const float* qpw_w    = (const float*)d_in[15];
  const float* qpw_b    = (const float*)d_in[16];
  const float* rdw_w    = (const float*)d_in[17];
  const float* rdw_b    = (const float*)d_in[18];
  const float* rpw_w    = (const float*)d_in[19];
  const float* rpw_b    = (const float*)d_in[20];
  const float* fdw_w    = (const float*)d_in[21];
  const float* fdw_b    = (const float*)d_in[22];
  const float* fpw_w    = (const float*)d_in[23];
  const float* fpw_b    = (const float*)d_in[24];
  const float* lc_w     = (const float*)d_in[25];
  const float* lc_b     = (const float*)d_in[26];
  const float* attn_inw = (const float*)d_in[27];
  const float* attn_inb = (const float*)d_in[28];
  const float* attn_outw= (const float*)d_in[29];
  const float* attn_outb= (const float*)d_in[30];
  const float* lgn_w    = (const float*)d_in[31];
  const float* lgn_b    = (const float*)d_in[32];
  const float* fc_w     = (const float*)d_in[33];
  const float* fc_b     = (const float*)d_in[34];
  const float* dwc_w    = (const float*)d_in[35];
  const float* dwc_b    = (const float*)d_in[36];
  const float* proj_w   = (const float*)d_in[37];
  const float* proj_b   = (const float*)d_in[38];
  float* out = (float*)d_out;

  float* ws = (float*)d_ws;
  const size_t F = 1048576;  // B*N*C
  // phase 1
  float* XS  = ws + 0 * F;       // (B,N,C) raw transposed input
  float* XN  = ws + 1 * F;       // (B,N,C) layernormed
  float* U   = ws + 2 * F;       // (NB,B,N,DIN)
  float* Z   = ws + 4 * F;       // (NB,B,N,DIN)
  float* DT  = ws + 6 * F;       // (NB,B,N,DIN); scan writes y here in place
  float* BM  = ws + 8 * F;       // (NB,B,N,DS)
  float* CM  = ws + 8 * F + F / 4;
  float* XMC = ws + 8 * F + F / 2;  // (B,N,C) mamba out + skip
  // phase 2 (reuse)
  float* G   = ws + 1 * F;       // (B,4,N)
  float* XG  = ws + 2 * F;       // (B,C,N)
  float* RD  = ws + 3 * F;       // (B,C,N) depthwise temp
  float* RB  = ws + 4 * F;       // (B,C,N) R
  float* XM2 = ws + 5 * F;       // (B,N,C)
  float* YDW = ws + 6 * F;       // (B,512,N)
  // phase 3 (reuse)
  float* XL  = ws + 0 * F;       // (B,N,C) x_local
  float* QKV = ws + 1 * F;       // (B,N,768)
  float* O   = ws + 4 * F;       // (B,N,C) attention out
  float* XGL = ws + 6 * F;       // (B,N,C) x_global
  float* XO  = ws + 7 * F;       // (B,N,C) post-fc
  float* XI  = ws + 8 * F;       // (B,C,N) post-gelu / ln_hw (in place)
  float* XD  = ws + 5 * F;       // (B,C,N) post dwc  (XM2 dead by then)
  float* LNF = ws + 0 * F;       // (B,N,C) final LN   (XL dead by then)
  (void)ws_size; (void)in_sizes; (void)n_in; (void)out_size;

  // K1: transpose + layernorm
  k_ln_t<<<4096, 256, 0, stream>>>(x, norm_w, norm_b, XN, XS);
  // K2: mamba in-proj
  k_inproj<<<dim3(64, 4), 256, 0, stream>>>(XN, m_inw, U, Z);
  // K3: causal conv + silu
  k_causal<<<2048, 256, 0, stream>>>(U, m_convw, m_convb);
  // K4: xdbc / dt / Bm / Cm
  k_xdbc<<<2048, 128, 0, stream>>>(U, m_xpw, m_dtw, m_dtb, DT, BM, CM);
  // K5: selective scan (y over DT)
  k_scan<<<128, 256, 0, stream>>>(DT, U, BM, CM, m_alog, m_d);
  // K6: out-proj + skip
  k_outproj<<<1024, 256, 0, stream>>>(DT, Z, m_outw, XN, skip, XMC);
  // K7: gate
  k_gate<<<16, 256, 0, stream>>>(XMC, qdw_w, qdw_b, qpw_w, qpw_b, G);
  // K8: xg
  k_xg<<<4096, 256, 0, stream>>>(XMC, G, XG);
  // K9: R = pw(dw(xg)) + xg
  k_dw3<<<4096, 256, 0, stream>>>(XG, rdw_w, rdw_b, RD, 256);
  k_pw<256, 32><<<128, 256, 0, stream>>>(RD, rpw_w, rpw_b, XG, RB);
  // K10/K11: xm2 = pw(dw(cat)) + xs
  k_fdw<<<8192, 256, 0, stream>>>(XS, RB, fdw_w, fdw_b, YDW);
  k_fpw<<<256, 256, 0, stream>>>(YDW, fpw_w, fpw_b, XS, XM2);
  // K12: x_local
  k_lc<<<4096, 256, 0, stream>>>(XM2, lc_w, lc_b, XL);
  // K13: qkv
  k_rowgemm<256, 3><<<256, 256, 0, stream>>>(XM2, attn_inw, attn_inb, QKV, 768);
  // K14: attention
  k_attn<<<128, 256, 0, stream>>>(QKV, O);
  // K15: attention out-proj
  k_rowgemm<256, 1><<<256, 256, 0, stream>>>(O, attn_outw, attn_outb, XGL, 256);
  // K16: fc over concat
  k_fc<<<256, 256, 0, stream>>>(XL, XGL, fc_w, fc_b, XO);
  // K17: LN + GELU -> (B,C,N)
  k_lngelu<<<4096, 256, 0, stream>>>(XO, lgn_w, lgn_b, XI);
  // K18: ln over H,W
  k_lnhw<<<1024, 256, 0, stream>>>(XI);
  // K19: depthwise 3x3
  k_dwc<<<4096, 256, 0, stream>>>(XI, dwc_w, dwc_b, XD);
  // K20: final LN + projection
  k_ln_t<<<4096, 256, 0, stream>>>(XD, norm_w, norm_b, LNF, nullptr);
  k_rowgemm_t<<<256, 256, 0, stream>>>(LNF, proj_w, proj_b, out);
}

// Round 2
// 776.373 us; speedup vs baseline: 1.5021x; 1.5021x over previous
//
#include <hip/hip_runtime.h>
#include <math.h>

// MambaLiteUNet — fp32, round 1: occupancy-fixed attention (key-split flash) +
// doubled grids on small-grid GEMM kernels + parallel gate.

namespace {
constexpr int NB_ = 4, DM_ = 64, DIN_ = 128, DS_ = 16, DTR_ = 4;
constexpr int C_ = 256, N_ = 1024, B_ = 4, HD_ = 32;
}

// ---------- helpers ----------
__device__ __forceinline__ float2 blockReduce2(float a, float b, float* red) {
#pragma unroll
  for (int m = 1; m < 64; m <<= 1) {
    a += __shfl_xor(a, m, 64);
    b += __shfl_xor(b, m, 64);
  }
  int w = threadIdx.x >> 6;
  if ((threadIdx.x & 63) == 0) { red[2 * w] = a; red[2 * w + 1] = b; }
  __syncthreads();
  float ra = red[0] + red[2] + red[4] + red[6];
  float rb = red[1] + red[3] + red[5] + red[7];
  return make_float2(ra, rb);
}

__device__ __forceinline__ float siluf(float x) { return x / (1.f + expf(-x)); }
__device__ __forceinline__ float sigmf(float x) { return 1.f / (1.f + expf(-x)); }
__device__ __forceinline__ float softplusf(float x) {
  return fmaxf(x, 0.f) + log1pf(expf(-fabsf(x)));
}

// ---------- K1/K20a: layernorm over C of a (B,C,N) tensor -> (B,N,C); optional raw copy ----------
__global__ __launch_bounds__(256) void k_ln_t(const float* __restrict__ in,
                                              const float* __restrict__ w,
                                              const float* __restrict__ bias,
                                              float* __restrict__ out_ln,
                                              float* __restrict__ out_copy) {
  __shared__ float red[8];
  int bn = blockIdx.x;            // b*N + n
  int b = bn >> 10, n = bn & 1023;
  int c = threadIdx.x;
  float v = in[(b * C_ + c) * N_ + n];
  if (out_copy) out_copy[(long)bn * C_ + c] = v;
  float2 s = blockReduce2(v, v * v, red);
  float mu = s.x * (1.f / C_);
  float var = s.y * (1.f / C_) - mu * mu;
  float rs = rsqrtf(var + 1e-5f);
  out_ln[(long)bn * C_ + c] = (v - mu) * rs * w[c] + bias[c];
}

// ---------- K2: mamba in-proj  xz = xn_block @ inw^T  -> u, z ----------
__global__ __launch_bounds__(256) void k_inproj(const float* __restrict__ xn,
                                                const float* __restrict__ inw,
                                                float* __restrict__ U, float* __restrict__ Z) {
  __shared__ float xrows[4][64];
  int nb = blockIdx.y;
  int j = threadIdx.x;                       // output col 0..255
  const float* wp = inw + ((long)nb * 2 * DIN_ + j) * DM_;
  float wreg[64];
#pragma unroll
  for (int m = 0; m < 64; ++m) wreg[m] = wp[m];
  int row0 = blockIdx.x * 64;                // over B*N = 4096 rows
  for (int r0 = 0; r0 < 64; r0 += 4) {
    __syncthreads();
    {
      int rr = threadIdx.x >> 6, m = threadIdx.x & 63;
      xrows[rr][m] = xn[(long)(row0 + r0 + rr) * C_ + nb * DM_ + m];
    }
    __syncthreads();
    for (int rr = 0; rr < 4; ++rr) {
      float acc = 0.f;
#pragma unroll
      for (int m = 0; m < 64; ++m) acc += xrows[rr][m] * wreg[m];
      long row = (long)nb * (B_ * N_) + row0 + r0 + rr;
      if (j < DIN_) U[row * DIN_ + j] = acc;
      else          Z[row * DIN_ + (j - DIN_)] = acc;
    }
  }
}

// ---------- K3: causal depthwise conv (K=4) + silu, in-place on U ----------
__global__ __launch_bounds__(256) void k_causal(float* __restrict__ U,
                                                const float* __restrict__ cw,
                                                const float* __restrict__ cb) {
  __shared__ float row[N_];
  int blk = blockIdx.x;                      // nbb*DIN + d,  nbb = nb*B+b
  int d = blk & 127, nbb = blk >> 7, nb = nbb >> 2;
  float* base = U + (long)nbb * N_ * DIN_ + d;
  for (int n = threadIdx.x; n < N_; n += 256) row[n] = base[(long)n * DIN_];
  __syncthreads();
  float w0 = cw[(nb * DIN_ + d) * 4 + 0], w1 = cw[(nb * DIN_ + d) * 4 + 1];
  float w2 = cw[(nb * DIN_ + d) * 4 + 2], w3 = cw[(nb * DIN_ + d) * 4 + 3];
  float bias = cb[nb * DIN_ + d];
  for (int n = threadIdx.x; n < N_; n += 256) {
    float acc = bias + w3 * row[n];
    if (n >= 1) acc += w2 * row[n - 1];
    if (n >= 2) acc += w1 * row[n - 2];
    if (n >= 3) acc += w0 * row[n - 3];
    base[(long)n * DIN_] = siluf(acc);
  }
}

// ---------- K4: xdbc = u @ xpw^T ; dt = softplus(xdbc[:4] @ dtw^T + dtb); Bm, Cm ----------
__global__ __launch_bounds__(128) void k_xdbc(const float* __restrict__ U,
                                              const float* __restrict__ xpw,
                                              const float* __restrict__ dtw,
                                              const float* __restrict__ dtb,
                                              float* __restrict__ DT,
                                              float* __restrict__ BMb, float* __restrict__ CMb) {
  __shared__ float wl[36][129];
  __shared__ float urow[128];
  __shared__ float xd[36];
  int t = threadIdx.x;
  int nb = blockIdx.x >> 9;                  // 2048 blocks, 8 rows each; 4096 rows per nb
  for (int i = t; i < 36 * 128; i += 128) wl[i >> 7][i & 127] = xpw[nb * 36 * 128 + i];
  float dw0 = dtw[(nb * DIN_ + t) * 4 + 0], dw1 = dtw[(nb * DIN_ + t) * 4 + 1];
  float dw2 = dtw[(nb * DIN_ + t) * 4 + 2], dw3 = dtw[(nb * DIN_ + t) * 4 + 3];
  float dtbv = dtb[nb * DIN_ + t];
  for (int r8 = 0; r8 < 8; ++r8) {
    long row = (long)blockIdx.x * 8 + r8;
    __syncthreads();
    urow[t] = U[row * DIN_ + t];
    __syncthreads();
    if (t < 36) {
      float a = 0.f;
#pragma unroll 8
      for (int m = 0; m < 128; ++m) a += urow[m] * wl[t][m];
      xd[t] = a;
    }
    __syncthreads();
    if (t < 16) { BMb[row * DS_ + t] = xd[4 + t]; CMb[row * DS_ + t] = xd[20 + t]; }
    float a = dtbv + xd[0] * dw0 + xd[1] * dw1 + xd[2] * dw2 + xd[3] * dw3;
    DT[row * DIN_ + t] = softplusf(a);
  }
}

// ---------- K5: selective scan; writes y in-place over DT ----------
__global__ __launch_bounds__(256) void k_scan(float* __restrict__ DT,
                                              const float* __restrict__ U,
                                              const float* __restrict__ BMb,
                                              const float* __restrict__ CMb,
                                              const float* __restrict__ alog,
                                              const float* __restrict__ Dp) {
  __shared__ float dt_s[64][16], u_s[64][16], bm_s[64][16], cm_s[64][16];
  int blk = blockIdx.x;                      // nbb*8 + dchunk
  int dch = blk & 7, nbb = blk >> 3, nb = nbb >> 2;
  int t = threadIdx.x;
  int ch = t >> 4, s = t & 15;
  int d = dch * 16 + ch;
  float A = -expf(alog[(nb * DIN_ + d) * DS_ + s]);
  float Dv = Dp[nb * DIN_ + d];
  float h = 0.f;
  long base = (long)nbb * N_;
  for (int c0 = 0; c0 < N_; c0 += 64) {
    for (int i = t; i < 1024; i += 256) {
      int tt = i >> 4, cc = i & 15;
      long r = base + c0 + tt;
      dt_s[tt][cc] = DT[r * DIN_ + dch * 16 + cc];
      u_s[tt][cc]  = U [r * DIN_ + dch * 16 + cc];
      bm_s[tt][cc] = BMb[r * DS_ + cc];
      cm_s[tt][cc] = CMb[r * DS_ + cc];
    }
    __syncthreads();
    for (int tt = 0; tt < 64; ++tt) {
      float dtv = dt_s[tt][ch];
      float uv  = u_s[tt][ch];
      float dA = __expf(dtv * A);
      h = dA * h + dtv * uv * bm_s[tt][s];
      float p = h * cm_s[tt][s];
      p += __shfl_xor(p, 1, 16);
      p += __shfl_xor(p, 2, 16);
      p += __shfl_xor(p, 4, 16);
      p += __shfl_xor(p, 8, 16);
      if (s == 0) DT[(base + c0 + tt) * DIN_ + d] = p + Dv * uv;
    }
    __syncthreads();
  }
}

// ---------- K6: y2 = y*silu(z); xm = y2 @ outw^T + skip*xn -> concat layout (B,N,C) ----------
__global__ __launch_bounds__(256) void k_outproj(const float* __restrict__ Y,
                                                 const float* __restrict__ Z,
                                                 const float* __restrict__ outw,
                                                 const float* __restrict__ xn,
                                                 const float* __restrict__ skip,
                                                 float* __restrict__ XMC) {
  __shared__ float wL[64][129];
  __shared__ float y2r[16][128];
  int row0 = blockIdx.x * 16;                // over NB*B*N = 16384 rows
  int nb = row0 >> 12;
  for (int i = threadIdx.x; i < 64 * 128; i += 256) {
    int col = i >> 7, j = i & 127;
    wL[col][j] = outw[nb * DM_ * DIN_ + i];
  }
  for (int i = threadIdx.x; i < 16 * 128; i += 256) {
    int r = i >> 7, j = i & 127;
    long row = (long)row0 + r;
    float z = Z[row * DIN_ + j];
    y2r[r][j] = Y[row * DIN_ + j] * siluf(z);
  }
  __syncthreads();
  float sk = skip[0];
  int col = threadIdx.x & 63;
  int rbase = threadIdx.x >> 6;
  for (int ii = 0; ii < 4; ++ii) {
    int rr = rbase + ii * 4;
    float acc = 0.f;
#pragma unroll 8
    for (int j = 0; j < 128; ++j) acc += y2r[rr][j] * wL[col][j];
    int bn = (row0 + rr) & 4095;
    long oc = (long)bn * C_ + nb * DM_ + col;
    XMC[oc] = acc + sk * xn[oc];
  }
}

// ---------- K7: gate  g = sigmoid(pw(dw(xm_concat^T))), parallel version ----------
// thread layout: 16 threads per position: cq = t&3 (16-chan quarter), p = (t>>2)&3
__global__ __launch_bounds__(256) void k_gate(const float* __restrict__ XMC,
                                              const float* __restrict__ qdw_w,
                                              const float* __restrict__ qdw_b,
                                              const float* __restrict__ qpw_w,
                                              const float* __restrict__ qpw_b,
                                              float* __restrict__ G) {
  int t = threadIdx.x;
  int gid = (blockIdx.x * 256 + t) >> 4;     // b*N + n
  int cq = t & 3, p = (t >> 2) & 3;
  int b = gid >> 10, n = gid & 1023;
  float a = 0.f;
#pragma unroll
  for (int k = 0; k < 3; ++k) {
    int nn = n + k - 1;
    if (nn < 0 || nn >= N_) continue;
    const float* xr = XMC + ((long)b * N_ + nn) * C_ + p * 64 + cq * 16;
    const float* wr = qdw_w + (p * 64 + cq * 16) * 3 + k;
#pragma unroll
    for (int i = 0; i < 16; ++i) a += xr[i] * wr[i * 3];
  }
  a += __shfl_xor(a, 1, 64);
  a += __shfl_xor(a, 2, 64);
  float q1 = a + qdw_b[p];                   // all cq lanes hold q1(gid, p)
  int lane = t & 63;
  float q1g[4];
#pragma unroll
  for (int pp = 0; pp < 4; ++pp) q1g[pp] = __shfl(q1, (lane & ~12) | (pp << 2), 64);
  int o = p;
  float r = qpw_b[o];
#pragma unroll
  for (int pp = 0; pp < 4; ++pp) r += qpw_w[o * 4 + pp] * q1g[pp];
  if (cq == 0) G[((long)b * 4 + o) * N_ + n] = sigmf(r);
}

// ---------- K8: xg (B,C,N) = g * xm ----------
__global__ __launch_bounds__(256) void k_xg(const float* __restrict__ XMC,
                                            const float* __restrict__ G,
                                            float* __restrict__ XG) {
  long i = (long)blockIdx.x * 256 + threadIdx.x;  // B*C*N
  int n = i & 1023;
  long bc = i >> 10;
  int c = bc & 255, b = (int)(bc >> 8);
  float g = G[((long)b * 4 + (c >> 6)) * N_ + n];
  XG[i] = g * XMC[((long)b * N_ + n) * C_ + c];
}

// ---------- generic 3-tap depthwise conv over n, (B,nchan,N) layout ----------
__global__ __launch_bounds__(256) void k_dw3(const float* __restrict__ in,
                                             const float* __restrict__ w,
                                             const float* __restrict__ bias,
                                             float* __restrict__ out, int nchan) {
  long i = (long)blockIdx.x * 256 + threadIdx.x;
  if (i >= (long)B_ * nchan * N_) return;
  int n = i & 1023;
  int c = (int)((i >> 10) % nchan);
  const float* r = in + (i - n);
  float a = bias[c] + w[c * 3 + 1] * r[n];
  if (n > 0)      a += w[c * 3 + 0] * r[n - 1];
  if (n < N_ - 1) a += w[c * 3 + 2] * r[n + 1];
  out[i] = a;
}

// ---------- K9b: pointwise conv (GEMM) (B,CIN,N)->(B,256,N) with (B,C,N) residual ----------
template <int CIN, int NT>
__global__ __launch_bounds__(256) void k_pw(const float* __restrict__ in,
                                            const float* __restrict__ w,
                                            const float* __restrict__ bias,
                                            const float* __restrict__ resid,
                                            float* __restrict__ out) {
  __shared__ float tile[CIN][NT + 1];
  int nt = N_ / NT;
  int b = blockIdx.x / nt, n0 = (blockIdx.x % nt) * NT;
  for (int r = threadIdx.x; r < CIN; r += 256)
    for (int j = 0; j < NT; ++j)
      tile[r][j] = in[((long)b * CIN + r) * N_ + n0 + j];
  __syncthreads();
  int c = threadIdx.x;
  float acc[NT];
#pragma unroll
  for (int j = 0; j < NT; ++j) acc[j] = 0.f;
  const float* wr = w + (long)c * CIN;
  for (int r = 0; r < CIN; ++r) {
    float wv = wr[r];
#pragma unroll
    for (int j = 0; j < NT; ++j) acc[j] += wv * tile[r][j];
  }
  float bv = bias[c];
  for (int j = 0; j < NT; ++j) {
    long o = ((long)b * C_ + c) * N_ + n0 + j;
    float v = acc[j] + bv;
    if (resid) v += resid[o];
    out[o] = v;
  }
}

// ---------- K10: depthwise conv over virtual cat = [xs^T ; R] (B,512,N) ----------
__global__ __launch_bounds__(256) void k_fdw(const float* __restrict__ XS,
                                             const float* __restrict__ RB,
                                             const float* __restrict__ w,
                                             const float* __restrict__ bias,
                                             float* __restrict__ YDW) {
  long i = (long)blockIdx.x * 256 + threadIdx.x;  // B*512*N
  int n = i & 1023;
  long bc = i >> 10;
  int cc = bc & 511, b = (int)(bc >> 9);
  float v0 = 0.f, v1, v2 = 0.f;
  if (cc < C_) {
    const float* p = XS + (long)b * N_ * C_ + cc;
    v1 = p[(long)n * C_];
    if (n > 0)      v0 = p[(long)(n - 1) * C_];
    if (n < N_ - 1) v2 = p[(long)(n + 1) * C_];
  } else {
    const float* p = RB + ((long)b * C_ + (cc - C_)) * N_;
    v1 = p[n];
    if (n > 0)      v0 = p[n - 1];
    if (n < N_ - 1) v2 = p[n + 1];
  }
  YDW[i] = bias[cc] + w[cc * 3] * v0 + w[cc * 3 + 1] * v1 + w[cc * 3 + 2] * v2;
}

// ---------- K11: fpw pointwise (B,512,N)->(B,N,C) + xs residual ----------
__global__ __launch_bounds__(256) void k_fpw(const float* __restrict__ YDW,
                                             const float* __restrict__ w,
                                             const float* __restrict__ bias,
                                             const float* __restrict__ XS,
                                             float* __restrict__ XM2) {
  __shared__ float tile[512][9];
  constexpr int NT = 8;
  int nt = N_ / NT;
  int b = blockIdx.x / nt, n0 = (blockIdx.x % nt) * NT;
  for (int i = threadIdx.x; i < 512 * NT; i += 256) {
    int r = i >> 3, j = i & 7;
    tile[r][j] = YDW[((long)b * 512 + r) * N_ + n0 + j];
  }
  __syncthreads();
  int c = threadIdx.x;
  float acc[NT];
#pragma unroll
  for (int j = 0; j < NT; ++j) acc[j] = 0.f;
  const float* wr = w + (long)c * 512;
  for (int r = 0; r < 512; ++r) {
    float wv = wr[r];
#pragma unroll
    for (int j = 0; j < NT; ++j) acc[j] += wv * tile[r][j];
  }
  float bv = bias[c];
  for (int j = 0; j < NT; ++j) {
    long o = ((long)b * N_ + n0 + j) * C_ + c;
    XM2[o] = acc[j] + bv + XS[o];
  }
}

// ---------- K12: x_local depthwise over n in (B,N,C) layout ----------
__global__ __launch_bounds__(256) void k_lc(const float* __restrict__ XM2,
                                            const float* __restrict__ w,
                                            const float* __restrict__ bias,
                                            float* __restrict__ XL) {
  long i = (long)blockIdx.x * 256 + threadIdx.x;  // B*N*C, c fastest
  int c = i & 255;
  long bn = i >> 8;
  int n = bn & 1023, b = (int)(bn >> 10);
  const float* p = XM2 + (long)b * N_ * C_ + c;
  float a = bias[c] + w[c * 3 + 1] * p[(long)n * C_];
  if (n > 0)      a += w[c * 3 + 0] * p[(long)(n - 1) * C_];
  if (n < N_ - 1) a += w[c * 3 + 2] * p[(long)(n + 1) * C_];
  XL[i] = a;
}

// ---------- row GEMM: out[r, c] = in[r,:KD] . W[c,:KD] + bias  (rows = B*N) ----------
template <int KD, int NCOL, int ROWS>
__global__ __launch_bounds__(256) void k_rowgemm(const float* __restrict__ in,
                                                 const float* __restrict__ w,
                                                 const float* __restrict__ bias,
                                                 float* __restrict__ out, int Cout) {
  __shared__ float tile[ROWS][KD + 1];
  long r0 = (long)blockIdx.x * ROWS;
  for (int i = threadIdx.x; i < ROWS * KD; i += 256) {
    int r = i / KD, k = i % KD;
    tile[r][k] = in[(r0 + r) * KD + k];
  }
  __syncthreads();
  int t = threadIdx.x;
  float acc[NCOL][ROWS];
#pragma unroll
  for (int q = 0; q < NCOL; ++q)
#pragma unroll
    for (int r = 0; r < ROWS; ++r) acc[q][r] = 0.f;
  for (int k = 0; k < KD; ++k) {
    float xv[ROWS];
#pragma unroll
    for (int r = 0; r < ROWS; ++r) xv[r] = tile[r][k];
#pragma unroll
    for (int q = 0; q < NCOL; ++q) {
      float wv = w[(long)(t + 256 * q) * KD + k];
#pragma unroll
      for (int r = 0; r < ROWS; ++r) acc[q][r] += wv * xv[r];
    }
  }
  for (int q = 0; q < NCOL; ++q) {
    int c = t + 256 * q;
    float bv = bias[c];
    for (int r = 0; r < ROWS; ++r) out[(r0 + r) * Cout + c] = acc[q][r] + bv;
  }
}

// ---------- K16: fc over concat[XL, XGL] ----------
__global__ __launch_bounds__(256) void k_fc(const float* __restrict__ XL,
                                            const float* __restrict__ XGL,
                                            const float* __restrict__ w,
                                            const float* __restrict__ bias,
                                            float* __restrict__ out) {
  constexpr int ROWS = 8;
  __shared__ float tile[ROWS][513];
  long r0 = (long)blockIdx.x * ROWS;
  for (int i = threadIdx.x; i < ROWS * 256; i += 256) {
    int r = i >> 8, k = i & 255;
    tile[r][k] = XL[(r0 + r) * C_ + k];
    tile[r][256 + k] = XGL[(r0 + r) * C_ + k];
  }
  __syncthreads();
  int t = threadIdx.x;
  float acc[ROWS];
#pragma unroll
  for (int r = 0; r < ROWS; ++r) acc[r] = 0.f;
  const float* wr = w + (long)t * 512;
  for (int k = 0; k < 512; ++k) {
    float wv = wr[k];
#pragma unroll
    for (int r = 0; r < ROWS; ++r) acc[r] += wv * tile[r][k];
  }
  float bv = bias[t];
  for (int r = 0; r < ROWS; ++r) out[(r0 + r) * C_ + t] = acc[r] + bv;
}

// ---------- K14: key-split flash attention ----------
// block: 256 threads = 32 queries x 8 key-splits (keys strided mod 8).
// grid: (B*NH) * (N/32) = 1024 blocks.
__global__ __launch_bounds__(256) void k_attn(const float* __restrict__ qkv,
                                              float* __restrict__ O) {
  __shared__ float smem[8 * 32 * 36];          // main: ks[64][32] | vs[64][32]; then cacc[8][32][36]
  __shared__ float cml[8][32][2];
  float* ks = smem;
  float* vs = smem + 2048;
  int bh = blockIdx.x >> 5;
  int qt = blockIdx.x & 31;
  int b = bh >> 3, h = bh & 7;
  int t = threadIdx.x;
  int q = t & 31, kl = t >> 5;
  int qrow = qt * 32 + q;
  const float scale = 0.17677669529663687f;    // 1/sqrt(32)
  float qv[32];
  {
    const float* qp = qkv + ((long)(b * N_ + qrow)) * 768 + h * HD_;
#pragma unroll
    for (int j4 = 0; j4 < 8; ++j4) {
      float4 v = *(const float4*)(qp + j4 * 4);
      qv[j4 * 4 + 0] = v.x * scale;
      qv[j4 * 4 + 1] = v.y * scale;
      qv[j4 * 4 + 2] = v.z * scale;
      qv[j4 * 4 + 3] = v.w * scale;
    }
  }
  float m = -1e30f, l = 0.f;
  float acc[32];
#pragma unroll
  for (int j = 0; j < 32; ++j) acc[j] = 0.f;

  for (int c0 = 0; c0 < N_; c0 += 64) {
    __syncthreads();
    for (int i = t; i < 1024; i += 256) {       // 64 rows * (K:8 + V:8) float4
      int row = i >> 4, part = (i >> 3) & 1, j4 = i & 7;
      const float* gp = qkv + ((long)(b * N_ + c0 + row)) * 768 + 256 + part * 256 + h * HD_ + j4 * 4;
      float4 v = *(const float4*)gp;
      float* dst = (part ? vs : ks) + row * 32 + j4 * 4;
      *(float4*)dst = v;
    }
    __syncthreads();
    float s[8];
#pragma unroll
    for (int i8 = 0; i8 < 8; ++i8) {
      const float* kr = ks + (kl + i8 * 8) * 32;
      float a = 0.f;
#pragma unroll
      for (int j4 = 0; j4 < 8; ++j4) {
        float4 kv = *(const float4*)(kr + j4 * 4);
        a += qv[j4 * 4 + 0] * kv.x + qv[j4 * 4 + 1] * kv.y +
             qv[j4 * 4 + 2] * kv.z + qv[j4 * 4 + 3] * kv.w;
      }
      s[i8] = a;
    }
    float mx = s[0];
#pragma unroll
    for (int i8 = 1; i8 < 8; ++i8) mx = fmaxf(mx, s[i8]);
    float mn = fmaxf(m, mx);
    float corr = __expf(m - mn);
    float p[8], ps = 0.f;
#pragma unroll
    for (int i8 = 0; i8 < 8; ++i8) { p[i8] = __expf(s[i8] - mn); ps += p[i8]; }
    l = l * corr + ps;
    m = mn;
#pragma unroll
    for (int j = 0; j < 32; ++j) acc[j] *= corr;
#pragma unroll
    for (int i8 = 0; i8 < 8; ++i8) {
      const float* vr = vs + (kl + i8 * 8) * 32;
      float pi = p[i8];
#pragma unroll
      for (int j4 = 0; j4 < 8; ++j4) {
        float4 vv = *(const float4*)(vr + j4 * 4);
        acc[j4 * 4 + 0] += pi * vv.x;
        acc[j4 * 4 + 1] += pi * vv.y;
        acc[j4 * 4 + 2] += pi * vv.z;
        acc[j4 * 4 + 3] += pi * vv.w;
      }
    }
  }
  // partials -> LDS
  cml[kl][q][0] = m;
  cml[kl][q][1] = l;
  __syncthreads();                              // ks/vs dead; smem becomes cacc[8][32][36]
  {
    float* dst = smem + (kl * 32 + q) * 36;
#pragma unroll
    for (int j4 = 0; j4 < 8; ++j4)
      *(float4*)(dst + j4 * 4) = make_float4(acc[j4 * 4 + 0], acc[j4 * 4 + 1],
                                             acc[j4 * 4 + 2], acc[j4 * 4 + 3]);
  }
  __syncthreads();
  // combine: ds = t&7 (4-dim group), q2 = t>>3
  int ds = t & 7, q2 = t >> 3;
  float m2 = cml[0][q2][0];
#pragma unroll
  for (int i = 1; i < 8; ++i) m2 = fmaxf(m2, cml[i][q2][0]);
  float lsum = 0.f, f[8];
#pragma unroll
  for (int i = 0; i < 8; ++i) {
    f[i] = __expf(cml[i][q2][0] - m2);
    lsum += f[i] * cml[i][q2][1];
  }
  float inv = 1.f / lsum;
  float o0 = 0.f, o1 = 0.f, o2 = 0.f, o3 = 0.f;
#pragma unroll
  for (int i = 0; i < 8; ++i) {
    const float* src = smem + (i * 32 + q2) * 36 + ds * 4;
    float4 a = *(const float4*)src;
    o0 += f[i] * a.x; o1 += f[i] * a.y; o2 += f[i] * a.z; o3 += f[i] * a.w;
  }
  *(float4*)(O + ((long)(b * N_ + qt * 32 + q2)) * C_ + h * HD_ + ds * 4) =
      make_float4(o0 * inv, o1 * inv, o2 * inv, o3 * inv);
}

// ---------- K17: LN(lgn) + exact GELU -> (B,C,N) layout ----------
__global__ __launch_bounds__(256) void k_lngelu(const float* __restrict__ XO,
                                                const float* __restrict__ lw,
                                                const float* __restrict__ lb,
                                                float* __restrict__ XI) {
  __shared__ float red[8];
  int bn = blockIdx.x;
  int b = bn >> 10, n = bn & 1023;
  int c = threadIdx.x;
  float v = XO[(long)bn * C_ + c];
  float2 s = blockReduce2(v, v * v, red);
  float mu = s.x * (1.f / C_);
  float rs = rsqrtf(s.y * (1.f / C_) - mu * mu + 1e-5f);
  float x = (v - mu) * rs * lw[c] + lb[c];
  float ge = 0.5f * x * (1.f + erff(x * 0.70710678118654752f));
  XI[((long)b * C_ + c) * N_ + n] = ge;
}

// ---------- K18: ln over (H,W) per (b,c), in place, no affine ----------
__global__ __launch_bounds__(256) void k_lnhw(float* __restrict__ XI) {
  __shared__ float red[8];
  long base = (long)blockIdx.x * N_;  // b*C + c
  float a = 0.f, b2 = 0.f;
  for (int i = threadIdx.x; i < N_; i += 256) {
    float v = XI[base + i];
    a += v; b2 += v * v;
  }
  float2 s = blockReduce2(a, b2, red);
  float mu = s.x * (1.f / N_);
  float rs = rsqrtf(s.y * (1.f / N_) - mu * mu + 1e-5f);
  for (int i = threadIdx.x; i < N_; i += 256) XI[base + i] = (XI[base + i] - mu) * rs;
}

// ---------- K19: depthwise 3x3 conv on (B,C,32,32), pad 1 ----------
__global__ __launch_bounds__(256) void k_dwc(const float* __restrict__ XI,
                                             const float* __restrict__ w,
                                             const float* __restrict__ bias,
                                             float* __restrict__ XD) {
  long i = (long)blockIdx.x * 256 + threadIdx.x;  // B*C*1024
  int hw = i & 1023;
  int wq = hw & 31, hq = hw >> 5;
  int c = (int)((i >> 10) & 255);
  const float* p = XI + (i - hw);
  const float* wk = w + c * 9;
  float a = bias[c];
#pragma unroll
  for (int kh = 0; kh < 3; ++kh) {
    int h2 = hq + kh - 1;
    if (h2 < 0 || h2 >= 32) continue;
#pragma unroll
    for (int kw = 0; kw < 3; ++kw) {
      int w2 = wq + kw - 1;
      if (w2 < 0 || w2 >= 32) continue;
      a += wk[kh * 3 + kw] * p[h2 * 32 + w2];
    }
  }
  XD[i] = a;
}

// ---------- K20b: final proj with transposed write (B,N,C)->(B,COUT,N) ----------
__global__ __launch_bounds__(256) void k_rowgemm_t(const float* __restrict__ in,
                                                   const float* __restrict__ w,
                                                   const float* __restrict__ bias,
                                                   float* __restrict__ out) {
  constexpr int ROWS = 8;
  __shared__ float tile[ROWS][257];
  long r0 = (long)blockIdx.x * ROWS;
  for (int i = threadIdx.x; i < ROWS * 256; i += 256) {
    int r = i >> 8, k = i & 255;
    tile[r][k] = in[(r0 + r) * C_ + k];
  }
  __syncthreads();
  int t = threadIdx.x;
  float acc[ROWS];
#pragma unroll
  for (int r = 0; r < ROWS; ++r) acc[r] = 0.f;
  const float* wr = w + (long)t * C_;
  for (int k = 0; k < C_; ++k) {
    float wv = wr[k];
#pragma unroll
    for (int r = 0; r < ROWS; ++r) acc[r] += wv * tile[r][k];
  }
  float bv = bias[t];
  for (int r = 0; r < ROWS; ++r) {
    long row = r0 + r;          // b*N + n
    int b = (int)(row >> 10), n = (int)(row & 1023);
    out[((long)b * C_ + t) * N_ + n] = acc[r] + bv;
  }
}

extern "C" void kernel_launch(void* const* d_in, const int* in_sizes, int n_in,
                              void* d_out, int out_size, void* d_ws, size_t ws_size,
                              hipStream_t stream) {
  const float* x        = (const float*)d_in[0];
  const float* norm_w   = (const float*)d_in[1];
  const float* norm_b   = (const float*)d_in[2];
  const float* skip     = (const float*)d_in[3];
  const float* m_inw    = (const float*)d_in[4];
  const float* m_convw  = (const float*)d_in[5];
  const float* m_convb  = (const float*)d_in[6];
  const float* m_xpw    = (const float*)d_in[7];
  const float* m_dtw    = (const float*)d_in[8];
  const float* m_dtb    = (const float*)d_in[9];
  const float* m_alog   = (const float*)d_in[10];
  const float* m_d      = (const float*)d_in[11];
  const float* m_outw   = (const float*)d_in[12];
  const float* qdw_w    = (const float*)d_in[13];
  const float* qdw_b    = (const float*)d_in[14];
  const float* qpw_w    = (const float*)d_in[15];
  const float* qpw_b    = (const float*)d_in[16];
  const float* rdw_w    = (const float*)d_in[17];
  const float* rdw_b    = (const float*)d_in[18];
  const float* rpw_w    = (const float*)d_in[19];
  const float* rpw_b    = (const float*)d_in[20];
  const float* fdw_w    = (const float*)d_in[21];
  const float* fdw_b    = (const float*)d_in[22];
  const float* fpw_w    = (const float*)d_in[23];
  const float* fpw_b    = (const float*)d_in[24];
  const float* lc_w     = (const float*)d_in[25];
  const float* lc_b     = (const float*)d_in[26];
  const float* attn_inw = (const float*)d_in[27];
  const float* attn_inb = (const float*)d_in[28];
  const float* attn_outw= (const float*)d_in[29];
  const float* attn_outb= (const float*)d_in[30];
  const float* lgn_w    = (const float*)d_in[31];
  const float* lgn_b    = (const float*)d_in[32];
  const float* fc_w     = (const float*)d_in[33];
  const float* fc_b     = (const float*)d_in[34];
  const float* dwc_w    = (const float*)d_in[35];
  const float* dwc_b    = (const float*)d_in[36];
  const float* proj_w   = (const float*)d_in[37];
  const float* proj_b   = (const float*)d_in[38];
  float* out = (float*)d_out;

  float* ws = (float*)d_ws;
  const size_t F = 1048576;  // B*N*C
  float* XS  = ws + 0 * F;
  float* XN  = ws + 1 * F;
  float* U   = ws + 2 * F;
  float* Z   = ws + 4 * F;
  float* DT  = ws + 6 * F;
  float* BM  = ws + 8 * F;
  float* CM  = ws + 8 * F + F / 4;
  float* XMC = ws + 8 * F + F / 2;
  float* G   = ws + 1 * F;
  float* XG  = ws + 2 * F;
  float* RD  = ws + 3 * F;
  float* RB  = ws + 4 * F;
  float* XM2 = ws + 5 * F;
  float* YDW = ws + 6 * F;
  float* XL  = ws + 0 * F;
  float* QKV = ws + 1 * F;
  float* O   = ws + 4 * F;
  float* XGL = ws + 6 * F;
  float* XO  = ws + 7 * F;
  float* XI  = ws + 8 * F;
  float* XD  = ws + 5 * F;
  float* LNF = ws + 0 * F;
  (void)ws_size; (void)in_sizes; (void)n_in; (void)out_size;

  k_ln_t<<<4096, 256, 0, stream>>>(x, norm_w, norm_b, XN, XS);
  k_inproj<<<dim3(64, 4), 256, 0, stream>>>(XN, m_inw, U, Z);
  k_causal<<<2048, 256, 0, stream>>>(U, m_convw, m_convb);
  k_xdbc<<<2048, 128, 0, stream>>>(U, m_xpw, m_dtw, m_dtb, DT, BM, CM);
  k_scan<<<128, 256, 0, stream>>>(DT, U, BM, CM, m_alog, m_d);
  k_outproj<<<1024, 256, 0, stream>>>(DT, Z, m_outw, XN, skip, XMC);
  k_gate<<<256, 256, 0, stream>>>(XMC, qdw_w, qdw_b, qpw_w, qpw_b, G);
  k_xg<<<4096, 256, 0, stream>>>(XMC, G, XG);
  k_dw3<<<4096, 256, 0, stream>>>(XG, rdw_w, rdw_b, RD, 256);
  k_pw<256, 16><<<256, 256, 0, stream>>>(RD, rpw_w, rpw_b, XG, RB);
  k_fdw<<<8192, 256, 0, stream>>>(XS, RB, fdw_w, fdw_b, YDW);
  k_fpw<<<512, 256, 0, stream>>>(YDW, fpw_w, fpw_b, XS, XM2);
  k_lc<<<4096, 256, 0, stream>>>(XM2, lc_w, lc_b, XL);
  k_rowgemm<256, 3, 8><<<512, 256, 0, stream>>>(XM2, attn_inw, attn_inb, QKV, 768);
  k_attn<<<1024, 256, 0, stream>>>(QKV, O);
  k_rowgemm<256, 1, 8><<<512, 256, 0, stream>>>(O, attn_outw, attn_outb, XGL, 256);
  k_fc<<<512, 256, 0, stream>>>(XL, XGL, fc_w, fc_b, XO);
  k_lngelu<<<4096, 256, 0, stream>>>(XO, lgn_w, lgn_b, XI);
  k_lnhw<<<1024, 256, 0, stream>>>(XI);
  k_dwc<<<4096, 256, 0, stream>>>(XI, dwc_w, dwc_b, XD);
  k_ln_t<<<4096, 256, 0, stream>>>(XD, norm_w, norm_b, LNF, nullptr);
  k_rowgemm_t<<<512, 256, 0, stream>>>(LNF, proj_w, proj_b, out);
}

// Round 3
// 596.127 us; speedup vs baseline: 1.9563x; 1.3024x over previous
//
#include <hip/hip_runtime.h>
#include <math.h>

// MambaLiteUNet — fp32, round 2: chunked parallel selective scan (3-phase),
// replacing the 128-block serial scan (241 us, 5.7% occupancy).

namespace {
constexpr int NB_ = 4, DM_ = 64, DIN_ = 128, DS_ = 16, DTR_ = 4;
constexpr int C_ = 256, N_ = 1024, B_ = 4, HD_ = 32;
constexpr int NCH = 16, LCH = 64;          // scan: 16 time-chunks of 64
constexpr int NSTATE = 16 * 128 * 16;      // nbb * DIN * DS = 32768
}

// ---------- helpers ----------
__device__ __forceinline__ float2 blockReduce2(float a, float b, float* red) {
#pragma unroll
  for (int m = 1; m < 64; m <<= 1) {
    a += __shfl_xor(a, m, 64);
    b += __shfl_xor(b, m, 64);
  }
  int w = threadIdx.x >> 6;
  if ((threadIdx.x & 63) == 0) { red[2 * w] = a; red[2 * w + 1] = b; }
  __syncthreads();
  float ra = red[0] + red[2] + red[4] + red[6];
  float rb = red[1] + red[3] + red[5] + red[7];
  return make_float2(ra, rb);
}

__device__ __forceinline__ float siluf(float x) { return x / (1.f + expf(-x)); }
__device__ __forceinline__ float sigmf(float x) { return 1.f / (1.f + expf(-x)); }
__device__ __forceinline__ float softplusf(float x) {
  return fmaxf(x, 0.f) + log1pf(expf(-fabsf(x)));
}

// ---------- K1/K20a: layernorm over C of a (B,C,N) tensor -> (B,N,C); optional raw copy ----------
__global__ __launch_bounds__(256) void k_ln_t(const float* __restrict__ in,
                                              const float* __restrict__ w,
                                              const float* __restrict__ bias,
                                              float* __restrict__ out_ln,
                                              float* __restrict__ out_copy) {
  __shared__ float red[8];
  int bn = blockIdx.x;            // b*N + n
  int b = bn >> 10, n = bn & 1023;
  int c = threadIdx.x;
  float v = in[(b * C_ + c) * N_ + n];
  if (out_copy) out_copy[(long)bn * C_ + c] = v;
  float2 s = blockReduce2(v, v * v, red);
  float mu = s.x * (1.f / C_);
  float var = s.y * (1.f / C_) - mu * mu;
  float rs = rsqrtf(var + 1e-5f);
  out_ln[(long)bn * C_ + c] = (v - mu) * rs * w[c] + bias[c];
}

// ---------- K2: mamba in-proj  xz = xn_block @ inw^T  -> u, z ----------
__global__ __launch_bounds__(256) void k_inproj(const float* __restrict__ xn,
                                                const float* __restrict__ inw,
                                                float* __restrict__ U, float* __restrict__ Z) {
  __shared__ float xrows[4][64];
  int nb = blockIdx.y;
  int j = threadIdx.x;                       // output col 0..255
  const float* wp = inw + ((long)nb * 2 * DIN_ + j) * DM_;
  float wreg[64];
#pragma unroll
  for (int m = 0; m < 64; ++m) wreg[m] = wp[m];
  int row0 = blockIdx.x * 64;                // over B*N = 4096 rows
  for (int r0 = 0; r0 < 64; r0 += 4) {
    __syncthreads();
    {
      int rr = threadIdx.x >> 6, m = threadIdx.x & 63;
      xrows[rr][m] = xn[(long)(row0 + r0 + rr) * C_ + nb * DM_ + m];
    }
    __syncthreads();
    for (int rr = 0; rr < 4; ++rr) {
      float acc = 0.f;
#pragma unroll
      for (int m = 0; m < 64; ++m) acc += xrows[rr][m] * wreg[m];
      long row = (long)nb * (B_ * N_) + row0 + r0 + rr;
      if (j < DIN_) U[row * DIN_ + j] = acc;
      else          Z[row * DIN_ + (j - DIN_)] = acc;
    }
  }
}

// ---------- K3: causal depthwise conv (K=4) + silu, in-place on U ----------
__global__ __launch_bounds__(256) void k_causal(float* __restrict__ U,
                                                const float* __restrict__ cw,
                                                const float* __restrict__ cb) {
  __shared__ float row[N_];
  int blk = blockIdx.x;                      // nbb*DIN + d,  nbb = nb*B+b
  int d = blk & 127, nbb = blk >> 7, nb = nbb >> 2;
  float* base = U + (long)nbb * N_ * DIN_ + d;
  for (int n = threadIdx.x; n < N_; n += 256) row[n] = base[(long)n * DIN_];
  __syncthreads();
  float w0 = cw[(nb * DIN_ + d) * 4 + 0], w1 = cw[(nb * DIN_ + d) * 4 + 1];
  float w2 = cw[(nb * DIN_ + d) * 4 + 2], w3 = cw[(nb * DIN_ + d) * 4 + 3];
  float bias = cb[nb * DIN_ + d];
  for (int n = threadIdx.x; n < N_; n += 256) {
    float acc = bias + w3 * row[n];
    if (n >= 1) acc += w2 * row[n - 1];
    if (n >= 2) acc += w1 * row[n - 2];
    if (n >= 3) acc += w0 * row[n - 3];
    base[(long)n * DIN_] = siluf(acc);
  }
}

// ---------- K4: xdbc = u @ xpw^T ; dt = softplus(xdbc[:4] @ dtw^T + dtb); Bm, Cm ----------
__global__ __launch_bounds__(128) void k_xdbc(const float* __restrict__ U,
                                              const float* __restrict__ xpw,
                                              const float* __restrict__ dtw,
                                              const float* __restrict__ dtb,
                                              float* __restrict__ DT,
                                              float* __restrict__ BMb, float* __restrict__ CMb) {
  __shared__ float wl[36][129];
  __shared__ float urow[128];
  __shared__ float xd[36];
  int t = threadIdx.x;
  int nb = blockIdx.x >> 9;                  // 2048 blocks, 8 rows each; 4096 rows per nb
  for (int i = t; i < 36 * 128; i += 128) wl[i >> 7][i & 127] = xpw[nb * 36 * 128 + i];
  float dw0 = dtw[(nb * DIN_ + t) * 4 + 0], dw1 = dtw[(nb * DIN_ + t) * 4 + 1];
  float dw2 = dtw[(nb * DIN_ + t) * 4 + 2], dw3 = dtw[(nb * DIN_ + t) * 4 + 3];
  float dtbv = dtb[nb * DIN_ + t];
  for (int r8 = 0; r8 < 8; ++r8) {
    long row = (long)blockIdx.x * 8 + r8;
    __syncthreads();
    urow[t] = U[row * DIN_ + t];
    __syncthreads();
    if (t < 36) {
      float a = 0.f;
#pragma unroll 8
      for (int m = 0; m < 128; ++m) a += urow[m] * wl[t][m];
      xd[t] = a;
    }
    __syncthreads();
    if (t < 16) { BMb[row * DS_ + t] = xd[4 + t]; CMb[row * DS_ + t] = xd[20 + t]; }
    float a = dtbv + xd[0] * dw0 + xd[1] * dw1 + xd[2] * dw2 + xd[3] * dw3;
    DT[row * DIN_ + t] = softplusf(a);
  }
}

// ---------- K5a: scan phase A — per-chunk local scan: decay product + end state ----------
// block: (chunk, nbb, dch); threads: ch = t>>4 (d in group), s = t&15.
__global__ __launch_bounds__(256) void k_scanA(const float* __restrict__ DT,
                                               const float* __restrict__ U,
                                               const float* __restrict__ BMb,
                                               const float* __restrict__ alog,
                                               float* __restrict__ Aprod,
                                               float* __restrict__ Hend) {
  __shared__ float dt_s[LCH][16], u_s[LCH][16], bm_s[LCH][16];
  int blk = blockIdx.x;
  int dch = blk & 7, nbb = (blk >> 3) & 15, chunk = blk >> 7;
  int nb = nbb >> 2;
  int t = threadIdx.x;
  int ch = t >> 4, s = t & 15;
  int d = dch * 16 + ch;
  float A = -expf(alog[(nb * DIN_ + d) * DS_ + s]);
  long base = (long)nbb * N_ + chunk * LCH;
  for (int i = t; i < LCH * 16; i += 256) {
    int tt = i >> 4, cc = i & 15;
    long r = base + tt;
    dt_s[tt][cc] = DT[r * DIN_ + dch * 16 + cc];
    u_s[tt][cc]  = U [r * DIN_ + dch * 16 + cc];
    bm_s[tt][cc] = BMb[r * DS_ + cc];
  }
  __syncthreads();
  float h = 0.f, ap = 1.f;
#pragma unroll 8
  for (int tt = 0; tt < LCH; ++tt) {
    float dtv = dt_s[tt][ch];
    float uv  = u_s[tt][ch];
    float dA = __expf(dtv * A);
    h = dA * h + dtv * uv * bm_s[tt][s];
    ap *= dA;
  }
  int state = ((nbb << 7) + d) * 16 + s;
  Aprod[(long)chunk * NSTATE + state] = ap;
  Hend[(long)chunk * NSTATE + state] = h;
}

// ---------- K5b: scan phase B — carry composition across chunks; Hin written over Aprod ----------
__global__ __launch_bounds__(256) void k_scanB(float* __restrict__ Aprod,
                                               const float* __restrict__ Hend) {
  int state = blockIdx.x * 256 + threadIdx.x;
  float H = 0.f;
#pragma unroll
  for (int c = 0; c < NCH; ++c) {
    long idx = (long)c * NSTATE + state;
    float a = Aprod[idx];
    float e = Hend[idx];
    Aprod[idx] = H;            // Hin for chunk c
    H = e + a * H;
  }
}

// ---------- K5c: scan phase C — re-run chunk from carry, emit y over DT ----------
__global__ __launch_bounds__(256) void k_scanC(float* __restrict__ DT,
                                               const float* __restrict__ U,
                                               const float* __restrict__ BMb,
                                               const float* __restrict__ CMb,
                                               const float* __restrict__ alog,
                                               const float* __restrict__ Dp,
                                               const float* __restrict__ Hin) {
  __shared__ float dt_s[LCH][16], u_s[LCH][16], bm_s[LCH][16], cm_s[LCH][16];
  int blk = blockIdx.x;
  int dch = blk & 7, nbb = (blk >> 3) & 15, chunk = blk >> 7;
  int nb = nbb >> 2;
  int t = threadIdx.x;
  int ch = t >> 4, s = t & 15;
  int d = dch * 16 + ch;
  float A = -expf(alog[(nb * DIN_ + d) * DS_ + s]);
  float Dv = Dp[nb * DIN_ + d];
  long base = (long)nbb * N_ + chunk * LCH;
  for (int i = t; i < LCH * 16; i += 256) {
    int tt = i >> 4, cc = i & 15;
    long r = base + tt;
    dt_s[tt][cc] = DT[r * DIN_ + dch * 16 + cc];
    u_s[tt][cc]  = U [r * DIN_ + dch * 16 + cc];
    bm_s[tt][cc] = BMb[r * DS_ + cc];
    cm_s[tt][cc] = CMb[r * DS_ + cc];
  }
  int state = ((nbb << 7) + d) * 16 + s;
  float h = Hin[(long)chunk * NSTATE + state];
  __syncthreads();
  for (int tt = 0; tt < LCH; ++tt) {
    float dtv = dt_s[tt][ch];
    float uv  = u_s[tt][ch];
    float dA = __expf(dtv * A);
    h = dA * h + dtv * uv * bm_s[tt][s];
    float p = h * cm_s[tt][s];
    p += __shfl_xor(p, 1, 16);
    p += __shfl_xor(p, 2, 16);
    p += __shfl_xor(p, 4, 16);
    p += __shfl_xor(p, 8, 16);
    if (s == 0) DT[(base + tt) * DIN_ + d] = p + Dv * uv;
  }
}

// ---------- K6: y2 = y*silu(z); xm = y2 @ outw^T + skip*xn -> concat layout (B,N,C) ----------
__global__ __launch_bounds__(256) void k_outproj(const float* __restrict__ Y,
                                                 const float* __restrict__ Z,
                                                 const float* __restrict__ outw,
                                                 const float* __restrict__ xn,
                                                 const float* __restrict__ skip,
                                                 float* __restrict__ XMC) {
  __shared__ float wL[64][129];
  __shared__ float y2r[16][128];
  int row0 = blockIdx.x * 16;                // over NB*B*N = 16384 rows
  int nb = row0 >> 12;
  for (int i = threadIdx.x; i < 64 * 128; i += 256) {
    int col = i >> 7, j = i & 127;
    wL[col][j] = outw[nb * DM_ * DIN_ + i];
  }
  for (int i = threadIdx.x; i < 16 * 128; i += 256) {
    int r = i >> 7, j = i & 127;
    long row = (long)row0 + r;
    float z = Z[row * DIN_ + j];
    y2r[r][j] = Y[row * DIN_ + j] * siluf(z);
  }
  __syncthreads();
  float sk = skip[0];
  int col = threadIdx.x & 63;
  int rbase = threadIdx.x >> 6;
  for (int ii = 0; ii < 4; ++ii) {
    int rr = rbase + ii * 4;
    float acc = 0.f;
#pragma unroll 8
    for (int j = 0; j < 128; ++j) acc += y2r[rr][j] * wL[col][j];
    int bn = (row0 + rr) & 4095;
    long oc = (long)bn * C_ + nb * DM_ + col;
    XMC[oc] = acc + sk * xn[oc];
  }
}

// ---------- K7: gate  g = sigmoid(pw(dw(xm_concat^T))), parallel version ----------
__global__ __launch_bounds__(256) void k_gate(const float* __restrict__ XMC,
                                              const float* __restrict__ qdw_w,
                                              const float* __restrict__ qdw_b,
                                              const float* __restrict__ qpw_w,
                                              const float* __restrict__ qpw_b,
                                              float* __restrict__ G) {
  int t = threadIdx.x;
  int gid = (blockIdx.x * 256 + t) >> 4;     // b*N + n
  int cq = t & 3, p = (t >> 2) & 3;
  int b = gid >> 10, n = gid & 1023;
  float a = 0.f;
#pragma unroll
  for (int k = 0; k < 3; ++k) {
    int nn = n + k - 1;
    if (nn < 0 || nn >= N_) continue;
    const float* xr = XMC + ((long)b * N_ + nn) * C_ + p * 64 + cq * 16;
    const float* wr = qdw_w + (p * 64 + cq * 16) * 3 + k;
#pragma unroll
    for (int i = 0; i < 16; ++i) a += xr[i] * wr[i * 3];
  }
  a += __shfl_xor(a, 1, 64);
  a += __shfl_xor(a, 2, 64);
  float q1 = a + qdw_b[p];                   // all cq lanes hold q1(gid, p)
  int lane = t & 63;
  float q1g[4];
#pragma unroll
  for (int pp = 0; pp < 4; ++pp) q1g[pp] = __shfl(q1, (lane & ~12) | (pp << 2), 64);
  int o = p;
  float r = qpw_b[o];
#pragma unroll
  for (int pp = 0; pp < 4; ++pp) r += qpw_w[o * 4 + pp] * q1g[pp];
  if (cq == 0) G[((long)b * 4 + o) * N_ + n] = sigmf(r);
}

// ---------- K8: xg (B,C,N) = g * xm ----------
__global__ __launch_bounds__(256) void k_xg(const float* __restrict__ XMC,
                                            const float* __restrict__ G,
                                            float* __restrict__ XG) {
  long i = (long)blockIdx.x * 256 + threadIdx.x;  // B*C*N
  int n = i & 1023;
  long bc = i >> 10;
  int c = bc & 255, b = (int)(bc >> 8);
  float g = G[((long)b * 4 + (c >> 6)) * N_ + n];
  XG[i] = g * XMC[((long)b * N_ + n) * C_ + c];
}

// ---------- generic 3-tap depthwise conv over n, (B,nchan,N) layout ----------
__global__ __launch_bounds__(256) void k_dw3(const float* __restrict__ in,
                                             const float* __restrict__ w,
                                             const float* __restrict__ bias,
                                             float* __restrict__ out, int nchan) {
  long i = (long)blockIdx.x * 256 + threadIdx.x;
  if (i >= (long)B_ * nchan * N_) return;
  int n = i & 1023;
  int c = (int)((i >> 10) % nchan);
  const float* r = in + (i - n);
  float a = bias[c] + w[c * 3 + 1] * r[n];
  if (n > 0)      a += w[c * 3 + 0] * r[n - 1];
  if (n < N_ - 1) a += w[c * 3 + 2] * r[n + 1];
  out[i] = a;
}

// ---------- K9b: pointwise conv (GEMM) (B,CIN,N)->(B,256,N) with (B,C,N) residual ----------
template <int CIN, int NT>
__global__ __launch_bounds__(256) void k_pw(const float* __restrict__ in,
                                            const float* __restrict__ w,
                                            const float* __restrict__ bias,
                                            const float* __restrict__ resid,
                                            float* __restrict__ out) {
  __shared__ float tile[CIN][NT + 1];
  int nt = N_ / NT;
  int b = blockIdx.x / nt, n0 = (blockIdx.x % nt) * NT;
  for (int r = threadIdx.x; r < CIN; r += 256)
    for (int j = 0; j < NT; ++j)
      tile[r][j] = in[((long)b * CIN + r) * N_ + n0 + j];
  __syncthreads();
  int c = threadIdx.x;
  float acc[NT];
#pragma unroll
  for (int j = 0; j < NT; ++j) acc[j] = 0.f;
  const float* wr = w + (long)c * CIN;
  for (int r = 0; r < CIN; ++r) {
    float wv = wr[r];
#pragma unroll
    for (int j = 0; j < NT; ++j) acc[j] += wv * tile[r][j];
  }
  float bv = bias[c];
  for (int j = 0; j < NT; ++j) {
    long o = ((long)b * C_ + c) * N_ + n0 + j;
    float v = acc[j] + bv;
    if (resid) v += resid[o];
    out[o] = v;
  }
}

// ---------- K10: depthwise conv over virtual cat = [xs^T ; R] (B,512,N) ----------
__global__ __launch_bounds__(256) void k_fdw(const float* __restrict__ XS,
                                             const float* __restrict__ RB,
                                             const float* __restrict__ w,
                                             const float* __restrict__ bias,
                                             float* __restrict__ YDW) {
  long i = (long)blockIdx.x * 256 + threadIdx.x;  // B*512*N
  int n = i & 1023;
  long bc = i >> 10;
  int cc = bc & 511, b = (int)(bc >> 9);
  float v0 = 0.f, v1, v2 = 0.f;
  if (cc < C_) {
    const float* p = XS + (long)b * N_ * C_ + cc;
    v1 = p[(long)n * C_];
    if (n > 0)      v0 = p[(long)(n - 1) * C_];
    if (n < N_ - 1) v2 = p[(long)(n + 1) * C_];
  } else {
    const float* p = RB + ((long)b * C_ + (cc - C_)) * N_;
    v1 = p[n];
    if (n > 0)      v0 = p[n - 1];
    if (n < N_ - 1) v2 = p[n + 1];
  }
  YDW[i] = bias[cc] + w[cc * 3] * v0 + w[cc * 3 + 1] * v1 + w[cc * 3 + 2] * v2;
}

// ---------- K11: fpw pointwise (B,512,N)->(B,N,C) + xs residual ----------
__global__ __launch_bounds__(256) void k_fpw(const float* __restrict__ YDW,
                                             const float* __restrict__ w,
                                             const float* __restrict__ bias,
                                             const float* __restrict__ XS,
                                             float* __restrict__ XM2) {
  __shared__ float tile[512][9];
  constexpr int NT = 8;
  int nt = N_ / NT;
  int b = blockIdx.x / nt, n0 = (blockIdx.x % nt) * NT;
  for (int i = threadIdx.x; i < 512 * NT; i += 256) {
    int r = i >> 3, j = i & 7;
    tile[r][j] = YDW[((long)b * 512 + r) * N_ + n0 + j];
  }
  __syncthreads();
  int c = threadIdx.x;
  float acc[NT];
#pragma unroll
  for (int j = 0; j < NT; ++j) acc[j] = 0.f;
  const float* wr = w + (long)c * 512;
  for (int r = 0; r < 512; ++r) {
    float wv = wr[r];
#pragma unroll
    for (int j = 0; j < NT; ++j) acc[j] += wv * tile[r][j];
  }
  float bv = bias[c];
  for (int j = 0; j < NT; ++j) {
    long o = ((long)b * N_ + n0 + j) * C_ + c;
    XM2[o] = acc[j] + bv + XS[o];
  }
}

// ---------- K12: x_local depthwise over n in (B,N,C) layout ----------
__global__ __launch_bounds__(256) void k_lc(const float* __restrict__ XM2,
                                            const float* __restrict__ w,
                                            const float* __restrict__ bias,
                                            float* __restrict__ XL) {
  long i = (long)blockIdx.x * 256 + threadIdx.x;  // B*N*C, c fastest
  int c = i & 255;
  long bn = i >> 8;
  int n = bn & 1023, b = (int)(bn >> 10);
  const float* p = XM2 + (long)b * N_ * C_ + c;
  float a = bias[c] + w[c * 3 + 1] * p[(long)n * C_];
  if (n > 0)      a += w[c * 3 + 0] * p[(long)(n - 1) * C_];
  if (n < N_ - 1) a += w[c * 3 + 2] * p[(long)(n + 1) * C_];
  XL[i] = a;
}

// ---------- row GEMM: out[r, c] = in[r,:KD] . W[c,:KD] + bias  (rows = B*N) ----------
template <int KD, int NCOL, int ROWS>
__global__ __launch_bounds__(256) void k_rowgemm(const float* __restrict__ in,
                                                 const float* __restrict__ w,
                                                 const float* __restrict__ bias,
                                                 float* __restrict__ out, int Cout) {
  __shared__ float tile[ROWS][KD + 1];
  long r0 = (long)blockIdx.x * ROWS;
  for (int i = threadIdx.x; i < ROWS * KD; i += 256) {
    int r = i / KD, k = i % KD;
    tile[r][k] = in[(r0 + r) * KD + k];
  }
  __syncthreads();
  int t = threadIdx.x;
  float acc[NCOL][ROWS];
#pragma unroll
  for (int q = 0; q < NCOL; ++q)
#pragma unroll
    for (int r = 0; r < ROWS; ++r) acc[q][r] = 0.f;
  for (int k = 0; k < KD; ++k) {
    float xv[ROWS];
#pragma unroll
    for (int r = 0; r < ROWS; ++r) xv[r] = tile[r][k];
#pragma unroll
    for (int q = 0; q < NCOL; ++q) {
      float wv = w[(long)(t + 256 * q) * KD + k];
#pragma unroll
      for (int r = 0; r < ROWS; ++r) acc[q][r] += wv * xv[r];
    }
  }
  for (int q = 0; q < NCOL; ++q) {
    int c = t + 256 * q;
    float bv = bias[c];
    for (int r = 0; r < ROWS; ++r) out[(r0 + r) * Cout + c] = acc[q][r] + bv;
  }
}

// ---------- K16: fc over concat[XL, XGL] ----------
__global__ __launch_bounds__(256) void k_fc(const float* __restrict__ XL,
                                            const float* __restrict__ XGL,
                                            const float* __restrict__ w,
                                            const float* __restrict__ bias,
                                            float* __restrict__ out) {
  constexpr int ROWS = 8;
  __shared__ float tile[ROWS][513];
  long r0 = (long)blockIdx.x * ROWS;
  for (int i = threadIdx.x; i < ROWS * 256; i += 256) {
    int r = i >> 8, k = i & 255;
    tile[r][k] = XL[(r0 + r) * C_ + k];
    tile[r][256 + k] = XGL[(r0 + r) * C_ + k];
  }
  __syncthreads();
  int t = threadIdx.x;
  float acc[ROWS];
#pragma unroll
  for (int r = 0; r < ROWS; ++r) acc[r] = 0.f;
  const float* wr = w + (long)t * 512;
  for (int k = 0; k < 512; ++k) {
    float wv = wr[k];
#pragma unroll
    for (int r = 0; r < ROWS; ++r) acc[r] += wv * tile[r][k];
  }
  float bv = bias[t];
  for (int r = 0; r < ROWS; ++r) out[(r0 + r) * C_ + t] = acc[r] + bv;
}

// ---------- K14: key-split flash attention ----------
__global__ __launch_bounds__(256) void k_attn(const float* __restrict__ qkv,
                                              float* __restrict__ O) {
  __shared__ float smem[8 * 32 * 36];
  __shared__ float cml[8][32][2];
  float* ks = smem;
  float* vs = smem + 2048;
  int bh = blockIdx.x >> 5;
  int qt = blockIdx.x & 31;
  int b = bh >> 3, h = bh & 7;
  int t = threadIdx.x;
  int q = t & 31, kl = t >> 5;
  int qrow = qt * 32 + q;
  const float scale = 0.17677669529663687f;
  float qv[32];
  {
    const float* qp = qkv + ((long)(b * N_ + qrow)) * 768 + h * HD_;
#pragma unroll
    for (int j4 = 0; j4 < 8; ++j4) {
      float4 v = *(const float4*)(qp + j4 * 4);
      qv[j4 * 4 + 0] = v.x * scale;
      qv[j4 * 4 + 1] = v.y * scale;
      qv[j4 * 4 + 2] = v.z * scale;
      qv[j4 * 4 + 3] = v.w * scale;
    }
  }
  float m = -1e30f, l = 0.f;
  float acc[32];
#pragma unroll
  for (int j = 0; j < 32; ++j) acc[j] = 0.f;

  for (int c0 = 0; c0 < N_; c0 += 64) {
    __syncthreads();
    for (int i = t; i < 1024; i += 256) {
      int row = i >> 4, part = (i >> 3) & 1, j4 = i & 7;
      const float* gp = qkv + ((long)(b * N_ + c0 + row)) * 768 + 256 + part * 256 + h * HD_ + j4 * 4;
      float4 v = *(const float4*)gp;
      float* dst = (part ? vs : ks) + row * 32 + j4 * 4;
      *(float4*)dst = v;
    }
    __syncthreads();
    float s[8];
#pragma unroll
    for (int i8 = 0; i8 < 8; ++i8) {
      const float* kr = ks + (kl + i8 * 8) * 32;
      float a = 0.f;
#pragma unroll
      for (int j4 = 0; j4 < 8; ++j4) {
        float4 kv = *(const float4*)(kr + j4 * 4);
        a += qv[j4 * 4 + 0] * kv.x + qv[j4 * 4 + 1] * kv.y +
             qv[j4 * 4 + 2] * kv.z + qv[j4 * 4 + 3] * kv.w;
      }
      s[i8] = a;
    }
    float mx = s[0];
#pragma unroll
    for (int i8 = 1; i8 < 8; ++i8) mx = fmaxf(mx, s[i8]);
    float mn = fmaxf(m, mx);
    float corr = __expf(m - mn);
    float p[8], ps = 0.f;
#pragma unroll
    for (int i8 = 0; i8 < 8; ++i8) { p[i8] = __expf(s[i8] - mn); ps += p[i8]; }
    l = l * corr + ps;
    m = mn;
#pragma unroll
    for (int j = 0; j < 32; ++j) acc[j] *= corr;
#pragma unroll
    for (int i8 = 0; i8 < 8; ++i8) {
      const float* vr = vs + (kl + i8 * 8) * 32;
      float pi = p[i8];
#pragma unroll
      for (int j4 = 0; j4 < 8; ++j4) {
        float4 vv = *(const float4*)(vr + j4 * 4);
        acc[j4 * 4 + 0] += pi * vv.x;
        acc[j4 * 4 + 1] += pi * vv.y;
        acc[j4 * 4 + 2] += pi * vv.z;
        acc[j4 * 4 + 3] += pi * vv.w;
      }
    }
  }
  cml[kl][q][0] = m;
  cml[kl][q][1] = l;
  __syncthreads();
  {
    float* dst = smem + (kl * 32 + q) * 36;
#pragma unroll
    for (int j4 = 0; j4 < 8; ++j4)
      *(float4*)(dst + j4 * 4) = make_float4(acc[j4 * 4 + 0], acc[j4 * 4 + 1],
                                             acc[j4 * 4 + 2], acc[j4 * 4 + 3]);
  }
  __syncthreads();
  int ds = t & 7, q2 = t >> 3;
  float m2 = cml[0][q2][0];
#pragma unroll
  for (int i = 1; i < 8; ++i) m2 = fmaxf(m2, cml[i][q2][0]);
  float lsum = 0.f, f[8];
#pragma unroll
  for (int i = 0; i < 8; ++i) {
    f[i] = __expf(cml[i][q2][0] - m2);
    lsum += f[i] * cml[i][q2][1];
  }
  float inv = 1.f / lsum;
  float o0 = 0.f, o1 = 0.f, o2 = 0.f, o3 = 0.f;
#pragma unroll
  for (int i = 0; i < 8; ++i) {
    const float* src = smem + (i * 32 + q2) * 36 + ds * 4;
    float4 a = *(const float4*)src;
    o0 += f[i] * a.x; o1 += f[i] * a.y; o2 += f[i] * a.z; o3 += f[i] * a.w;
  }
  *(float4*)(O + ((long)(b * N_ + qt * 32 + q2)) * C_ + h * HD_ + ds * 4) =
      make_float4(o0 * inv, o1 * inv, o2 * inv, o3 * inv);
}

// ---------- K17: LN(lgn) + exact GELU -> (B,C,N) layout ----------
__global__ __launch_bounds__(256) void k_lngelu(const float* __restrict__ XO,
                                                const float* __restrict__ lw,
                                                const float* __restrict__ lb,
                                                float* __restrict__ XI) {
  __shared__ float red[8];
  int bn = blockIdx.x;
  int b = bn >> 10, n = bn & 1023;
  int c = threadIdx.x;
  float v = XO[(long)bn * C_ + c];
  float2 s = blockReduce2(v, v * v, red);
  float mu = s.x * (1.f / C_);
  float rs = rsqrtf(s.y * (1.f / C_) - mu * mu + 1e-5f);
  float x = (v - mu) * rs * lw[c] + lb[c];
  float ge = 0.5f * x * (1.f + erff(x * 0.70710678118654752f));
  XI[((long)b * C_ + c) * N_ + n] = ge;
}

// ---------- K18: ln over (H,W) per (b,c), in place, no affine ----------
__global__ __launch_bounds__(256) void k_lnhw(float* __restrict__ XI) {
  __shared__ float red[8];
  long base = (long)blockIdx.x * N_;  // b*C + c
  float a = 0.f, b2 = 0.f;
  for (int i = threadIdx.x; i < N_; i += 256) {
    float v = XI[base + i];
    a += v; b2 += v * v;
  }
  float2 s = blockReduce2(a, b2, red);
  float mu = s.x * (1.f / N_);
  float rs = rsqrtf(s.y * (1.f / N_) - mu * mu + 1e-5f);
  for (int i = threadIdx.x; i < N_; i += 256) XI[base + i] = (XI[base + i] - mu) * rs;
}

// ---------- K19: depthwise 3x3 conv on (B,C,32,32), pad 1 ----------
__global__ __launch_bounds__(256) void k_dwc(const float* __restrict__ XI,
                                             const float* __restrict__ w,
                                             const float* __restrict__ bias,
                                             float* __restrict__ XD) {
  long i = (long)blockIdx.x * 256 + threadIdx.x;  // B*C*1024
  int hw = i & 1023;
  int wq = hw & 31, hq = hw >> 5;
  int c = (int)((i >> 10) & 255);
  const float* p = XI + (i - hw);
  const float* wk = w + c * 9;
  float a = bias[c];
#pragma unroll
  for (int kh = 0; kh < 3; ++kh) {
    int h2 = hq + kh - 1;
    if (h2 < 0 || h2 >= 32) continue;
#pragma unroll
    for (int kw = 0; kw < 3; ++kw) {
      int w2 = wq + kw - 1;
      if (w2 < 0 || w2 >= 32) continue;
      a += wk[kh * 3 + kw] * p[h2 * 32 + w2];
    }
  }
  XD[i] = a;
}

// ---------- K20b: final proj with transposed write (B,N,C)->(B,COUT,N) ----------
__global__ __launch_bounds__(256) void k_rowgemm_t(const float* __restrict__ in,
                                                   const float* __restrict__ w,
                                                   const float* __restrict__ bias,
                                                   float* __restrict__ out) {
  constexpr int ROWS = 8;
  __shared__ float tile[ROWS][257];
  long r0 = (long)blockIdx.x * ROWS;
  for (int i = threadIdx.x; i < ROWS * 256; i += 256) {
    int r = i >> 8, k = i & 255;
    tile[r][k] = in[(r0 + r) * C_ + k];
  }
  __syncthreads();
  int t = threadIdx.x;
  float acc[ROWS];
#pragma unroll
  for (int r = 0; r < ROWS; ++r) acc[r] = 0.f;
  const float* wr = w + (long)t * C_;
  for (int k = 0; k < C_; ++k) {
    float wv = wr[k];
#pragma unroll
    for (int r = 0; r < ROWS; ++r) acc[r] += wv * tile[r][k];
  }
  float bv = bias[t];
  for (int r = 0; r < ROWS; ++r) {
    long row = r0 + r;          // b*N + n
    int b = (int)(row >> 10), n = (int)(row & 1023);
    out[((long)b * C_ + t) * N_ + n] = acc[r] + bv;
  }
}

extern "C" void kernel_launch(void* const* d_in, const int* in_sizes, int n_in,
                              void* d_out, int out_size, void* d_ws, size_t ws_size,
                              hipStream_t stream) {
  const float* x        = (const float*)d_in[0];
  const float* norm_w   = (const float*)d_in[1];
  const float* norm_b   = (const float*)d_in[2];
  const float* skip     = (const float*)d_in[3];
  const float* m_inw    = (const float*)d_in[4];
  const float* m_convw  = (const float*)d_in[5];
  const float* m_convb  = (const float*)d_in[6];
  const float* m_xpw    = (const float*)d_in[7];
  const float* m_dtw    = (const float*)d_in[8];
  const float* m_dtb    = (const float*)d_in[9];
  const float* m_alog   = (const float*)d_in[10];
  const float* m_d      = (const float*)d_in[11];
  const float* m_outw   = (const float*)d_in[12];
  const float* qdw_w    = (const float*)d_in[13];
  const float* qdw_b    = (const float*)d_in[14];
  const float* qpw_w    = (const float*)d_in[15];
  const float* qpw_b    = (const float*)d_in[16];
  const float* rdw_w    = (const float*)d_in[17];
  const float* rdw_b    = (const float*)d_in[18];
  const float* rpw_w    = (const float*)d_in[19];
  const float* rpw_b    = (const float*)d_in[20];
  const float* fdw_w    = (const float*)d_in[21];
  const float* fdw_b    = (const float*)d_in[22];
  const float* fpw_w    = (const float*)d_in[23];
  const float* fpw_b    = (const float*)d_in[24];
  const float* lc_w     = (const float*)d_in[25];
  const float* lc_b     = (const float*)d_in[26];
  const float* attn_inw = (const float*)d_in[27];
  const float* attn_inb = (const float*)d_in[28];
  const float* attn_outw= (const float*)d_in[29];
  const float* attn_outb= (const float*)d_in[30];
  const float* lgn_w    = (const float*)d_in[31];
  const float* lgn_b    = (const float*)d_in[32];
  const float* fc_w     = (const float*)d_in[33];
  const float* fc_b     = (const float*)d_in[34];
  const float* dwc_w    = (const float*)d_in[35];
  const float* dwc_b    = (const float*)d_in[36];
  const float* proj_w   = (const float*)d_in[37];
  const float* proj_b   = (const float*)d_in[38];
  float* out = (float*)d_out;

  float* ws = (float*)d_ws;
  const size_t F = 1048576;  // B*N*C
  float* XS  = ws + 0 * F;
  float* XN  = ws + 1 * F;
  float* U   = ws + 2 * F;
  float* Z   = ws + 4 * F;
  float* DT  = ws + 6 * F;
  float* BM  = ws + 8 * F;
  float* CM  = ws + 8 * F + F / 4;
  float* XMC = ws + 8 * F + F / 2;
  // scan scratch: overlays XMC region (dead until k_outproj)
  float* SC_APROD = ws + 8 * F + F / 2;            // NCH*NSTATE = 524288 = F/2
  float* SC_HEND  = ws + 9 * F;                    // another F/2
  float* G   = ws + 1 * F;
  float* XG  = ws + 2 * F;
  float* RD  = ws + 3 * F;
  float* RB  = ws + 4 * F;
  float* XM2 = ws + 5 * F;
  float* YDW = ws + 6 * F;
  float* XL  = ws + 0 * F;
  float* QKV = ws + 1 * F;
  float* O   = ws + 4 * F;
  float* XGL = ws + 6 * F;
  float* XO  = ws + 7 * F;
  float* XI  = ws + 8 * F;
  float* XD  = ws + 5 * F;
  float* LNF = ws + 0 * F;
  (void)ws_size; (void)in_sizes; (void)n_in; (void)out_size;

  k_ln_t<<<4096, 256, 0, stream>>>(x, norm_w, norm_b, XN, XS);
  k_inproj<<<dim3(64, 4), 256, 0, stream>>>(XN, m_inw, U, Z);
  k_causal<<<2048, 256, 0, stream>>>(U, m_convw, m_convb);
  k_xdbc<<<2048, 128, 0, stream>>>(U, m_xpw, m_dtw, m_dtb, DT, BM, CM);
  // chunked parallel scan
  k_scanA<<<2048, 256, 0, stream>>>(DT, U, BM, m_alog, SC_APROD, SC_HEND);
  k_scanB<<<128, 256, 0, stream>>>(SC_APROD, SC_HEND);
  k_scanC<<<2048, 256, 0, stream>>>(DT, U, BM, CM, m_alog, m_d, SC_APROD);
  k_outproj<<<1024, 256, 0, stream>>>(DT, Z, m_outw, XN, skip, XMC);
  k_gate<<<256, 256, 0, stream>>>(XMC, qdw_w, qdw_b, qpw_w, qpw_b, G);
  k_xg<<<4096, 256, 0, stream>>>(XMC, G, XG);
  k_dw3<<<4096, 256, 0, stream>>>(XG, rdw_w, rdw_b, RD, 256);
  k_pw<256, 16><<<256, 256, 0, stream>>>(RD, rpw_w, rpw_b, XG, RB);
  k_fdw<<<8192, 256, 0, stream>>>(XS, RB, fdw_w, fdw_b, YDW);
  k_fpw<<<512, 256, 0, stream>>>(YDW, fpw_w, fpw_b, XS, XM2);
  k_lc<<<4096, 256, 0, stream>>>(XM2, lc_w, lc_b, XL);
  k_rowgemm<256, 3, 8><<<512, 256, 0, stream>>>(XM2, attn_inw, attn_inb, QKV, 768);
  k_attn<<<1024, 256, 0, stream>>>(QKV, O);
  k_rowgemm<256, 1, 8><<<512, 256, 0, stream>>>(O, attn_outw, attn_outb, XGL, 256);
  k_fc<<<512, 256, 0, stream>>>(XL, XGL, fc_w, fc_b, XO);
  k_lngelu<<<4096, 256, 0, stream>>>(XO, lgn_w, lgn_b, XI);
  k_lnhw<<<1024, 256, 0, stream>>>(XI);
  k_dwc<<<4096, 256, 0, stream>>>(XI, dwc_w, dwc_b, XD);
  k_ln_t<<<4096, 256, 0, stream>>>(XD, norm_w, norm_b, LNF, nullptr);
  k_rowgemm_t<<<512, 256, 0, stream>>>(LNF, proj_w, proj_b, out);
}

// Round 4
// 529.774 us; speedup vs baseline: 2.2014x; 1.1252x over previous
//
#include <hip/hip_runtime.h>
#include <math.h>

// MambaLiteUNet — fp32 graph, round 3: MFMA bf16 flash attention (swapped-QK layout),
// replacing the fp32 VALU attention (114 us, VALU-bound, MfmaUtil 0).

namespace {
constexpr int NB_ = 4, DM_ = 64, DIN_ = 128, DS_ = 16, DTR_ = 4;
constexpr int C_ = 256, N_ = 1024, B_ = 4, HD_ = 32;
constexpr int NCH = 16, LCH = 64;          // scan: 16 time-chunks of 64
constexpr int NSTATE = 16 * 128 * 16;      // nbb * DIN * DS = 32768
}

typedef __attribute__((ext_vector_type(8))) short bf16x8;
typedef __attribute__((ext_vector_type(4))) float f32x4;
typedef __attribute__((ext_vector_type(8))) unsigned short ushort8v;
typedef __attribute__((ext_vector_type(4))) unsigned short ushort4v;

// ---------- helpers ----------
__device__ __forceinline__ unsigned short f2b(float f) {  // fp32 -> bf16 RNE
  unsigned int u = __float_as_uint(f);
  unsigned int r = u + 0x7FFFu + ((u >> 16) & 1u);
  return (unsigned short)(r >> 16);
}

__device__ __forceinline__ float2 blockReduce2(float a, float b, float* red) {
#pragma unroll
  for (int m = 1; m < 64; m <<= 1) {
    a += __shfl_xor(a, m, 64);
    b += __shfl_xor(b, m, 64);
  }
  int w = threadIdx.x >> 6;
  if ((threadIdx.x & 63) == 0) { red[2 * w] = a; red[2 * w + 1] = b; }
  __syncthreads();
  float ra = red[0] + red[2] + red[4] + red[6];
  float rb = red[1] + red[3] + red[5] + red[7];
  return make_float2(ra, rb);
}

__device__ __forceinline__ float siluf(float x) { return x / (1.f + expf(-x)); }
__device__ __forceinline__ float sigmf(float x) { return 1.f / (1.f + expf(-x)); }
__device__ __forceinline__ float softplusf(float x) {
  return fmaxf(x, 0.f) + log1pf(expf(-fabsf(x)));
}

// ---------- K1/K20a: layernorm over C of a (B,C,N) tensor -> (B,N,C); optional raw copy ----------
__global__ __launch_bounds__(256) void k_ln_t(const float* __restrict__ in,
                                              const float* __restrict__ w,
                                              const float* __restrict__ bias,
                                              float* __restrict__ out_ln,
                                              float* __restrict__ out_copy) {
  __shared__ float red[8];
  int bn = blockIdx.x;            // b*N + n
  int b = bn >> 10, n = bn & 1023;
  int c = threadIdx.x;
  float v = in[(b * C_ + c) * N_ + n];
  if (out_copy) out_copy[(long)bn * C_ + c] = v;
  float2 s = blockReduce2(v, v * v, red);
  float mu = s.x * (1.f / C_);
  float var = s.y * (1.f / C_) - mu * mu;
  float rs = rsqrtf(var + 1e-5f);
  out_ln[(long)bn * C_ + c] = (v - mu) * rs * w[c] + bias[c];
}

// ---------- K2: mamba in-proj  xz = xn_block @ inw^T  -> u, z ----------
__global__ __launch_bounds__(256) void k_inproj(const float* __restrict__ xn,
                                                const float* __restrict__ inw,
                                                float* __restrict__ U, float* __restrict__ Z) {
  __shared__ float xrows[4][64];
  int nb = blockIdx.y;
  int j = threadIdx.x;                       // output col 0..255
  const float* wp = inw + ((long)nb * 2 * DIN_ + j) * DM_;
  float wreg[64];
#pragma unroll
  for (int m = 0; m < 64; ++m) wreg[m] = wp[m];
  int row0 = blockIdx.x * 64;                // over B*N = 4096 rows
  for (int r0 = 0; r0 < 64; r0 += 4) {
    __syncthreads();
    {
      int rr = threadIdx.x >> 6, m = threadIdx.x & 63;
      xrows[rr][m] = xn[(long)(row0 + r0 + rr) * C_ + nb * DM_ + m];
    }
    __syncthreads();
    for (int rr = 0; rr < 4; ++rr) {
      float acc = 0.f;
#pragma unroll
      for (int m = 0; m < 64; ++m) acc += xrows[rr][m] * wreg[m];
      long row = (long)nb * (B_ * N_) + row0 + r0 + rr;
      if (j < DIN_) U[row * DIN_ + j] = acc;
      else          Z[row * DIN_ + (j - DIN_)] = acc;
    }
  }
}

// ---------- K3: causal depthwise conv (K=4) + silu, in-place on U ----------
__global__ __launch_bounds__(256) void k_causal(float* __restrict__ U,
                                                const float* __restrict__ cw,
                                                const float* __restrict__ cb) {
  __shared__ float row[N_];
  int blk = blockIdx.x;                      // nbb*DIN + d,  nbb = nb*B+b
  int d = blk & 127, nbb = blk >> 7, nb = nbb >> 2;
  float* base = U + (long)nbb * N_ * DIN_ + d;
  for (int n = threadIdx.x; n < N_; n += 256) row[n] = base[(long)n * DIN_];
  __syncthreads();
  float w0 = cw[(nb * DIN_ + d) * 4 + 0], w1 = cw[(nb * DIN_ + d) * 4 + 1];
  float w2 = cw[(nb * DIN_ + d) * 4 + 2], w3 = cw[(nb * DIN_ + d) * 4 + 3];
  float bias = cb[nb * DIN_ + d];
  for (int n = threadIdx.x; n < N_; n += 256) {
    float acc = bias + w3 * row[n];
    if (n >= 1) acc += w2 * row[n - 1];
    if (n >= 2) acc += w1 * row[n - 2];
    if (n >= 3) acc += w0 * row[n - 3];
    base[(long)n * DIN_] = siluf(acc);
  }
}

// ---------- K4: xdbc = u @ xpw^T ; dt = softplus(xdbc[:4] @ dtw^T + dtb); Bm, Cm ----------
__global__ __launch_bounds__(128) void k_xdbc(const float* __restrict__ U,
                                              const float* __restrict__ xpw,
                                              const float* __restrict__ dtw,
                                              const float* __restrict__ dtb,
                                              float* __restrict__ DT,
                                              float* __restrict__ BMb, float* __restrict__ CMb) {
  __shared__ float wl[36][129];
  __shared__ float urow[128];
  __shared__ float xd[36];
  int t = threadIdx.x;
  int nb = blockIdx.x >> 9;                  // 2048 blocks, 8 rows each; 4096 rows per nb
  for (int i = t; i < 36 * 128; i += 128) wl[i >> 7][i & 127] = xpw[nb * 36 * 128 + i];
  float dw0 = dtw[(nb * DIN_ + t) * 4 + 0], dw1 = dtw[(nb * DIN_ + t) * 4 + 1];
  float dw2 = dtw[(nb * DIN_ + t) * 4 + 2], dw3 = dtw[(nb * DIN_ + t) * 4 + 3];
  float dtbv = dtb[nb * DIN_ + t];
  for (int r8 = 0; r8 < 8; ++r8) {
    long row = (long)blockIdx.x * 8 + r8;
    __syncthreads();
    urow[t] = U[row * DIN_ + t];
    __syncthreads();
    if (t < 36) {
      float a = 0.f;
#pragma unroll 8
      for (int m = 0; m < 128; ++m) a += urow[m] * wl[t][m];
      xd[t] = a;
    }
    __syncthreads();
    if (t < 16) { BMb[row * DS_ + t] = xd[4 + t]; CMb[row * DS_ + t] = xd[20 + t]; }
    float a = dtbv + xd[0] * dw0 + xd[1] * dw1 + xd[2] * dw2 + xd[3] * dw3;
    DT[row * DIN_ + t] = softplusf(a);
  }
}

// ---------- K5a: scan phase A — per-chunk local scan: decay product + end state ----------
__global__ __launch_bounds__(256) void k_scanA(const float* __restrict__ DT,
                                               const float* __restrict__ U,
                                               const float* __restrict__ BMb,
                                               const float* __restrict__ alog,
                                               float* __restrict__ Aprod,
                                               float* __restrict__ Hend) {
  __shared__ float dt_s[LCH][16], u_s[LCH][16], bm_s[LCH][16];
  int blk = blockIdx.x;
  int dch = blk & 7, nbb = (blk >> 3) & 15, chunk = blk >> 7;
  int nb = nbb >> 2;
  int t = threadIdx.x;
  int ch = t >> 4, s = t & 15;
  int d = dch * 16 + ch;
  float A = -expf(alog[(nb * DIN_ + d) * DS_ + s]);
  long base = (long)nbb * N_ + chunk * LCH;
  for (int i = t; i < LCH * 16; i += 256) {
    int tt = i >> 4, cc = i & 15;
    long r = base + tt;
    dt_s[tt][cc] = DT[r * DIN_ + dch * 16 + cc];
    u_s[tt][cc]  = U [r * DIN_ + dch * 16 + cc];
    bm_s[tt][cc] = BMb[r * DS_ + cc];
  }
  __syncthreads();
  float h = 0.f, ap = 1.f;
#pragma unroll 8
  for (int tt = 0; tt < LCH; ++tt) {
    float dtv = dt_s[tt][ch];
    float uv  = u_s[tt][ch];
    float dA = __expf(dtv * A);
    h = dA * h + dtv * uv * bm_s[tt][s];
    ap *= dA;
  }
  int state = ((nbb << 7) + d) * 16 + s;
  Aprod[(long)chunk * NSTATE + state] = ap;
  Hend[(long)chunk * NSTATE + state] = h;
}

// ---------- K5b: scan phase B — carry composition across chunks; Hin written over Aprod ----------
__global__ __launch_bounds__(256) void k_scanB(float* __restrict__ Aprod,
                                               const float* __restrict__ Hend) {
  int state = blockIdx.x * 256 + threadIdx.x;
  float H = 0.f;
#pragma unroll
  for (int c = 0; c < NCH; ++c) {
    long idx = (long)c * NSTATE + state;
    float a = Aprod[idx];
    float e = Hend[idx];
    Aprod[idx] = H;            // Hin for chunk c
    H = e + a * H;
  }
}

// ---------- K5c: scan phase C — re-run chunk from carry, emit y over DT ----------
__global__ __launch_bounds__(256) void k_scanC(float* __restrict__ DT,
                                               const float* __restrict__ U,
                                               const float* __restrict__ BMb,
                                               const float* __restrict__ CMb,
                                               const float* __restrict__ alog,
                                               const float* __restrict__ Dp,
                                               const float* __restrict__ Hin) {
  __shared__ float dt_s[LCH][16], u_s[LCH][16], bm_s[LCH][16], cm_s[LCH][16];
  int blk = blockIdx.x;
  int dch = blk & 7, nbb = (blk >> 3) & 15, chunk = blk >> 7;
  int nb = nbb >> 2;
  int t = threadIdx.x;
  int ch = t >> 4, s = t & 15;
  int d = dch * 16 + ch;
  float A = -expf(alog[(nb * DIN_ + d) * DS_ + s]);
  float Dv = Dp[nb * DIN_ + d];
  long base = (long)nbb * N_ + chunk * LCH;
  for (int i = t; i < LCH * 16; i += 256) {
    int tt = i >> 4, cc = i & 15;
    long r = base + tt;
    dt_s[tt][cc] = DT[r * DIN_ + dch * 16 + cc];
    u_s[tt][cc]  = U [r * DIN_ + dch * 16 + cc];
    bm_s[tt][cc] = BMb[r * DS_ + cc];
    cm_s[tt][cc] = CMb[r * DS_ + cc];
  }
  int state = ((nbb << 7) + d) * 16 + s;
  float h = Hin[(long)chunk * NSTATE + state];
  __syncthreads();
  for (int tt = 0; tt < LCH; ++tt) {
    float dtv = dt_s[tt][ch];
    float uv  = u_s[tt][ch];
    float dA = __expf(dtv * A);
    h = dA * h + dtv * uv * bm_s[tt][s];
    float p = h * cm_s[tt][s];
    p += __shfl_xor(p, 1, 16);
    p += __shfl_xor(p, 2, 16);
    p += __shfl_xor(p, 4, 16);
    p += __shfl_xor(p, 8, 16);
    if (s == 0) DT[(base + tt) * DIN_ + d] = p + Dv * uv;
  }
}

// ---------- K6: y2 = y*silu(z); xm = y2 @ outw^T + skip*xn -> concat layout (B,N,C) ----------
__global__ __launch_bounds__(256) void k_outproj(const float* __restrict__ Y,
                                                 const float* __restrict__ Z,
                                                 const float* __restrict__ outw,
                                                 const float* __restrict__ xn,
                                                 const float* __restrict__ skip,
                                                 float* __restrict__ XMC) {
  __shared__ float wL[64][129];
  __shared__ float y2r[16][128];
  int row0 = blockIdx.x * 16;                // over NB*B*N = 16384 rows
  int nb = row0 >> 12;
  for (int i = threadIdx.x; i < 64 * 128; i += 256) {
    int col = i >> 7, j = i & 127;
    wL[col][j] = outw[nb * DM_ * DIN_ + i];
  }
  for (int i = threadIdx.x; i < 16 * 128; i += 256) {
    int r = i >> 7, j = i & 127;
    long row = (long)row0 + r;
    float z = Z[row * DIN_ + j];
    y2r[r][j] = Y[row * DIN_ + j] * siluf(z);
  }
  __syncthreads();
  float sk = skip[0];
  int col = threadIdx.x & 63;
  int rbase = threadIdx.x >> 6;
  for (int ii = 0; ii < 4; ++ii) {
    int rr = rbase + ii * 4;
    float acc = 0.f;
#pragma unroll 8
    for (int j = 0; j < 128; ++j) acc += y2r[rr][j] * wL[col][j];
    int bn = (row0 + rr) & 4095;
    long oc = (long)bn * C_ + nb * DM_ + col;
    XMC[oc] = acc + sk * xn[oc];
  }
}

// ---------- K7: gate  g = sigmoid(pw(dw(xm_concat^T))), parallel version ----------
__global__ __launch_bounds__(256) void k_gate(const float* __restrict__ XMC,
                                              const float* __restrict__ qdw_w,
                                              const float* __restrict__ qdw_b,
                                              const float* __restrict__ qpw_w,
                                              const float* __restrict__ qpw_b,
                                              float* __restrict__ G) {
  int t = threadIdx.x;
  int gid = (blockIdx.x * 256 + t) >> 4;     // b*N + n
  int cq = t & 3, p = (t >> 2) & 3;
  int b = gid >> 10, n = gid & 1023;
  float a = 0.f;
#pragma unroll
  for (int k = 0; k < 3; ++k) {
    int nn = n + k - 1;
    if (nn < 0 || nn >= N_) continue;
    const float* xr = XMC + ((long)b * N_ + nn) * C_ + p * 64 + cq * 16;
    const float* wr = qdw_w + (p * 64 + cq * 16) * 3 + k;
#pragma unroll
    for (int i = 0; i < 16; ++i) a += xr[i] * wr[i * 3];
  }
  a += __shfl_xor(a, 1, 64);
  a += __shfl_xor(a, 2, 64);
  float q1 = a + qdw_b[p];                   // all cq lanes hold q1(gid, p)
  int lane = t & 63;
  float q1g[4];
#pragma unroll
  for (int pp = 0; pp < 4; ++pp) q1g[pp] = __shfl(q1, (lane & ~12) | (pp << 2), 64);
  int o = p;
  float r = qpw_b[o];
#pragma unroll
  for (int pp = 0; pp < 4; ++pp) r += qpw_w[o * 4 + pp] * q1g[pp];
  if (cq == 0) G[((long)b * 4 + o) * N_ + n] = sigmf(r);
}

// ---------- K8: xg (B,C,N) = g * xm ----------
__global__ __launch_bounds__(256) void k_xg(const float* __restrict__ XMC,
                                            const float* __restrict__ G,
                                            float* __restrict__ XG) {
  long i = (long)blockIdx.x * 256 + threadIdx.x;  // B*C*N
  int n = i & 1023;
  long bc = i >> 10;
  int c = bc & 255, b = (int)(bc >> 8);
  float g = G[((long)b * 4 + (c >> 6)) * N_ + n];
  XG[i] = g * XMC[((long)b * N_ + n) * C_ + c];
}

// ---------- generic 3-tap depthwise conv over n, (B,nchan,N) layout ----------
__global__ __launch_bounds__(256) void k_dw3(const float* __restrict__ in,
                                             const float* __restrict__ w,
                                             const float* __restrict__ bias,
                                             float* __restrict__ out, int nchan) {
  long i = (long)blockIdx.x * 256 + threadIdx.x;
  if (i >= (long)B_ * nchan * N_) return;
  int n = i & 1023;
  int c = (int)((i >> 10) % nchan);
  const float* r = in + (i - n);
  float a = bias[c] + w[c * 3 + 1] * r[n];
  if (n > 0)      a += w[c * 3 + 0] * r[n - 1];
  if (n < N_ - 1) a += w[c * 3 + 2] * r[n + 1];
  out[i] = a;
}

// ---------- K9b: pointwise conv (GEMM) (B,CIN,N)->(B,256,N) with (B,C,N) residual ----------
template <int CIN, int NT>
__global__ __launch_bounds__(256) void k_pw(const float* __restrict__ in,
                                            const float* __restrict__ w,
                                            const float* __restrict__ bias,
                                            const float* __restrict__ resid,
                                            float* __restrict__ out) {
  __shared__ float tile[CIN][NT + 1];
  int nt = N_ / NT;
  int b = blockIdx.x / nt, n0 = (blockIdx.x % nt) * NT;
  for (int r = threadIdx.x; r < CIN; r += 256)
    for (int j = 0; j < NT; ++j)
      tile[r][j] = in[((long)b * CIN + r) * N_ + n0 + j];
  __syncthreads();
  int c = threadIdx.x;
  float acc[NT];
#pragma unroll
  for (int j = 0; j < NT; ++j) acc[j] = 0.f;
  const float* wr = w + (long)c * CIN;
  for (int r = 0; r < CIN; ++r) {
    float wv = wr[r];
#pragma unroll
    for (int j = 0; j < NT; ++j) acc[j] += wv * tile[r][j];
  }
  float bv = bias[c];
  for (int j = 0; j < NT; ++j) {
    long o = ((long)b * C_ + c) * N_ + n0 + j;
    float v = acc[j] + bv;
    if (resid) v += resid[o];
    out[o] = v;
  }
}

// ---------- K10: depthwise conv over virtual cat = [xs^T ; R] (B,512,N) ----------
__global__ __launch_bounds__(256) void k_fdw(const float* __restrict__ XS,
                                             const float* __restrict__ RB,
                                             const float* __restrict__ w,
                                             const float* __restrict__ bias,
                                             float* __restrict__ YDW) {
  long i = (long)blockIdx.x * 256 + threadIdx.x;  // B*512*N
  int n = i & 1023;
  long bc = i >> 10;
  int cc = bc & 511, b = (int)(bc >> 9);
  float v0 = 0.f, v1, v2 = 0.f;
  if (cc < C_) {
    const float* p = XS + (long)b * N_ * C_ + cc;
    v1 = p[(long)n * C_];
    if (n > 0)      v0 = p[(long)(n - 1) * C_];
    if (n < N_ - 1) v2 = p[(long)(n + 1) * C_];
  } else {
    const float* p = RB + ((long)b * C_ + (cc - C_)) * N_;
    v1 = p[n];
    if (n > 0)      v0 = p[n - 1];
    if (n < N_ - 1) v2 = p[n + 1];
  }
  YDW[i] = bias[cc] + w[cc * 3] * v0 + w[cc * 3 + 1] * v1 + w[cc * 3 + 2] * v2;
}

// ---------- K11: fpw pointwise (B,512,N)->(B,N,C) + xs residual ----------
__global__ __launch_bounds__(256) void k_fpw(const float* __restrict__ YDW,
                                             const float* __restrict__ w,
                                             const float* __restrict__ bias,
                                             const float* __restrict__ XS,
                                             float* __restrict__ XM2) {
  __shared__ float tile[512][9];
  constexpr int NT = 8;
  int nt = N_ / NT;
  int b = blockIdx.x / nt, n0 = (blockIdx.x % nt) * NT;
  for (int i = threadIdx.x; i < 512 * NT; i += 256) {
    int r = i >> 3, j = i & 7;
    tile[r][j] = YDW[((long)b * 512 + r) * N_ + n0 + j];
  }
  __syncthreads();
  int c = threadIdx.x;
  float acc[NT];
#pragma unroll
  for (int j = 0; j < NT; ++j) acc[j] = 0.f;
  const float* wr = w + (long)c * 512;
  for (int r = 0; r < 512; ++r) {
    float wv = wr[r];
#pragma unroll
    for (int j = 0; j < NT; ++j) acc[j] += wv * tile[r][j];
  }
  float bv = bias[c];
  for (int j = 0; j < NT; ++j) {
    long o = ((long)b * N_ + n0 + j) * C_ + c;
    XM2[o] = acc[j] + bv + XS[o];
  }
}

// ---------- K12: x_local depthwise over n in (B,N,C) layout ----------
__global__ __launch_bounds__(256) void k_lc(const float* __restrict__ XM2,
                                            const float* __restrict__ w,
                                            const float* __restrict__ bias,
                                            float* __restrict__ XL) {
  long i = (long)blockIdx.x * 256 + threadIdx.x;  // B*N*C, c fastest
  int c = i & 255;
  long bn = i >> 8;
  int n = bn & 1023, b = (int)(bn >> 10);
  const float* p = XM2 + (long)b * N_ * C_ + c;
  float a = bias[c] + w[c * 3 + 1] * p[(long)n * C_];
  if (n > 0)      a += w[c * 3 + 0] * p[(long)(n - 1) * C_];
  if (n < N_ - 1) a += w[c * 3 + 2] * p[(long)(n + 1) * C_];
  XL[i] = a;
}

// ---------- row GEMM: out[r, c] = in[r,:KD] . W[c,:KD] + bias  (rows = B*N) ----------
template <int KD, int NCOL, int ROWS>
__global__ __launch_bounds__(256) void k_rowgemm(const float* __restrict__ in,
                                                 const float* __restrict__ w,
                                                 const float* __restrict__ bias,
                                                 float* __restrict__ out, int Cout) {
  __shared__ float tile[ROWS][KD + 1];
  long r0 = (long)blockIdx.x * ROWS;
  for (int i = threadIdx.x; i < ROWS * KD; i += 256) {
    int r = i / KD, k = i % KD;
    tile[r][k] = in[(r0 + r) * KD + k];
  }
  __syncthreads();
  int t = threadIdx.x;
  float acc[NCOL][ROWS];
#pragma unroll
  for (int q = 0; q < NCOL; ++q)
#pragma unroll
    for (int r = 0; r < ROWS; ++r) acc[q][r] = 0.f;
  for (int k = 0; k < KD; ++k) {
    float xv[ROWS];
#pragma unroll
    for (int r = 0; r < ROWS; ++r) xv[r] = tile[r][k];
#pragma unroll
    for (int q = 0; q < NCOL; ++q) {
      float wv = w[(long)(t + 256 * q) * KD + k];
#pragma unroll
      for (int r = 0; r < ROWS; ++r) acc[q][r] += wv * xv[r];
    }
  }
  for (int q = 0; q < NCOL; ++q) {
    int c = t + 256 * q;
    float bv = bias[c];
    for (int r = 0; r < ROWS; ++r) out[(r0 + r) * Cout + c] = acc[q][r] + bv;
  }
}

// ---------- K16: fc over concat[XL, XGL] ----------
__global__ __launch_bounds__(256) void k_fc(const float* __restrict__ XL,
                                            const float* __restrict__ XGL,
                                            const float* __restrict__ w,
                                            const float* __restrict__ bias,
                                            float* __restrict__ out) {
  constexpr int ROWS = 8;
  __shared__ float tile[ROWS][513];
  long r0 = (long)blockIdx.x * ROWS;
  for (int i = threadIdx.x; i < ROWS * 256; i += 256) {
    int r = i >> 8, k = i & 255;
    tile[r][k] = XL[(r0 + r) * C_ + k];
    tile[r][256 + k] = XGL[(r0 + r) * C_ + k];
  }
  __syncthreads();
  int t = threadIdx.x;
  float acc[ROWS];
#pragma unroll
  for (int r = 0; r < ROWS; ++r) acc[r] = 0.f;
  const float* wr = w + (long)t * 512;
  for (int k = 0; k < 512; ++k) {
    float wv = wr[k];
#pragma unroll
    for (int r = 0; r < ROWS; ++r) acc[r] += wv * tile[r][k];
  }
  float bv = bias[t];
  for (int r = 0; r < ROWS; ++r) out[(r0 + r) * C_ + t] = acc[r] + bv;
}

// ---------- K14: MFMA bf16 flash attention ----------
// block = 256 thr = 4 waves; each wave: 16 q-rows; block: 64 q-rows of one (b,h).
// grid = B*NH*(N/64) = 512. Swapped-QK layout: S^T = mfma(K,Q), O^T = mfma(V^T,P).
__global__ __launch_bounds__(256) void k_attn_mfma(const float* __restrict__ qkv,
                                                   float* __restrict__ O) {
  __shared__ unsigned short K_lds[64 * 40];       // [64 keys][32+8 dims]
  __shared__ unsigned short Vt_lds[32 * 72];      // [32 dims][64+8 keys]
  __shared__ unsigned short P_lds[4][16 * 72];    // per wave: [16 q][64+8 keys]
  int bx = blockIdx.x;
  int bh = bx >> 4, qt = bx & 15;
  int b = bh >> 3, h = bh & 7;
  int t = threadIdx.x;
  int w = t >> 6, lane = t & 63;
  int g = lane >> 4, ql = lane & 15;
  const float qscale = 0.17677669529663687f * 1.44269504088896341f;  // 1/sqrt(32) * log2(e)

  bf16x8 q_frag;  // B-operand of S^T: lane holds Q[q=ql][dim g*8..g*8+7]
  {
    const float* qp = qkv + ((long)(b * N_ + qt * 64 + w * 16 + ql)) * 768 + h * HD_ + g * 8;
#pragma unroll
    for (int i = 0; i < 8; ++i) q_frag[i] = (short)f2b(qp[i] * qscale);
  }
  float m = -1e30f, l = 0.f;
  f32x4 o_acc[2];
  const f32x4 zf = {0.f, 0.f, 0.f, 0.f};
  o_acc[0] = zf; o_acc[1] = zf;

  for (int kt = 0; kt < 16; ++kt) {
    __syncthreads();
    {
      // stage K [64][32] and V^T [32][64] as bf16; thread t: key t>>2, dims (t&3)*8..+7
      int kr = t >> 2, d0 = (t & 3) * 8;
      const float* gp = qkv + ((long)(b * N_ + kt * 64 + kr)) * 768 + 256 + h * HD_ + d0;
      ushort8v kv;
#pragma unroll
      for (int i = 0; i < 8; ++i) kv[i] = f2b(gp[i]);
      *(ushort8v*)&K_lds[kr * 40 + d0] = kv;
      const float* vp = gp + 256;
#pragma unroll
      for (int i = 0; i < 8; ++i) Vt_lds[(d0 + i) * 72 + kr] = f2b(vp[i]);
    }
    __syncthreads();
    // S^T[key][q] per 16-key subtile: one MFMA each (K=32 = full head dim)
    f32x4 s_frag[4];
#pragma unroll
    for (int s = 0; s < 4; ++s) {
      bf16x8 k_frag = *(const bf16x8*)&K_lds[(s * 16 + ql) * 40 + g * 8];
      s_frag[s] = __builtin_amdgcn_mfma_f32_16x16x32_bf16(k_frag, q_frag, zf, 0, 0, 0);
    }
    // online softmax (exp2 domain); lane owns q=ql, keys {s*16 + g*4 + r}
    float sv[16];
#pragma unroll
    for (int s = 0; s < 4; ++s)
#pragma unroll
      for (int r = 0; r < 4; ++r) sv[s * 4 + r] = s_frag[s][r];
    float tmax = sv[0];
#pragma unroll
    for (int i = 1; i < 16; ++i) tmax = fmaxf(tmax, sv[i]);
    tmax = fmaxf(tmax, __shfl_xor(tmax, 16));
    tmax = fmaxf(tmax, __shfl_xor(tmax, 32));
    float mn = fmaxf(m, tmax);
    float corr = exp2f(m - mn);
    float psum = 0.f;
    unsigned short pb[16];
#pragma unroll
    for (int i = 0; i < 16; ++i) {
      float p = exp2f(sv[i] - mn);
      psum += p;
      pb[i] = f2b(p);
    }
    psum += __shfl_xor(psum, 16);
    psum += __shfl_xor(psum, 32);
    l = l * corr + psum;
    m = mn;
#pragma unroll
    for (int mt = 0; mt < 2; ++mt)
#pragma unroll
      for (int r = 0; r < 4; ++r) o_acc[mt][r] *= corr;
    // P -> LDS (bf16), layout [q][key], keys s*16+g*4..+3 contiguous
#pragma unroll
    for (int s = 0; s < 4; ++s) {
      ushort4v p4 = {pb[s * 4], pb[s * 4 + 1], pb[s * 4 + 2], pb[s * 4 + 3]};
      *(ushort4v*)&P_lds[w][ql * 72 + s * 16 + g * 4] = p4;
    }
    // O^T += V^T @ P : 2 dim-tiles x 2 key-chunks
#pragma unroll
    for (int c = 0; c < 2; ++c) {
      bf16x8 p_frag = *(const bf16x8*)&P_lds[w][ql * 72 + c * 32 + g * 8];
#pragma unroll
      for (int mt = 0; mt < 2; ++mt) {
        bf16x8 v_frag = *(const bf16x8*)&Vt_lds[(mt * 16 + ql) * 72 + c * 32 + g * 8];
        o_acc[mt] = __builtin_amdgcn_mfma_f32_16x16x32_bf16(v_frag, p_frag, o_acc[mt], 0, 0, 0);
      }
    }
  }
  float inv = 1.f / l;
  float* op = O + ((long)(b * N_ + qt * 64 + w * 16 + ql)) * C_ + h * HD_;
#pragma unroll
  for (int mt = 0; mt < 2; ++mt) {
    float4 o4 = make_float4(o_acc[mt][0] * inv, o_acc[mt][1] * inv,
                            o_acc[mt][2] * inv, o_acc[mt][3] * inv);
    *(float4*)(op + mt * 16 + g * 4) = o4;
  }
}

// ---------- K17: LN(lgn) + exact GELU -> (B,C,N) layout ----------
__global__ __launch_bounds__(256) void k_lngelu(const float* __restrict__ XO,
                                                const float* __restrict__ lw,
                                                const float* __restrict__ lb,
                                                float* __restrict__ XI) {
  __shared__ float red[8];
  int bn = blockIdx.x;
  int b = bn >> 10, n = bn & 1023;
  int c = threadIdx.x;
  float v = XO[(long)bn * C_ + c];
  float2 s = blockReduce2(v, v * v, red);
  float mu = s.x * (1.f / C_);
  float rs = rsqrtf(s.y * (1.f / C_) - mu * mu + 1e-5f);
  float x = (v - mu) * rs * lw[c] + lb[c];
  float ge = 0.5f * x * (1.f + erff(x * 0.70710678118654752f));
  XI[((long)b * C_ + c) * N_ + n] = ge;
}

// ---------- K18: ln over (H,W) per (b,c), in place, no affine ----------
__global__ __launch_bounds__(256) void k_lnhw(float* __restrict__ XI) {
  __shared__ float red[8];
  long base = (long)blockIdx.x * N_;  // b*C + c
  float a = 0.f, b2 = 0.f;
  for (int i = threadIdx.x; i < N_; i += 256) {
    float v = XI[base + i];
    a += v; b2 += v * v;
  }
  float2 s = blockReduce2(a, b2, red);
  float mu = s.x * (1.f / N_);
  float rs = rsqrtf(s.y * (1.f / N_) - mu * mu + 1e-5f);
  for (int i = threadIdx.x; i < N_; i += 256) XI[base + i] = (XI[base + i] - mu) * rs;
}

// ---------- K19: depthwise 3x3 conv on (B,C,32,32), pad 1 ----------
__global__ __launch_bounds__(256) void k_dwc(const float* __restrict__ XI,
                                             const float* __restrict__ w,
                                             const float* __restrict__ bias,
                                             float* __restrict__ XD) {
  long i = (long)blockIdx.x * 256 + threadIdx.x;  // B*C*1024
  int hw = i & 1023;
  int wq = hw & 31, hq = hw >> 5;
  int c = (int)((i >> 10) & 255);
  const float* p = XI + (i - hw);
  const float* wk = w + c * 9;
  float a = bias[c];
#pragma unroll
  for (int kh = 0; kh < 3; ++kh) {
    int h2 = hq + kh - 1;
    if (h2 < 0 || h2 >= 32) continue;
#pragma unroll
    for (int kw = 0; kw < 3; ++kw) {
      int w2 = wq + kw - 1;
      if (w2 < 0 || w2 >= 32) continue;
      a += wk[kh * 3 + kw] * p[h2 * 32 + w2];
    }
  }
  XD[i] = a;
}

// ---------- K20b: final proj with transposed write (B,N,C)->(B,COUT,N) ----------
__global__ __launch_bounds__(256) void k_rowgemm_t(const float* __restrict__ in,
                                                   const float* __restrict__ w,
                                                   const float* __restrict__ bias,
                                                   float* __restrict__ out) {
  constexpr int ROWS = 8;
  __shared__ float tile[ROWS][257];
  long r0 = (long)blockIdx.x * ROWS;
  for (int i = threadIdx.x; i < ROWS * 256; i += 256) {
    int r = i >> 8, k = i & 255;
    tile[r][k] = in[(r0 + r) * C_ + k];
  }
  __syncthreads();
  int t = threadIdx.x;
  float acc[ROWS];
#pragma unroll
  for (int r = 0; r < ROWS; ++r) acc[r] = 0.f;
  const float* wr = w + (long)t * C_;
  for (int k = 0; k < C_; ++k) {
    float wv = wr[k];
#pragma unroll
    for (int r = 0; r < ROWS; ++r) acc[r] += wv * tile[r][k];
  }
  float bv = bias[t];
  for (int r = 0; r < ROWS; ++r) {
    long row = r0 + r;          // b*N + n
    int b = (int)(row >> 10), n = (int)(row & 1023);
    out[((long)b * C_ + t) * N_ + n] = acc[r] + bv;
  }
}

extern "C" void kernel_launch(void* const* d_in, const int* in_sizes, int n_in,
                              void* d_out, int out_size, void* d_ws, size_t ws_size,
                              hipStream_t stream) {
  const float* x        = (const float*)d_in[0];
  const float* norm_w   = (const float*)d_in[1];
  const float* norm_b   = (const float*)d_in[2];
  const float* skip     = (const float*)d_in[3];
  const float* m_inw    = (const float*)d_in[4];
  const float* m_convw  = (const float*)d_in[5];
  const float* m_convb  = (const float*)d_in[6];
  const float* m_xpw    = (const float*)d_in[7];
  const float* m_dtw    = (const float*)d_in[8];
  const float* m_dtb    = (const float*)d_in[9];
  const float* m_alog   = (const float*)d_in[10];
  const float* m_d      = (const float*)d_in[11];
  const float* m_outw   = (const float*)d_in[12];
  const float* qdw_w    = (const float*)d_in[13];
  const float* qdw_b    = (const float*)d_in[14];
  const float* qpw_w    = (const float*)d_in[15];
  const float* qpw_b    = (const float*)d_in[16];
  const float* rdw_w    = (const float*)d_in[17];
  const float* rdw_b    = (const float*)d_in[18];
  const float* rpw_w    = (const float*)d_in[19];
  const float* rpw_b    = (const float*)d_in[20];
  const float* fdw_w    = (const float*)d_in[21];
  const float* fdw_b    = (const float*)d_in[22];
  const float* fpw_w    = (const float*)d_in[23];
  const float* fpw_b    = (const float*)d_in[24];
  const float* lc_w     = (const float*)d_in[25];
  const float* lc_b     = (const float*)d_in[26];
  const float* attn_inw = (const float*)d_in[27];
  const float* attn_inb = (const float*)d_in[28];
  const float* attn_outw= (const float*)d_in[29];
  const float* attn_outb= (const float*)d_in[30];
  const float* lgn_w    = (const float*)d_in[31];
  const float* lgn_b    = (const float*)d_in[32];
  const float* fc_w     = (const float*)d_in[33];
  const float* fc_b     = (const float*)d_in[34];
  const float* dwc_w    = (const float*)d_in[35];
  const float* dwc_b    = (const float*)d_in[36];
  const float* proj_w   = (const float*)d_in[37];
  const float* proj_b   = (const float*)d_in[38];
  float* out = (float*)d_out;

  float* ws = (float*)d_ws;
  const size_t F = 1048576;  // B*N*C
  float* XS  = ws + 0 * F;
  float* XN  = ws + 1 * F;
  float* U   = ws + 2 * F;
  float* Z   = ws + 4 * F;
  float* DT  = ws + 6 * F;
  float* BM  = ws + 8 * F;
  float* CM  = ws + 8 * F + F / 4;
  float* XMC = ws + 8 * F + F / 2;
  float* SC_APROD = ws + 8 * F + F / 2;            // scan scratch (XMC region, dead then)
  float* SC_HEND  = ws + 9 * F;
  float* G   = ws + 1 * F;
  float* XG  = ws + 2 * F;
  float* RD  = ws + 3 * F;
  float* RB  = ws + 4 * F;
  float* XM2 = ws + 5 * F;
  float* YDW = ws + 6 * F;
  float* XL  = ws + 0 * F;
  float* QKV = ws + 1 * F;
  float* O   = ws + 4 * F;
  float* XGL = ws + 6 * F;
  float* XO  = ws + 7 * F;
  float* XI  = ws + 8 * F;
  float* XD  = ws + 5 * F;
  float* LNF = ws + 0 * F;
  (void)ws_size; (void)in_sizes; (void)n_in; (void)out_size;

  k_ln_t<<<4096, 256, 0, stream>>>(x, norm_w, norm_b, XN, XS);
  k_inproj<<<dim3(64, 4), 256, 0, stream>>>(XN, m_inw, U, Z);
  k_causal<<<2048, 256, 0, stream>>>(U, m_convw, m_convb);
  k_xdbc<<<2048, 128, 0, stream>>>(U, m_xpw, m_dtw, m_dtb, DT, BM, CM);
  k_scanA<<<2048, 256, 0, stream>>>(DT, U, BM, m_alog, SC_APROD, SC_HEND);
  k_scanB<<<128, 256, 0, stream>>>(SC_APROD, SC_HEND);
  k_scanC<<<2048, 256, 0, stream>>>(DT, U, BM, CM, m_alog, m_d, SC_APROD);
  k_outproj<<<1024, 256, 0, stream>>>(DT, Z, m_outw, XN, skip, XMC);
  k_gate<<<256, 256, 0, stream>>>(XMC, qdw_w, qdw_b, qpw_w, qpw_b, G);
  k_xg<<<4096, 256, 0, stream>>>(XMC, G, XG);
  k_dw3<<<4096, 256, 0, stream>>>(XG, rdw_w, rdw_b, RD, 256);
  k_pw<256, 16><<<256, 256, 0, stream>>>(RD, rpw_w, rpw_b, XG, RB);
  k_fdw<<<8192, 256, 0, stream>>>(XS, RB, fdw_w, fdw_b, YDW);
  k_fpw<<<512, 256, 0, stream>>>(YDW, fpw_w, fpw_b, XS, XM2);
  k_lc<<<4096, 256, 0, stream>>>(XM2, lc_w, lc_b, XL);
  k_rowgemm<256, 3, 8><<<512, 256, 0, stream>>>(XM2, attn_inw, attn_inb, QKV, 768);
  k_attn_mfma<<<512, 256, 0, stream>>>(QKV, O);
  k_rowgemm<256, 1, 8><<<512, 256, 0, stream>>>(O, attn_outw, attn_outb, XGL, 256);
  k_fc<<<512, 256, 0, stream>>>(XL, XGL, fc_w, fc_b, XO);
  k_lngelu<<<4096, 256, 0, stream>>>(XO, lgn_w, lgn_b, XI);
  k_lnhw<<<1024, 256, 0, stream>>>(XI);
  k_dwc<<<4096, 256, 0, stream>>>(XI, dwc_w, dwc_b, XD);
  k_ln_t<<<4096, 256, 0, stream>>>(XD, norm_w, norm_b, LNF, nullptr);
  k_rowgemm_t<<<512, 256, 0, stream>>>(LNF, proj_w, proj_b, out);
}

// Round 5
// 345.458 us; speedup vs baseline: 3.3759x; 1.5335x over previous
//
#include <hip/hip_runtime.h>
#include <math.h>

// MambaLiteUNet — round 4: MFMA bf16 GEMMs for all six projection GEMMs
// (QKV, attn-out, fc, final-proj row-major; pw/fpw channel-major with fused residuals).

namespace {
constexpr int NB_ = 4, DM_ = 64, DIN_ = 128, DS_ = 16, DTR_ = 4;
constexpr int C_ = 256, N_ = 1024, B_ = 4, HD_ = 32;
constexpr int NCH = 16, LCH = 64;          // scan: 16 time-chunks of 64
constexpr int NSTATE = 16 * 128 * 16;      // nbb * DIN * DS = 32768
}

typedef __attribute__((ext_vector_type(8))) short bf16x8;
typedef __attribute__((ext_vector_type(4))) float f32x4;
typedef __attribute__((ext_vector_type(8))) unsigned short ushort8v;
typedef __attribute__((ext_vector_type(4))) unsigned short ushort4v;

// ---------- helpers ----------
__device__ __forceinline__ unsigned short f2b(float f) {  // fp32 -> bf16 RNE
  unsigned int u = __float_as_uint(f);
  unsigned int r = u + 0x7FFFu + ((u >> 16) & 1u);
  return (unsigned short)(r >> 16);
}

__device__ __forceinline__ float2 blockReduce2(float a, float b, float* red) {
#pragma unroll
  for (int m = 1; m < 64; m <<= 1) {
    a += __shfl_xor(a, m, 64);
    b += __shfl_xor(b, m, 64);
  }
  int w = threadIdx.x >> 6;
  if ((threadIdx.x & 63) == 0) { red[2 * w] = a; red[2 * w + 1] = b; }
  __syncthreads();
  float ra = red[0] + red[2] + red[4] + red[6];
  float rb = red[1] + red[3] + red[5] + red[7];
  return make_float2(ra, rb);
}

__device__ __forceinline__ float siluf(float x) { return x / (1.f + expf(-x)); }
__device__ __forceinline__ float sigmf(float x) { return 1.f / (1.f + expf(-x)); }
__device__ __forceinline__ float softplusf(float x) {
  return fmaxf(x, 0.f) + log1pf(expf(-fabsf(x)));
}

// ---------- K1/K20a: layernorm over C of a (B,C,N) tensor -> (B,N,C); optional raw copy ----------
__global__ __launch_bounds__(256) void k_ln_t(const float* __restrict__ in,
                                              const float* __restrict__ w,
                                              const float* __restrict__ bias,
                                              float* __restrict__ out_ln,
                                              float* __restrict__ out_copy) {
  __shared__ float red[8];
  int bn = blockIdx.x;            // b*N + n
  int b = bn >> 10, n = bn & 1023;
  int c = threadIdx.x;
  float v = in[(b * C_ + c) * N_ + n];
  if (out_copy) out_copy[(long)bn * C_ + c] = v;
  float2 s = blockReduce2(v, v * v, red);
  float mu = s.x * (1.f / C_);
  float var = s.y * (1.f / C_) - mu * mu;
  float rs = rsqrtf(var + 1e-5f);
  out_ln[(long)bn * C_ + c] = (v - mu) * rs * w[c] + bias[c];
}

// ---------- K2: mamba in-proj  xz = xn_block @ inw^T  -> u, z ----------
__global__ __launch_bounds__(256) void k_inproj(const float* __restrict__ xn,
                                                const float* __restrict__ inw,
                                                float* __restrict__ U, float* __restrict__ Z) {
  __shared__ float xrows[4][64];
  int nb = blockIdx.y;
  int j = threadIdx.x;                       // output col 0..255
  const float* wp = inw + ((long)nb * 2 * DIN_ + j) * DM_;
  float wreg[64];
#pragma unroll
  for (int m = 0; m < 64; ++m) wreg[m] = wp[m];
  int row0 = blockIdx.x * 64;                // over B*N = 4096 rows
  for (int r0 = 0; r0 < 64; r0 += 4) {
    __syncthreads();
    {
      int rr = threadIdx.x >> 6, m = threadIdx.x & 63;
      xrows[rr][m] = xn[(long)(row0 + r0 + rr) * C_ + nb * DM_ + m];
    }
    __syncthreads();
    for (int rr = 0; rr < 4; ++rr) {
      float acc = 0.f;
#pragma unroll
      for (int m = 0; m < 64; ++m) acc += xrows[rr][m] * wreg[m];
      long row = (long)nb * (B_ * N_) + row0 + r0 + rr;
      if (j < DIN_) U[row * DIN_ + j] = acc;
      else          Z[row * DIN_ + (j - DIN_)] = acc;
    }
  }
}

// ---------- K3: causal depthwise conv (K=4) + silu, in-place on U ----------
__global__ __launch_bounds__(256) void k_causal(float* __restrict__ U,
                                                const float* __restrict__ cw,
                                                const float* __restrict__ cb) {
  __shared__ float row[N_];
  int blk = blockIdx.x;                      // nbb*DIN + d,  nbb = nb*B+b
  int d = blk & 127, nbb = blk >> 7, nb = nbb >> 2;
  float* base = U + (long)nbb * N_ * DIN_ + d;
  for (int n = threadIdx.x; n < N_; n += 256) row[n] = base[(long)n * DIN_];
  __syncthreads();
  float w0 = cw[(nb * DIN_ + d) * 4 + 0], w1 = cw[(nb * DIN_ + d) * 4 + 1];
  float w2 = cw[(nb * DIN_ + d) * 4 + 2], w3 = cw[(nb * DIN_ + d) * 4 + 3];
  float bias = cb[nb * DIN_ + d];
  for (int n = threadIdx.x; n < N_; n += 256) {
    float acc = bias + w3 * row[n];
    if (n >= 1) acc += w2 * row[n - 1];
    if (n >= 2) acc += w1 * row[n - 2];
    if (n >= 3) acc += w0 * row[n - 3];
    base[(long)n * DIN_] = siluf(acc);
  }
}

// ---------- K4: xdbc = u @ xpw^T ; dt = softplus(xdbc[:4] @ dtw^T + dtb); Bm, Cm ----------
__global__ __launch_bounds__(128) void k_xdbc(const float* __restrict__ U,
                                              const float* __restrict__ xpw,
                                              const float* __restrict__ dtw,
                                              const float* __restrict__ dtb,
                                              float* __restrict__ DT,
                                              float* __restrict__ BMb, float* __restrict__ CMb) {
  __shared__ float wl[36][129];
  __shared__ float urow[128];
  __shared__ float xd[36];
  int t = threadIdx.x;
  int nb = blockIdx.x >> 9;                  // 2048 blocks, 8 rows each; 4096 rows per nb
  for (int i = t; i < 36 * 128; i += 128) wl[i >> 7][i & 127] = xpw[nb * 36 * 128 + i];
  float dw0 = dtw[(nb * DIN_ + t) * 4 + 0], dw1 = dtw[(nb * DIN_ + t) * 4 + 1];
  float dw2 = dtw[(nb * DIN_ + t) * 4 + 2], dw3 = dtw[(nb * DIN_ + t) * 4 + 3];
  float dtbv = dtb[nb * DIN_ + t];
  for (int r8 = 0; r8 < 8; ++r8) {
    long row = (long)blockIdx.x * 8 + r8;
    __syncthreads();
    urow[t] = U[row * DIN_ + t];
    __syncthreads();
    if (t < 36) {
      float a = 0.f;
#pragma unroll 8
      for (int m = 0; m < 128; ++m) a += urow[m] * wl[t][m];
      xd[t] = a;
    }
    __syncthreads();
    if (t < 16) { BMb[row * DS_ + t] = xd[4 + t]; CMb[row * DS_ + t] = xd[20 + t]; }
    float a = dtbv + xd[0] * dw0 + xd[1] * dw1 + xd[2] * dw2 + xd[3] * dw3;
    DT[row * DIN_ + t] = softplusf(a);
  }
}

// ---------- K5a: scan phase A ----------
__global__ __launch_bounds__(256) void k_scanA(const float* __restrict__ DT,
                                               const float* __restrict__ U,
                                               const float* __restrict__ BMb,
                                               const float* __restrict__ alog,
                                               float* __restrict__ Aprod,
                                               float* __restrict__ Hend) {
  __shared__ float dt_s[LCH][16], u_s[LCH][16], bm_s[LCH][16];
  int blk = blockIdx.x;
  int dch = blk & 7, nbb = (blk >> 3) & 15, chunk = blk >> 7;
  int nb = nbb >> 2;
  int t = threadIdx.x;
  int ch = t >> 4, s = t & 15;
  int d = dch * 16 + ch;
  float A = -expf(alog[(nb * DIN_ + d) * DS_ + s]);
  long base = (long)nbb * N_ + chunk * LCH;
  for (int i = t; i < LCH * 16; i += 256) {
    int tt = i >> 4, cc = i & 15;
    long r = base + tt;
    dt_s[tt][cc] = DT[r * DIN_ + dch * 16 + cc];
    u_s[tt][cc]  = U [r * DIN_ + dch * 16 + cc];
    bm_s[tt][cc] = BMb[r * DS_ + cc];
  }
  __syncthreads();
  float h = 0.f, ap = 1.f;
#pragma unroll 8
  for (int tt = 0; tt < LCH; ++tt) {
    float dtv = dt_s[tt][ch];
    float uv  = u_s[tt][ch];
    float dA = __expf(dtv * A);
    h = dA * h + dtv * uv * bm_s[tt][s];
    ap *= dA;
  }
  int state = ((nbb << 7) + d) * 16 + s;
  Aprod[(long)chunk * NSTATE + state] = ap;
  Hend[(long)chunk * NSTATE + state] = h;
}

// ---------- K5b: scan phase B ----------
__global__ __launch_bounds__(256) void k_scanB(float* __restrict__ Aprod,
                                               const float* __restrict__ Hend) {
  int state = blockIdx.x * 256 + threadIdx.x;
  float H = 0.f;
#pragma unroll
  for (int c = 0; c < NCH; ++c) {
    long idx = (long)c * NSTATE + state;
    float a = Aprod[idx];
    float e = Hend[idx];
    Aprod[idx] = H;            // Hin for chunk c
    H = e + a * H;
  }
}

// ---------- K5c: scan phase C ----------
__global__ __launch_bounds__(256) void k_scanC(float* __restrict__ DT,
                                               const float* __restrict__ U,
                                               const float* __restrict__ BMb,
                                               const float* __restrict__ CMb,
                                               const float* __restrict__ alog,
                                               const float* __restrict__ Dp,
                                               const float* __restrict__ Hin) {
  __shared__ float dt_s[LCH][16], u_s[LCH][16], bm_s[LCH][16], cm_s[LCH][16];
  int blk = blockIdx.x;
  int dch = blk & 7, nbb = (blk >> 3) & 15, chunk = blk >> 7;
  int nb = nbb >> 2;
  int t = threadIdx.x;
  int ch = t >> 4, s = t & 15;
  int d = dch * 16 + ch;
  float A = -expf(alog[(nb * DIN_ + d) * DS_ + s]);
  float Dv = Dp[nb * DIN_ + d];
  long base = (long)nbb * N_ + chunk * LCH;
  for (int i = t; i < LCH * 16; i += 256) {
    int tt = i >> 4, cc = i & 15;
    long r = base + tt;
    dt_s[tt][cc] = DT[r * DIN_ + dch * 16 + cc];
    u_s[tt][cc]  = U [r * DIN_ + dch * 16 + cc];
    bm_s[tt][cc] = BMb[r * DS_ + cc];
    cm_s[tt][cc] = CMb[r * DS_ + cc];
  }
  int state = ((nbb << 7) + d) * 16 + s;
  float h = Hin[(long)chunk * NSTATE + state];
  __syncthreads();
  for (int tt = 0; tt < LCH; ++tt) {
    float dtv = dt_s[tt][ch];
    float uv  = u_s[tt][ch];
    float dA = __expf(dtv * A);
    h = dA * h + dtv * uv * bm_s[tt][s];
    float p = h * cm_s[tt][s];
    p += __shfl_xor(p, 1, 16);
    p += __shfl_xor(p, 2, 16);
    p += __shfl_xor(p, 4, 16);
    p += __shfl_xor(p, 8, 16);
    if (s == 0) DT[(base + tt) * DIN_ + d] = p + Dv * uv;
  }
}

// ---------- K6: y2 = y*silu(z); xm = y2 @ outw^T + skip*xn -> concat layout (B,N,C) ----------
__global__ __launch_bounds__(256) void k_outproj(const float* __restrict__ Y,
                                                 const float* __restrict__ Z,
                                                 const float* __restrict__ outw,
                                                 const float* __restrict__ xn,
                                                 const float* __restrict__ skip,
                                                 float* __restrict__ XMC) {
  __shared__ float wL[64][129];
  __shared__ float y2r[16][128];
  int row0 = blockIdx.x * 16;                // over NB*B*N = 16384 rows
  int nb = row0 >> 12;
  for (int i = threadIdx.x; i < 64 * 128; i += 256) {
    int col = i >> 7, j = i & 127;
    wL[col][j] = outw[nb * DM_ * DIN_ + i];
  }
  for (int i = threadIdx.x; i < 16 * 128; i += 256) {
    int r = i >> 7, j = i & 127;
    long row = (long)row0 + r;
    float z = Z[row * DIN_ + j];
    y2r[r][j] = Y[row * DIN_ + j] * siluf(z);
  }
  __syncthreads();
  float sk = skip[0];
  int col = threadIdx.x & 63;
  int rbase = threadIdx.x >> 6;
  for (int ii = 0; ii < 4; ++ii) {
    int rr = rbase + ii * 4;
    float acc = 0.f;
#pragma unroll 8
    for (int j = 0; j < 128; ++j) acc += y2r[rr][j] * wL[col][j];
    int bn = (row0 + rr) & 4095;
    long oc = (long)bn * C_ + nb * DM_ + col;
    XMC[oc] = acc + sk * xn[oc];
  }
}

// ---------- K7: gate ----------
__global__ __launch_bounds__(256) void k_gate(const float* __restrict__ XMC,
                                              const float* __restrict__ qdw_w,
                                              const float* __restrict__ qdw_b,
                                              const float* __restrict__ qpw_w,
                                              const float* __restrict__ qpw_b,
                                              float* __restrict__ G) {
  int t = threadIdx.x;
  int gid = (blockIdx.x * 256 + t) >> 4;     // b*N + n
  int cq = t & 3, p = (t >> 2) & 3;
  int b = gid >> 10, n = gid & 1023;
  float a = 0.f;
#pragma unroll
  for (int k = 0; k < 3; ++k) {
    int nn = n + k - 1;
    if (nn < 0 || nn >= N_) continue;
    const float* xr = XMC + ((long)b * N_ + nn) * C_ + p * 64 + cq * 16;
    const float* wr = qdw_w + (p * 64 + cq * 16) * 3 + k;
#pragma unroll
    for (int i = 0; i < 16; ++i) a += xr[i] * wr[i * 3];
  }
  a += __shfl_xor(a, 1, 64);
  a += __shfl_xor(a, 2, 64);
  float q1 = a + qdw_b[p];                   // all cq lanes hold q1(gid, p)
  int lane = t & 63;
  float q1g[4];
#pragma unroll
  for (int pp = 0; pp < 4; ++pp) q1g[pp] = __shfl(q1, (lane & ~12) | (pp << 2), 64);
  int o = p;
  float r = qpw_b[o];
#pragma unroll
  for (int pp = 0; pp < 4; ++pp) r += qpw_w[o * 4 + pp] * q1g[pp];
  if (cq == 0) G[((long)b * 4 + o) * N_ + n] = sigmf(r);
}

// ---------- K8: xg (B,C,N) = g * xm ----------
__global__ __launch_bounds__(256) void k_xg(const float* __restrict__ XMC,
                                            const float* __restrict__ G,
                                            float* __restrict__ XG) {
  long i = (long)blockIdx.x * 256 + threadIdx.x;  // B*C*N
  int n = i & 1023;
  long bc = i >> 10;
  int c = bc & 255, b = (int)(bc >> 8);
  float g = G[((long)b * 4 + (c >> 6)) * N_ + n];
  XG[i] = g * XMC[((long)b * N_ + n) * C_ + c];
}

// ---------- generic 3-tap depthwise conv over n, (B,nchan,N) layout ----------
__global__ __launch_bounds__(256) void k_dw3(const float* __restrict__ in,
                                             const float* __restrict__ w,
                                             const float* __restrict__ bias,
                                             float* __restrict__ out, int nchan) {
  long i = (long)blockIdx.x * 256 + threadIdx.x;
  if (i >= (long)B_ * nchan * N_) return;
  int n = i & 1023;
  int c = (int)((i >> 10) % nchan);
  const float* r = in + (i - n);
  float a = bias[c] + w[c * 3 + 1] * r[n];
  if (n > 0)      a += w[c * 3 + 0] * r[n - 1];
  if (n < N_ - 1) a += w[c * 3 + 2] * r[n + 1];
  out[i] = a;
}

// ---------- K10: depthwise conv over virtual cat = [xs^T ; R] (B,512,N) ----------
__global__ __launch_bounds__(256) void k_fdw(const float* __restrict__ XS,
                                             const float* __restrict__ RB,
                                             const float* __restrict__ w,
                                             const float* __restrict__ bias,
                                             float* __restrict__ YDW) {
  long i = (long)blockIdx.x * 256 + threadIdx.x;  // B*512*N
  int n = i & 1023;
  long bc = i >> 10;
  int cc = bc & 511, b = (int)(bc >> 9);
  float v0 = 0.f, v1, v2 = 0.f;
  if (cc < C_) {
    const float* p = XS + (long)b * N_ * C_ + cc;
    v1 = p[(long)n * C_];
    if (n > 0)      v0 = p[(long)(n - 1) * C_];
    if (n < N_ - 1) v2 = p[(long)(n + 1) * C_];
  } else {
    const float* p = RB + ((long)b * C_ + (cc - C_)) * N_;
    v1 = p[n];
    if (n > 0)      v0 = p[n - 1];
    if (n < N_ - 1) v2 = p[n + 1];
  }
  YDW[i] = bias[cc] + w[cc * 3] * v0 + w[cc * 3 + 1] * v1 + w[cc * 3 + 2] * v2;
}

// ---------- K12: x_local depthwise over n in (B,N,C) layout ----------
__global__ __launch_bounds__(256) void k_lc(const float* __restrict__ XM2,
                                            const float* __restrict__ w,
                                            const float* __restrict__ bias,
                                            float* __restrict__ XL) {
  long i = (long)blockIdx.x * 256 + threadIdx.x;  // B*N*C, c fastest
  int c = i & 255;
  long bn = i >> 8;
  int n = bn & 1023, b = (int)(bn >> 10);
  const float* p = XM2 + (long)b * N_ * C_ + c;
  float a = bias[c] + w[c * 3 + 1] * p[(long)n * C_];
  if (n > 0)      a += w[c * 3 + 0] * p[(long)(n - 1) * C_];
  if (n < N_ - 1) a += w[c * 3 + 2] * p[(long)(n + 1) * C_];
  XL[i] = a;
}

// ---------- MFMA GEMM, row-major activations ----------
// out[r][c] = sum_k in[r][k] * w[c][k] + bias[c].
// Block: 64 rows x 64 cols, 4 waves x 16 rows. inB = optional second K-half (concat).
// TOUT: write transposed to (B,256,N) via LDS bounce.
template <int KD, bool TOUT>
__global__ __launch_bounds__(256) void k_gemm_rm(const float* __restrict__ inA,
                                                 const float* __restrict__ inB,
                                                 const float* __restrict__ w,
                                                 const float* __restrict__ bias,
                                                 float* __restrict__ out,
                                                 int Cout, int lda) {
  __shared__ unsigned short xa[64][72];
  __shared__ unsigned short wb[64][72];
  __shared__ float tt[TOUT ? 64 : 1][TOUT ? 68 : 1];
  int r0 = blockIdx.x * 64;
  int c0 = blockIdx.y * 64;
  int t = threadIdx.x;
  int wv = t >> 6, lane = t & 63, g = lane >> 4, ql = lane & 15;
  const f32x4 zf = {0.f, 0.f, 0.f, 0.f};
  f32x4 acc[4] = {zf, zf, zf, zf};
  int rr = t >> 2, kq = (t & 3) * 16;
  for (int k0 = 0; k0 < KD; k0 += 64) {
    __syncthreads();
    int kk = k0 + kq;
    const float* xsrc = (inB != nullptr && kk >= KD / 2)
                            ? inB + (long)(r0 + rr) * lda + (kk - KD / 2)
                            : inA + (long)(r0 + rr) * lda + kk;
#pragma unroll
    for (int j = 0; j < 4; ++j) {
      float4 v = *(const float4*)(xsrc + 4 * j);
      ushort4v u = {f2b(v.x), f2b(v.y), f2b(v.z), f2b(v.w)};
      *(ushort4v*)&xa[rr][kq + 4 * j] = u;
    }
    const float* wsrc = w + (long)(c0 + rr) * KD + kk;
#pragma unroll
    for (int j = 0; j < 4; ++j) {
      float4 v = *(const float4*)(wsrc + 4 * j);
      ushort4v u = {f2b(v.x), f2b(v.y), f2b(v.z), f2b(v.w)};
      *(ushort4v*)&wb[rr][kq + 4 * j] = u;
    }
    __syncthreads();
#pragma unroll
    for (int ks = 0; ks < 2; ++ks) {
      bf16x8 a = *(const bf16x8*)&xa[wv * 16 + ql][ks * 32 + g * 8];
#pragma unroll
      for (int ct = 0; ct < 4; ++ct) {
        bf16x8 b = *(const bf16x8*)&wb[ct * 16 + ql][ks * 32 + g * 8];
        acc[ct] = __builtin_amdgcn_mfma_f32_16x16x32_bf16(a, b, acc[ct], 0, 0, 0);
      }
    }
  }
  if constexpr (!TOUT) {
#pragma unroll
    for (int ct = 0; ct < 4; ++ct) {
      int col = c0 + ct * 16 + ql;
      float bv = bias[col];
#pragma unroll
      for (int reg = 0; reg < 4; ++reg) {
        long row = r0 + wv * 16 + g * 4 + reg;
        out[row * Cout + col] = acc[ct][reg] + bv;
      }
    }
  } else {
#pragma unroll
    for (int ct = 0; ct < 4; ++ct) {
      int col = ct * 16 + ql;
      float bv = bias[c0 + col];
#pragma unroll
      for (int reg = 0; reg < 4; ++reg)
        tt[col][wv * 16 + g * 4 + reg] = acc[ct][reg] + bv;
    }
    __syncthreads();
    int b = r0 >> 10, n0 = r0 & 1023;
    int col = t >> 2, nq = (t & 3) * 16;
    float* op = out + ((long)(b * 256 + c0 + col)) * 1024 + n0 + nq;
#pragma unroll
    for (int j = 0; j < 4; ++j) {
      float4 v = make_float4(tt[col][nq + 4 * j], tt[col][nq + 4 * j + 1],
                             tt[col][nq + 4 * j + 2], tt[col][nq + 4 * j + 3]);
      *(float4*)(op + 4 * j) = v;
    }
  }
}

// ---------- MFMA GEMM, channel-major activations (B, KD, 1024) ----------
// out rows = n, cols = cout; fused residual (CM or RM layout). Cout = 256.
template <int KD>
__global__ __launch_bounds__(256) void k_gemm_cm(const float* __restrict__ in,
                                                 const float* __restrict__ w,
                                                 const float* __restrict__ bias,
                                                 const float* __restrict__ residCM,
                                                 const float* __restrict__ residRM,
                                                 float* __restrict__ outCM,
                                                 float* __restrict__ outRM) {
  __shared__ unsigned short xa[64][72];  // [n][k]
  __shared__ unsigned short wb[64][72];  // [cout][k]
  int rb = blockIdx.x;
  int b = rb >> 4, n0 = (rb & 15) * 64;
  int c0 = blockIdx.y * 64;
  int t = threadIdx.x;
  int wv = t >> 6, lane = t & 63, g = lane >> 4, ql = lane & 15;
  const f32x4 zf = {0.f, 0.f, 0.f, 0.f};
  f32x4 acc[4] = {zf, zf, zf, zf};
  int rr = t >> 2, kq = (t & 3) * 16;
  for (int k0 = 0; k0 < KD; k0 += 64) {
    __syncthreads();
    {
      const float* src = in + ((long)(b * KD + k0 + rr)) * 1024 + n0 + kq;
#pragma unroll
      for (int j = 0; j < 4; ++j) {
        float4 v = *(const float4*)(src + 4 * j);
        xa[kq + 4 * j + 0][rr] = f2b(v.x);
        xa[kq + 4 * j + 1][rr] = f2b(v.y);
        xa[kq + 4 * j + 2][rr] = f2b(v.z);
        xa[kq + 4 * j + 3][rr] = f2b(v.w);
      }
    }
    const float* wsrc = w + (long)(c0 + rr) * KD + k0 + kq;
#pragma unroll
    for (int j = 0; j < 4; ++j) {
      float4 v = *(const float4*)(wsrc + 4 * j);
      ushort4v u = {f2b(v.x), f2b(v.y), f2b(v.z), f2b(v.w)};
      *(ushort4v*)&wb[rr][kq + 4 * j] = u;
    }
    __syncthreads();
#pragma unroll
    for (int ks = 0; ks < 2; ++ks) {
      bf16x8 a = *(const bf16x8*)&xa[wv * 16 + ql][ks * 32 + g * 8];
#pragma unroll
      for (int ct = 0; ct < 4; ++ct) {
        bf16x8 bfr = *(const bf16x8*)&wb[ct * 16 + ql][ks * 32 + g * 8];
        acc[ct] = __builtin_amdgcn_mfma_f32_16x16x32_bf16(a, bfr, acc[ct], 0, 0, 0);
      }
    }
  }
#pragma unroll
  for (int ct = 0; ct < 4; ++ct) {
    int col = c0 + ct * 16 + ql;
    float bv = bias[col];
    if (outCM) {
      long base = ((long)(b * 256 + col)) * 1024 + n0 + wv * 16 + g * 4;
      float4 r4 = *(const float4*)(residCM + base);
      float4 o = make_float4(acc[ct][0] + bv + r4.x, acc[ct][1] + bv + r4.y,
                             acc[ct][2] + bv + r4.z, acc[ct][3] + bv + r4.w);
      *(float4*)(outCM + base) = o;
    } else {
#pragma unroll
      for (int reg = 0; reg < 4; ++reg) {
        long row = (long)b * 1024 + n0 + wv * 16 + g * 4 + reg;
        long idx = row * 256 + col;
        outRM[idx] = acc[ct][reg] + bv + residRM[idx];
      }
    }
  }
}

// ---------- K14: MFMA bf16 flash attention ----------
__global__ __launch_bounds__(256) void k_attn_mfma(const float* __restrict__ qkv,
                                                   float* __restrict__ O) {
  __shared__ unsigned short K_lds[64 * 40];       // [64 keys][32+8 dims]
  __shared__ unsigned short Vt_lds[32 * 72];      // [32 dims][64+8 keys]
  __shared__ unsigned short P_lds[4][16 * 72];    // per wave: [16 q][64+8 keys]
  int bx = blockIdx.x;
  int bh = bx >> 4, qt = bx & 15;
  int b = bh >> 3, h = bh & 7;
  int t = threadIdx.x;
  int w = t >> 6, lane = t & 63;
  int g = lane >> 4, ql = lane & 15;
  const float qscale = 0.17677669529663687f * 1.44269504088896341f;  // 1/sqrt(32) * log2(e)

  bf16x8 q_frag;
  {
    const float* qp = qkv + ((long)(b * N_ + qt * 64 + w * 16 + ql)) * 768 + h * HD_ + g * 8;
#pragma unroll
    for (int i = 0; i < 8; ++i) q_frag[i] = (short)f2b(qp[i] * qscale);
  }
  float m = -1e30f, l = 0.f;
  f32x4 o_acc[2];
  const f32x4 zf = {0.f, 0.f, 0.f, 0.f};
  o_acc[0] = zf; o_acc[1] = zf;

  for (int kt = 0; kt < 16; ++kt) {
    __syncthreads();
    {
      int kr = t >> 2, d0 = (t & 3) * 8;
      const float* gp = qkv + ((long)(b * N_ + kt * 64 + kr)) * 768 + 256 + h * HD_ + d0;
      ushort8v kv;
#pragma unroll
      for (int i = 0; i < 8; ++i) kv[i] = f2b(gp[i]);
      *(ushort8v*)&K_lds[kr * 40 + d0] = kv;
      const float* vp = gp + 256;
#pragma unroll
      for (int i = 0; i < 8; ++i) Vt_lds[(d0 + i) * 72 + kr] = f2b(vp[i]);
    }
    __syncthreads();
    f32x4 s_frag[4];
#pragma unroll
    for (int s = 0; s < 4; ++s) {
      bf16x8 k_frag = *(const bf16x8*)&K_lds[(s * 16 + ql) * 40 + g * 8];
      s_frag[s] = __builtin_amdgcn_mfma_f32_16x16x32_bf16(k_frag, q_frag, zf, 0, 0, 0);
    }
    float sv[16];
#pragma unroll
    for (int s = 0; s < 4; ++s)
#pragma unroll
      for (int r = 0; r < 4; ++r) sv[s * 4 + r] = s_frag[s][r];
    float tmax = sv[0];
#pragma unroll
    for (int i = 1; i < 16; ++i) tmax = fmaxf(tmax, sv[i]);
    tmax = fmaxf(tmax, __shfl_xor(tmax, 16));
    tmax = fmaxf(tmax, __shfl_xor(tmax, 32));
    float mn = fmaxf(m, tmax);
    float corr = exp2f(m - mn);
    float psum = 0.f;
    unsigned short pb[16];
#pragma unroll
    for (int i = 0; i < 16; ++i) {
      float p = exp2f(sv[i] - mn);
      psum += p;
      pb[i] = f2b(p);
    }
    psum += __shfl_xor(psum, 16);
    psum += __shfl_xor(psum, 32);
    l = l * corr + psum;
    m = mn;
#pragma unroll
    for (int mt = 0; mt < 2; ++mt)
#pragma unroll
      for (int r = 0; r < 4; ++r) o_acc[mt][r] *= corr;
#pragma unroll
    for (int s = 0; s < 4; ++s) {
      ushort4v p4 = {pb[s * 4], pb[s * 4 + 1], pb[s * 4 + 2], pb[s * 4 + 3]};
      *(ushort4v*)&P_lds[w][ql * 72 + s * 16 + g * 4] = p4;
    }
#pragma unroll
    for (int c = 0; c < 2; ++c) {
      bf16x8 p_frag = *(const bf16x8*)&P_lds[w][ql * 72 + c * 32 + g * 8];
#pragma unroll
      for (int mt = 0; mt < 2; ++mt) {
        bf16x8 v_frag = *(const bf16x8*)&Vt_lds[(mt * 16 + ql) * 72 + c * 32 + g * 8];
        o_acc[mt] = __builtin_amdgcn_mfma_f32_16x16x32_bf16(v_frag, p_frag, o_acc[mt], 0, 0, 0);
      }
    }
  }
  float inv = 1.f / l;
  float* op = O + ((long)(b * N_ + qt * 64 + w * 16 + ql)) * C_ + h * HD_;
#pragma unroll
  for (int mt = 0; mt < 2; ++mt) {
    float4 o4 = make_float4(o_acc[mt][0] * inv, o_acc[mt][1] * inv,
                            o_acc[mt][2] * inv, o_acc[mt][3] * inv);
    *(float4*)(op + mt * 16 + g * 4) = o4;
  }
}

// ---------- K17: LN(lgn) + exact GELU -> (B,C,N) layout ----------
__global__ __launch_bounds__(256) void k_lngelu(const float* __restrict__ XO,
                                                const float* __restrict__ lw,
                                                const float* __restrict__ lb,
                                                float* __restrict__ XI) {
  __shared__ float red[8];
  int bn = blockIdx.x;
  int b = bn >> 10, n = bn & 1023;
  int c = threadIdx.x;
  float v = XO[(long)bn * C_ + c];
  float2 s = blockReduce2(v, v * v, red);
  float mu = s.x * (1.f / C_);
  float rs = rsqrtf(s.y * (1.f / C_) - mu * mu + 1e-5f);
  float x = (v - mu) * rs * lw[c] + lb[c];
  float ge = 0.5f * x * (1.f + erff(x * 0.70710678118654752f));
  XI[((long)b * C_ + c) * N_ + n] = ge;
}

// ---------- K18: ln over (H,W) per (b,c), in place, no affine ----------
__global__ __launch_bounds__(256) void k_lnhw(float* __restrict__ XI) {
  __shared__ float red[8];
  long base = (long)blockIdx.x * N_;  // b*C + c
  float a = 0.f, b2 = 0.f;
  for (int i = threadIdx.x; i < N_; i += 256) {
    float v = XI[base + i];
    a += v; b2 += v * v;
  }
  float2 s = blockReduce2(a, b2, red);
  float mu = s.x * (1.f / N_);
  float rs = rsqrtf(s.y * (1.f / N_) - mu * mu + 1e-5f);
  for (int i = threadIdx.x; i < N_; i += 256) XI[base + i] = (XI[base + i] - mu) * rs;
}

// ---------- K19: depthwise 3x3 conv on (B,C,32,32), pad 1 ----------
__global__ __launch_bounds__(256) void k_dwc(const float* __restrict__ XI,
                                             const float* __restrict__ w,
                                             const float* __restrict__ bias,
                                             float* __restrict__ XD) {
  long i = (long)blockIdx.x * 256 + threadIdx.x;  // B*C*1024
  int hw = i & 1023;
  int wq = hw & 31, hq = hw >> 5;
  int c = (int)((i >> 10) & 255);
  const float* p = XI + (i - hw);
  const float* wk = w + c * 9;
  float a = bias[c];
#pragma unroll
  for (int kh = 0; kh < 3; ++kh) {
    int h2 = hq + kh - 1;
    if (h2 < 0 || h2 >= 32) continue;
#pragma unroll
    for (int kw = 0; kw < 3; ++kw) {
      int w2 = wq + kw - 1;
      if (w2 < 0 || w2 >= 32) continue;
      a += wk[kh * 3 + kw] * p[h2 * 32 + w2];
    }
  }
  XD[i] = a;
}

extern "C" void kernel_launch(void* const* d_in, const int* in_sizes, int n_in,
                              void* d_out, int out_size, void* d_ws, size_t ws_size,
                              hipStream_t stream) {
  const float* x        = (const float*)d_in[0];
  const float* norm_w   = (const float*)d_in[1];
  const float* norm_b   = (const float*)d_in[2];
  const float* skip     = (const float*)d_in[3];
  const float* m_inw    = (const float*)d_in[4];
  const float* m_convw  = (const float*)d_in[5];
  const float* m_convb  = (const float*)d_in[6];
  const float* m_xpw    = (const float*)d_in[7];
  const float* m_dtw    = (const float*)d_in[8];
  const float* m_dtb    = (const float*)d_in[9];
  const float* m_alog   = (const float*)d_in[10];
  const float* m_d      = (const float*)d_in[11];
  const float* m_outw   = (const float*)d_in[12];
  const float* qdw_w    = (const float*)d_in[13];
  const float* qdw_b    = (const float*)d_in[14];
  const float* qpw_w    = (const float*)d_in[15];
  const float* qpw_b    = (const float*)d_in[16];
  const float* rdw_w    = (const float*)d_in[17];
  const float* rdw_b    = (const float*)d_in[18];
  const float* rpw_w    = (const float*)d_in[19];
  const float* rpw_b    = (const float*)d_in[20];
  const float* fdw_w    = (const float*)d_in[21];
  const float* fdw_b    = (const float*)d_in[22];
  const float* fpw_w    = (const float*)d_in[23];
  const float* fpw_b    = (const float*)d_in[24];
  const float* lc_w     = (const float*)d_in[25];
  const float* lc_b     = (const float*)d_in[26];
  const float* attn_inw = (const float*)d_in[27];
  const float* attn_inb = (const float*)d_in[28];
  const float* attn_outw= (const float*)d_in[29];
  const float* attn_outb= (const float*)d_in[30];
  const float* lgn_w    = (const float*)d_in[31];
  const float* lgn_b    = (const float*)d_in[32];
  const float* fc_w     = (const float*)d_in[33];
  const float* fc_b     = (const float*)d_in[34];
  const float* dwc_w    = (const float*)d_in[35];
  const float* dwc_b    = (const float*)d_in[36];
  const float* proj_w   = (const float*)d_in[37];
  const float* proj_b   = (const float*)d_in[38];
  float* out = (float*)d_out;

  float* ws = (float*)d_ws;
  const size_t F = 1048576;  // B*N*C
  float* XS  = ws + 0 * F;
  float* XN  = ws + 1 * F;
  float* U   = ws + 2 * F;
  float* Z   = ws + 4 * F;
  float* DT  = ws + 6 * F;
  float* BM  = ws + 8 * F;
  float* CM  = ws + 8 * F + F / 4;
  float* XMC = ws + 8 * F + F / 2;
  float* SC_APROD = ws + 8 * F + F / 2;            // scan scratch (XMC region, dead then)
  float* SC_HEND  = ws + 9 * F;
  float* G   = ws + 1 * F;
  float* XG  = ws + 2 * F;
  float* RD  = ws + 3 * F;
  float* RB  = ws + 4 * F;
  float* XM2 = ws + 5 * F;
  float* YDW = ws + 6 * F;
  float* XL  = ws + 0 * F;
  float* QKV = ws + 1 * F;
  float* O   = ws + 4 * F;
  float* XGL = ws + 6 * F;
  float* XO  = ws + 7 * F;
  float* XI  = ws + 8 * F;
  float* XD  = ws + 5 * F;
  float* LNF = ws + 0 * F;
  (void)ws_size; (void)in_sizes; (void)n_in; (void)out_size;

  k_ln_t<<<4096, 256, 0, stream>>>(x, norm_w, norm_b, XN, XS);
  k_inproj<<<dim3(64, 4), 256, 0, stream>>>(XN, m_inw, U, Z);
  k_causal<<<2048, 256, 0, stream>>>(U, m_convw, m_convb);
  k_xdbc<<<2048, 128, 0, stream>>>(U, m_xpw, m_dtw, m_dtb, DT, BM, CM);
  k_scanA<<<2048, 256, 0, stream>>>(DT, U, BM, m_alog, SC_APROD, SC_HEND);
  k_scanB<<<128, 256, 0, stream>>>(SC_APROD, SC_HEND);
  k_scanC<<<2048, 256, 0, stream>>>(DT, U, BM, CM, m_alog, m_d, SC_APROD);
  k_outproj<<<1024, 256, 0, stream>>>(DT, Z, m_outw, XN, skip, XMC);
  k_gate<<<256, 256, 0, stream>>>(XMC, qdw_w, qdw_b, qpw_w, qpw_b, G);
  k_xg<<<4096, 256, 0, stream>>>(XMC, G, XG);
  k_dw3<<<4096, 256, 0, stream>>>(XG, rdw_w, rdw_b, RD, 256);
  k_gemm_cm<256><<<dim3(64, 4), 256, 0, stream>>>(RD, rpw_w, rpw_b, XG, nullptr, RB, nullptr);
  k_fdw<<<8192, 256, 0, stream>>>(XS, RB, fdw_w, fdw_b, YDW);
  k_gemm_cm<512><<<dim3(64, 4), 256, 0, stream>>>(YDW, fpw_w, fpw_b, nullptr, XS, nullptr, XM2);
  k_lc<<<4096, 256, 0, stream>>>(XM2, lc_w, lc_b, XL);
  k_gemm_rm<256, false><<<dim3(64, 12), 256, 0, stream>>>(XM2, nullptr, attn_inw, attn_inb, QKV, 768, 256);
  k_attn_mfma<<<512, 256, 0, stream>>>(QKV, O);
  k_gemm_rm<256, false><<<dim3(64, 4), 256, 0, stream>>>(O, nullptr, attn_outw, attn_outb, XGL, 256, 256);
  k_gemm_rm<512, false><<<dim3(64, 4), 256, 0, stream>>>(XL, XGL, fc_w, fc_b, XO, 256, 256);
  k_lngelu<<<4096, 256, 0, stream>>>(XO, lgn_w, lgn_b, XI);
  k_lnhw<<<1024, 256, 0, stream>>>(XI);
  k_dwc<<<4096, 256, 0, stream>>>(XI, dwc_w, dwc_b, XD);
  k_ln_t<<<4096, 256, 0, stream>>>(XD, norm_w, norm_b, LNF, nullptr);
  k_gemm_rm<256, true><<<dim3(64, 4), 256, 0, stream>>>(LNF, nullptr, proj_w, proj_b, out, 256, 256);
}

// Round 6
// 313.900 us; speedup vs baseline: 3.7153x; 1.1005x over previous
//
#include <hip/hip_runtime.h>
#include <math.h>

// MambaLiteUNet — round 5: scan phases A/C remapped to 4 s-states per thread
// (register h[4], 2-shuffle reduce, float4 staging) — was issue-bound at 46 us.

namespace {
constexpr int NB_ = 4, DM_ = 64, DIN_ = 128, DS_ = 16, DTR_ = 4;
constexpr int C_ = 256, N_ = 1024, B_ = 4, HD_ = 32;
constexpr int NCH = 16, LCH = 64;          // scan: 16 time-chunks of 64
constexpr int NSTATE = 16 * 128 * 16;      // nbb * DIN * DS = 32768
}

typedef __attribute__((ext_vector_type(8))) short bf16x8;
typedef __attribute__((ext_vector_type(4))) float f32x4;
typedef __attribute__((ext_vector_type(8))) unsigned short ushort8v;
typedef __attribute__((ext_vector_type(4))) unsigned short ushort4v;

// ---------- helpers ----------
__device__ __forceinline__ unsigned short f2b(float f) {  // fp32 -> bf16 RNE
  unsigned int u = __float_as_uint(f);
  unsigned int r = u + 0x7FFFu + ((u >> 16) & 1u);
  return (unsigned short)(r >> 16);
}

__device__ __forceinline__ float2 blockReduce2(float a, float b, float* red) {
#pragma unroll
  for (int m = 1; m < 64; m <<= 1) {
    a += __shfl_xor(a, m, 64);
    b += __shfl_xor(b, m, 64);
  }
  int w = threadIdx.x >> 6;
  if ((threadIdx.x & 63) == 0) { red[2 * w] = a; red[2 * w + 1] = b; }
  __syncthreads();
  float ra = red[0] + red[2] + red[4] + red[6];
  float rb = red[1] + red[3] + red[5] + red[7];
  return make_float2(ra, rb);
}

__device__ __forceinline__ float siluf(float x) { return x / (1.f + expf(-x)); }
__device__ __forceinline__ float sigmf(float x) { return 1.f / (1.f + expf(-x)); }
__device__ __forceinline__ float softplusf(float x) {
  return fmaxf(x, 0.f) + log1pf(expf(-fabsf(x)));
}

// ---------- K1/K20a: layernorm over C of a (B,C,N) tensor -> (B,N,C); optional raw copy ----------
__global__ __launch_bounds__(256) void k_ln_t(const float* __restrict__ in,
                                              const float* __restrict__ w,
                                              const float* __restrict__ bias,
                                              float* __restrict__ out_ln,
                                              float* __restrict__ out_copy) {
  __shared__ float red[8];
  int bn = blockIdx.x;            // b*N + n
  int b = bn >> 10, n = bn & 1023;
  int c = threadIdx.x;
  float v = in[(b * C_ + c) * N_ + n];
  if (out_copy) out_copy[(long)bn * C_ + c] = v;
  float2 s = blockReduce2(v, v * v, red);
  float mu = s.x * (1.f / C_);
  float var = s.y * (1.f / C_) - mu * mu;
  float rs = rsqrtf(var + 1e-5f);
  out_ln[(long)bn * C_ + c] = (v - mu) * rs * w[c] + bias[c];
}

// ---------- K2: mamba in-proj  xz = xn_block @ inw^T  -> u, z ----------
__global__ __launch_bounds__(256) void k_inproj(const float* __restrict__ xn,
                                                const float* __restrict__ inw,
                                                float* __restrict__ U, float* __restrict__ Z) {
  __shared__ float xrows[4][64];
  int nb = blockIdx.y;
  int j = threadIdx.x;                       // output col 0..255
  const float* wp = inw + ((long)nb * 2 * DIN_ + j) * DM_;
  float wreg[64];
#pragma unroll
  for (int m = 0; m < 64; ++m) wreg[m] = wp[m];
  int row0 = blockIdx.x * 64;                // over B*N = 4096 rows
  for (int r0 = 0; r0 < 64; r0 += 4) {
    __syncthreads();
    {
      int rr = threadIdx.x >> 6, m = threadIdx.x & 63;
      xrows[rr][m] = xn[(long)(row0 + r0 + rr) * C_ + nb * DM_ + m];
    }
    __syncthreads();
    for (int rr = 0; rr < 4; ++rr) {
      float acc = 0.f;
#pragma unroll
      for (int m = 0; m < 64; ++m) acc += xrows[rr][m] * wreg[m];
      long row = (long)nb * (B_ * N_) + row0 + r0 + rr;
      if (j < DIN_) U[row * DIN_ + j] = acc;
      else          Z[row * DIN_ + (j - DIN_)] = acc;
    }
  }
}

// ---------- K3: causal depthwise conv (K=4) + silu, in-place on U ----------
__global__ __launch_bounds__(256) void k_causal(float* __restrict__ U,
                                                const float* __restrict__ cw,
                                                const float* __restrict__ cb) {
  __shared__ float row[N_];
  int blk = blockIdx.x;                      // nbb*DIN + d,  nbb = nb*B+b
  int d = blk & 127, nbb = blk >> 7, nb = nbb >> 2;
  float* base = U + (long)nbb * N_ * DIN_ + d;
  for (int n = threadIdx.x; n < N_; n += 256) row[n] = base[(long)n * DIN_];
  __syncthreads();
  float w0 = cw[(nb * DIN_ + d) * 4 + 0], w1 = cw[(nb * DIN_ + d) * 4 + 1];
  float w2 = cw[(nb * DIN_ + d) * 4 + 2], w3 = cw[(nb * DIN_ + d) * 4 + 3];
  float bias = cb[nb * DIN_ + d];
  for (int n = threadIdx.x; n < N_; n += 256) {
    float acc = bias + w3 * row[n];
    if (n >= 1) acc += w2 * row[n - 1];
    if (n >= 2) acc += w1 * row[n - 2];
    if (n >= 3) acc += w0 * row[n - 3];
    base[(long)n * DIN_] = siluf(acc);
  }
}

// ---------- K4: xdbc = u @ xpw^T ; dt = softplus(xdbc[:4] @ dtw^T + dtb); Bm, Cm ----------
__global__ __launch_bounds__(128) void k_xdbc(const float* __restrict__ U,
                                              const float* __restrict__ xpw,
                                              const float* __restrict__ dtw,
                                              const float* __restrict__ dtb,
                                              float* __restrict__ DT,
                                              float* __restrict__ BMb, float* __restrict__ CMb) {
  __shared__ float wl[36][129];
  __shared__ float urow[128];
  __shared__ float xd[36];
  int t = threadIdx.x;
  int nb = blockIdx.x >> 9;                  // 2048 blocks, 8 rows each; 4096 rows per nb
  for (int i = t; i < 36 * 128; i += 128) wl[i >> 7][i & 127] = xpw[nb * 36 * 128 + i];
  float dw0 = dtw[(nb * DIN_ + t) * 4 + 0], dw1 = dtw[(nb * DIN_ + t) * 4 + 1];
  float dw2 = dtw[(nb * DIN_ + t) * 4 + 2], dw3 = dtw[(nb * DIN_ + t) * 4 + 3];
  float dtbv = dtb[nb * DIN_ + t];
  for (int r8 = 0; r8 < 8; ++r8) {
    long row = (long)blockIdx.x * 8 + r8;
    __syncthreads();
    urow[t] = U[row * DIN_ + t];
    __syncthreads();
    if (t < 36) {
      float a = 0.f;
#pragma unroll 8
      for (int m = 0; m < 128; ++m) a += urow[m] * wl[t][m];
      xd[t] = a;
    }
    __syncthreads();
    if (t < 16) { BMb[row * DS_ + t] = xd[4 + t]; CMb[row * DS_ + t] = xd[20 + t]; }
    float a = dtbv + xd[0] * dw0 + xd[1] * dw1 + xd[2] * dw2 + xd[3] * dw3;
    DT[row * DIN_ + t] = softplusf(a);
  }
}

// ---------- K5a: scan phase A (v2) — thread owns (d, 4 s-states) ----------
// grid 512: chunk(16) x nbb(16) x dhalf(2). threads: t = dl*4 + sg.
__global__ __launch_bounds__(256) void k_scanA(const float* __restrict__ DT,
                                               const float* __restrict__ U,
                                               const float* __restrict__ BMb,
                                               const float* __restrict__ alog,
                                               float* __restrict__ Aprod,
                                               float* __restrict__ Hend) {
  __shared__ float dt_s[64][64];
  __shared__ float u_s[64][64];
  __shared__ float bm_s[64][16];
  int bx = blockIdx.x;
  int chunk = bx >> 5, rem = bx & 31, nbb = rem >> 1, dh = rem & 1;
  int nb = nbb >> 2;
  int t = threadIdx.x;
  int dl = t >> 2, sg = t & 3;
  int d = dh * 64 + dl;
  long base = (long)nbb * N_ + chunk * LCH;
#pragma unroll
  for (int j = 0; j < 4; ++j) {
    int f = t + 256 * j;                   // float4 index 0..1023
    int tt = f >> 4, dq = (f & 15) * 4;
    long src = (base + tt) * DIN_ + dh * 64 + dq;
    *(float4*)&dt_s[tt][dq] = *(const float4*)&DT[src];
    *(float4*)&u_s[tt][dq]  = *(const float4*)&U[src];
  }
  {
    int tt = t >> 2, sq = (t & 3) * 4;
    *(float4*)&bm_s[tt][sq] = *(const float4*)&BMb[(base + tt) * DS_ + sq];
  }
  float A[4];
#pragma unroll
  for (int i = 0; i < 4; ++i)
    A[i] = -expf(alog[(nb * DIN_ + d) * DS_ + sg * 4 + i]);
  __syncthreads();
  float h[4] = {0.f, 0.f, 0.f, 0.f};
  float ap[4] = {1.f, 1.f, 1.f, 1.f};
  for (int tt = 0; tt < LCH; ++tt) {
    float dtv = dt_s[tt][dl];
    float uv  = u_s[tt][dl];
    float c = dtv * uv;
    float4 bm4 = *(const float4*)&bm_s[tt][sg * 4];
    float bmv[4] = {bm4.x, bm4.y, bm4.z, bm4.w};
#pragma unroll
    for (int i = 0; i < 4; ++i) {
      float dA = __expf(dtv * A[i]);
      h[i] = dA * h[i] + c * bmv[i];
      ap[i] *= dA;
    }
  }
  long st = (long)chunk * NSTATE + ((nbb << 7) + d) * 16 + sg * 4;
  *(float4*)&Aprod[st] = make_float4(ap[0], ap[1], ap[2], ap[3]);
  *(float4*)&Hend[st]  = make_float4(h[0], h[1], h[2], h[3]);
}

// ---------- K5b: scan phase B — carry composition across chunks; Hin over Aprod ----------
__global__ __launch_bounds__(256) void k_scanB(float* __restrict__ Aprod,
                                               const float* __restrict__ Hend) {
  int state = blockIdx.x * 256 + threadIdx.x;
  float H = 0.f;
#pragma unroll
  for (int c = 0; c < NCH; ++c) {
    long idx = (long)c * NSTATE + state;
    float a = Aprod[idx];
    float e = Hend[idx];
    Aprod[idx] = H;            // Hin for chunk c
    H = e + a * H;
  }
}

// ---------- K5c: scan phase C (v2) — re-run chunk from carry, emit y over DT ----------
__global__ __launch_bounds__(256) void k_scanC(float* __restrict__ DT,
                                               const float* __restrict__ U,
                                               const float* __restrict__ BMb,
                                               const float* __restrict__ CMb,
                                               const float* __restrict__ alog,
                                               const float* __restrict__ Dp,
                                               const float* __restrict__ Hin) {
  __shared__ float dt_s[64][64];
  __shared__ float u_s[64][64];
  __shared__ float bm_s[64][16];
  __shared__ float cm_s[64][16];
  int bx = blockIdx.x;
  int chunk = bx >> 5, rem = bx & 31, nbb = rem >> 1, dh = rem & 1;
  int nb = nbb >> 2;
  int t = threadIdx.x;
  int dl = t >> 2, sg = t & 3;
  int d = dh * 64 + dl;
  long base = (long)nbb * N_ + chunk * LCH;
#pragma unroll
  for (int j = 0; j < 4; ++j) {
    int f = t + 256 * j;
    int tt = f >> 4, dq = (f & 15) * 4;
    long src = (base + tt) * DIN_ + dh * 64 + dq;
    *(float4*)&dt_s[tt][dq] = *(const float4*)&DT[src];
    *(float4*)&u_s[tt][dq]  = *(const float4*)&U[src];
  }
  {
    int tt = t >> 2, sq = (t & 3) * 4;
    *(float4*)&bm_s[tt][sq] = *(const float4*)&BMb[(base + tt) * DS_ + sq];
    *(float4*)&cm_s[tt][sq] = *(const float4*)&CMb[(base + tt) * DS_ + sq];
  }
  float A[4];
#pragma unroll
  for (int i = 0; i < 4; ++i)
    A[i] = -expf(alog[(nb * DIN_ + d) * DS_ + sg * 4 + i]);
  float Dv = Dp[nb * DIN_ + d];
  float h[4];
  {
    long st = (long)chunk * NSTATE + ((nbb << 7) + d) * 16 + sg * 4;
    float4 h4 = *(const float4*)&Hin[st];
    h[0] = h4.x; h[1] = h4.y; h[2] = h4.z; h[3] = h4.w;
  }
  __syncthreads();
  for (int tt = 0; tt < LCH; ++tt) {
    float dtv = dt_s[tt][dl];
    float uv  = u_s[tt][dl];
    float c = dtv * uv;
    float4 bm4 = *(const float4*)&bm_s[tt][sg * 4];
    float4 cm4 = *(const float4*)&cm_s[tt][sg * 4];
    float bmv[4] = {bm4.x, bm4.y, bm4.z, bm4.w};
    float cmv[4] = {cm4.x, cm4.y, cm4.z, cm4.w};
    float p = 0.f;
#pragma unroll
    for (int i = 0; i < 4; ++i) {
      float dA = __expf(dtv * A[i]);
      h[i] = dA * h[i] + c * bmv[i];
      p += h[i] * cmv[i];
    }
    p += __shfl_xor(p, 1, 64);
    p += __shfl_xor(p, 2, 64);
    if (sg == 0) DT[(base + tt) * DIN_ + d] = p + Dv * uv;
  }
}

// ---------- K6: y2 = y*silu(z); xm = y2 @ outw^T + skip*xn -> concat layout (B,N,C) ----------
__global__ __launch_bounds__(256) void k_outproj(const float* __restrict__ Y,
                                                 const float* __restrict__ Z,
                                                 const float* __restrict__ outw,
                                                 const float* __restrict__ xn,
                                                 const float* __restrict__ skip,
                                                 float* __restrict__ XMC) {
  __shared__ float wL[64][129];
  __shared__ float y2r[16][128];
  int row0 = blockIdx.x * 16;                // over NB*B*N = 16384 rows
  int nb = row0 >> 12;
  for (int i = threadIdx.x; i < 64 * 128; i += 256) {
    int col = i >> 7, j = i & 127;
    wL[col][j] = outw[nb * DM_ * DIN_ + i];
  }
  for (int i = threadIdx.x; i < 16 * 128; i += 256) {
    int r = i >> 7, j = i & 127;
    long row = (long)row0 + r;
    float z = Z[row * DIN_ + j];
    y2r[r][j] = Y[row * DIN_ + j] * siluf(z);
  }
  __syncthreads();
  float sk = skip[0];
  int col = threadIdx.x & 63;
  int rbase = threadIdx.x >> 6;
  for (int ii = 0; ii < 4; ++ii) {
    int rr = rbase + ii * 4;
    float acc = 0.f;
#pragma unroll 8
    for (int j = 0; j < 128; ++j) acc += y2r[rr][j] * wL[col][j];
    int bn = (row0 + rr) & 4095;
    long oc = (long)bn * C_ + nb * DM_ + col;
    XMC[oc] = acc + sk * xn[oc];
  }
}

// ---------- K7: gate ----------
__global__ __launch_bounds__(256) void k_gate(const float* __restrict__ XMC,
                                              const float* __restrict__ qdw_w,
                                              const float* __restrict__ qdw_b,
                                              const float* __restrict__ qpw_w,
                                              const float* __restrict__ qpw_b,
                                              float* __restrict__ G) {
  int t = threadIdx.x;
  int gid = (blockIdx.x * 256 + t) >> 4;     // b*N + n
  int cq = t & 3, p = (t >> 2) & 3;
  int b = gid >> 10, n = gid & 1023;
  float a = 0.f;
#pragma unroll
  for (int k = 0; k < 3; ++k) {
    int nn = n + k - 1;
    if (nn < 0 || nn >= N_) continue;
    const float* xr = XMC + ((long)b * N_ + nn) * C_ + p * 64 + cq * 16;
    const float* wr = qdw_w + (p * 64 + cq * 16) * 3 + k;
#pragma unroll
    for (int i = 0; i < 16; ++i) a += xr[i] * wr[i * 3];
  }
  a += __shfl_xor(a, 1, 64);
  a += __shfl_xor(a, 2, 64);
  float q1 = a + qdw_b[p];                   // all cq lanes hold q1(gid, p)
  int lane = t & 63;
  float q1g[4];
#pragma unroll
  for (int pp = 0; pp < 4; ++pp) q1g[pp] = __shfl(q1, (lane & ~12) | (pp << 2), 64);
  int o = p;
  float r = qpw_b[o];
#pragma unroll
  for (int pp = 0; pp < 4; ++pp) r += qpw_w[o * 4 + pp] * q1g[pp];
  if (cq == 0) G[((long)b * 4 + o) * N_ + n] = sigmf(r);
}

// ---------- K8: xg (B,C,N) = g * xm ----------
__global__ __launch_bounds__(256) void k_xg(const float* __restrict__ XMC,
                                            const float* __restrict__ G,
                                            float* __restrict__ XG) {
  long i = (long)blockIdx.x * 256 + threadIdx.x;  // B*C*N
  int n = i & 1023;
  long bc = i >> 10;
  int c = bc & 255, b = (int)(bc >> 8);
  float g = G[((long)b * 4 + (c >> 6)) * N_ + n];
  XG[i] = g * XMC[((long)b * N_ + n) * C_ + c];
}

// ---------- generic 3-tap depthwise conv over n, (B,nchan,N) layout ----------
__global__ __launch_bounds__(256) void k_dw3(const float* __restrict__ in,
                                             const float* __restrict__ w,
                                             const float* __restrict__ bias,
                                             float* __restrict__ out, int nchan) {
  long i = (long)blockIdx.x * 256 + threadIdx.x;
  if (i >= (long)B_ * nchan * N_) return;
  int n = i & 1023;
  int c = (int)((i >> 10) % nchan);
  const float* r = in + (i - n);
  float a = bias[c] + w[c * 3 + 1] * r[n];
  if (n > 0)      a += w[c * 3 + 0] * r[n - 1];
  if (n < N_ - 1) a += w[c * 3 + 2] * r[n + 1];
  out[i] = a;
}

// ---------- K10: depthwise conv over virtual cat = [xs^T ; R] (B,512,N) ----------
__global__ __launch_bounds__(256) void k_fdw(const float* __restrict__ XS,
                                             const float* __restrict__ RB,
                                             const float* __restrict__ w,
                                             const float* __restrict__ bias,
                                             float* __restrict__ YDW) {
  long i = (long)blockIdx.x * 256 + threadIdx.x;  // B*512*N
  int n = i & 1023;
  long bc = i >> 10;
  int cc = bc & 511, b = (int)(bc >> 9);
  float v0 = 0.f, v1, v2 = 0.f;
  if (cc < C_) {
    const float* p = XS + (long)b * N_ * C_ + cc;
    v1 = p[(long)n * C_];
    if (n > 0)      v0 = p[(long)(n - 1) * C_];
    if (n < N_ - 1) v2 = p[(long)(n + 1) * C_];
  } else {
    const float* p = RB + ((long)b * C_ + (cc - C_)) * N_;
    v1 = p[n];
    if (n > 0)      v0 = p[n - 1];
    if (n < N_ - 1) v2 = p[n + 1];
  }
  YDW[i] = bias[cc] + w[cc * 3] * v0 + w[cc * 3 + 1] * v1 + w[cc * 3 + 2] * v2;
}

// ---------- K12: x_local depthwise over n in (B,N,C) layout ----------
__global__ __launch_bounds__(256) void k_lc(const float* __restrict__ XM2,
                                            const float* __restrict__ w,
                                            const float* __restrict__ bias,
                                            float* __restrict__ XL) {
  long i = (long)blockIdx.x * 256 + threadIdx.x;  // B*N*C, c fastest
  int c = i & 255;
  long bn = i >> 8;
  int n = bn & 1023, b = (int)(bn >> 10);
  const float* p = XM2 + (long)b * N_ * C_ + c;
  float a = bias[c] + w[c * 3 + 1] * p[(long)n * C_];
  if (n > 0)      a += w[c * 3 + 0] * p[(long)(n - 1) * C_];
  if (n < N_ - 1) a += w[c * 3 + 2] * p[(long)(n + 1) * C_];
  XL[i] = a;
}

// ---------- MFMA GEMM, row-major activations ----------
template <int KD, bool TOUT>
__global__ __launch_bounds__(256) void k_gemm_rm(const float* __restrict__ inA,
                                                 const float* __restrict__ inB,
                                                 const float* __restrict__ w,
                                                 const float* __restrict__ bias,
                                                 float* __restrict__ out,
                                                 int Cout, int lda) {
  __shared__ unsigned short xa[64][72];
  __shared__ unsigned short wb[64][72];
  __shared__ float tt[TOUT ? 64 : 1][TOUT ? 68 : 1];
  int r0 = blockIdx.x * 64;
  int c0 = blockIdx.y * 64;
  int t = threadIdx.x;
  int wv = t >> 6, lane = t & 63, g = lane >> 4, ql = lane & 15;
  const f32x4 zf = {0.f, 0.f, 0.f, 0.f};
  f32x4 acc[4] = {zf, zf, zf, zf};
  int rr = t >> 2, kq = (t & 3) * 16;
  for (int k0 = 0; k0 < KD; k0 += 64) {
    __syncthreads();
    int kk = k0 + kq;
    const float* xsrc = (inB != nullptr && kk >= KD / 2)
                            ? inB + (long)(r0 + rr) * lda + (kk - KD / 2)
                            : inA + (long)(r0 + rr) * lda + kk;
#pragma unroll
    for (int j = 0; j < 4; ++j) {
      float4 v = *(const float4*)(xsrc + 4 * j);
      ushort4v u = {f2b(v.x), f2b(v.y), f2b(v.z), f2b(v.w)};
      *(ushort4v*)&xa[rr][kq + 4 * j] = u;
    }
    const float* wsrc = w + (long)(c0 + rr) * KD + kk;
#pragma unroll
    for (int j = 0; j < 4; ++j) {
      float4 v = *(const float4*)(wsrc + 4 * j);
      ushort4v u = {f2b(v.x), f2b(v.y), f2b(v.z), f2b(v.w)};
      *(ushort4v*)&wb[rr][kq + 4 * j] = u;
    }
    __syncthreads();
#pragma unroll
    for (int ks = 0; ks < 2; ++ks) {
      bf16x8 a = *(const bf16x8*)&xa[wv * 16 + ql][ks * 32 + g * 8];
#pragma unroll
      for (int ct = 0; ct < 4; ++ct) {
        bf16x8 b = *(const bf16x8*)&wb[ct * 16 + ql][ks * 32 + g * 8];
        acc[ct] = __builtin_amdgcn_mfma_f32_16x16x32_bf16(a, b, acc[ct], 0, 0, 0);
      }
    }
  }
  if constexpr (!TOUT) {
#pragma unroll
    for (int ct = 0; ct < 4; ++ct) {
      int col = c0 + ct * 16 + ql;
      float bv = bias[col];
#pragma unroll
      for (int reg = 0; reg < 4; ++reg) {
        long row = r0 + wv * 16 + g * 4 + reg;
        out[row * Cout + col] = acc[ct][reg] + bv;
      }
    }
  } else {
#pragma unroll
    for (int ct = 0; ct < 4; ++ct) {
      int col = ct * 16 + ql;
      float bv = bias[c0 + col];
#pragma unroll
      for (int reg = 0; reg < 4; ++reg)
        tt[col][wv * 16 + g * 4 + reg] = acc[ct][reg] + bv;
    }
    __syncthreads();
    int b = r0 >> 10, n0 = r0 & 1023;
    int col = t >> 2, nq = (t & 3) * 16;
    float* op = out + ((long)(b * 256 + c0 + col)) * 1024 + n0 + nq;
#pragma unroll
    for (int j = 0; j < 4; ++j) {
      float4 v = make_float4(tt[col][nq + 4 * j], tt[col][nq + 4 * j + 1],
                             tt[col][nq + 4 * j + 2], tt[col][nq + 4 * j + 3]);
      *(float4*)(op + 4 * j) = v;
    }
  }
}

// ---------- MFMA GEMM, channel-major activations (B, KD, 1024) ----------
template <int KD>
__global__ __launch_bounds__(256) void k_gemm_cm(const float* __restrict__ in,
                                                 const float* __restrict__ w,
                                                 const float* __restrict__ bias,
                                                 const float* __restrict__ residCM,
                                                 const float* __restrict__ residRM,
                                                 float* __restrict__ outCM,
                                                 float* __restrict__ outRM) {
  __shared__ unsigned short xa[64][72];  // [n][k]
  __shared__ unsigned short wb[64][72];  // [cout][k]
  int rb = blockIdx.x;
  int b = rb >> 4, n0 = (rb & 15) * 64;
  int c0 = blockIdx.y * 64;
  int t = threadIdx.x;
  int wv = t >> 6, lane = t & 63, g = lane >> 4, ql = lane & 15;
  const f32x4 zf = {0.f, 0.f, 0.f, 0.f};
  f32x4 acc[4] = {zf, zf, zf, zf};
  int rr = t >> 2, kq = (t & 3) * 16;
  for (int k0 = 0; k0 < KD; k0 += 64) {
    __syncthreads();
    {
      const float* src = in + ((long)(b * KD + k0 + rr)) * 1024 + n0 + kq;
#pragma unroll
      for (int j = 0; j < 4; ++j) {
        float4 v = *(const float4*)(src + 4 * j);
        xa[kq + 4 * j + 0][rr] = f2b(v.x);
        xa[kq + 4 * j + 1][rr] = f2b(v.y);
        xa[kq + 4 * j + 2][rr] = f2b(v.z);
        xa[kq + 4 * j + 3][rr] = f2b(v.w);
      }
    }
    const float* wsrc = w + (long)(c0 + rr) * KD + k0 + kq;
#pragma unroll
    for (int j = 0; j < 4; ++j) {
      float4 v = *(const float4*)(wsrc + 4 * j);
      ushort4v u = {f2b(v.x), f2b(v.y), f2b(v.z), f2b(v.w)};
      *(ushort4v*)&wb[rr][kq + 4 * j] = u;
    }
    __syncthreads();
#pragma unroll
    for (int ks = 0; ks < 2; ++ks) {
      bf16x8 a = *(const bf16x8*)&xa[wv * 16 + ql][ks * 32 + g * 8];
#pragma unroll
      for (int ct = 0; ct < 4; ++ct) {
        bf16x8 bfr = *(const bf16x8*)&wb[ct * 16 + ql][ks * 32 + g * 8];
        acc[ct] = __builtin_amdgcn_mfma_f32_16x16x32_bf16(a, bfr, acc[ct], 0, 0, 0);
      }
    }
  }
#pragma unroll
  for (int ct = 0; ct < 4; ++ct) {
    int col = c0 + ct * 16 + ql;
    float bv = bias[col];
    if (outCM) {
      long base = ((long)(b * 256 + col)) * 1024 + n0 + wv * 16 + g * 4;
      float4 r4 = *(const float4*)(residCM + base);
      float4 o = make_float4(acc[ct][0] + bv + r4.x, acc[ct][1] + bv + r4.y,
                             acc[ct][2] + bv + r4.z, acc[ct][3] + bv + r4.w);
      *(float4*)(outCM + base) = o;
    } else {
#pragma unroll
      for (int reg = 0; reg < 4; ++reg) {
        long row = (long)b * 1024 + n0 + wv * 16 + g * 4 + reg;
        long idx = row * 256 + col;
        outRM[idx] = acc[ct][reg] + bv + residRM[idx];
      }
    }
  }
}

// ---------- K14: MFMA bf16 flash attention ----------
__global__ __launch_bounds__(256) void k_attn_mfma(const float* __restrict__ qkv,
                                                   float* __restrict__ O) {
  __shared__ unsigned short K_lds[64 * 40];       // [64 keys][32+8 dims]
  __shared__ unsigned short Vt_lds[32 * 72];      // [32 dims][64+8 keys]
  __shared__ unsigned short P_lds[4][16 * 72];    // per wave: [16 q][64+8 keys]
  int bx = blockIdx.x;
  int bh = bx >> 4, qt = bx & 15;
  int b = bh >> 3, h = bh & 7;
  int t = threadIdx.x;
  int w = t >> 6, lane = t & 63;
  int g = lane >> 4, ql = lane & 15;
  const float qscale = 0.17677669529663687f * 1.44269504088896341f;  // 1/sqrt(32) * log2(e)

  bf16x8 q_frag;
  {
    const float* qp = qkv + ((long)(b * N_ + qt * 64 + w * 16 + ql)) * 768 + h * HD_ + g * 8;
#pragma unroll
    for (int i = 0; i < 8; ++i) q_frag[i] = (short)f2b(qp[i] * qscale);
  }
  float m = -1e30f, l = 0.f;
  f32x4 o_acc[2];
  const f32x4 zf = {0.f, 0.f, 0.f, 0.f};
  o_acc[0] = zf; o_acc[1] = zf;

  for (int kt = 0; kt < 16; ++kt) {
    __syncthreads();
    {
      int kr = t >> 2, d0 = (t & 3) * 8;
      const float* gp = qkv + ((long)(b * N_ + kt * 64 + kr)) * 768 + 256 + h * HD_ + d0;
      ushort8v kv;
#pragma unroll
      for (int i = 0; i < 8; ++i) kv[i] = f2b(gp[i]);
      *(ushort8v*)&K_lds[kr * 40 + d0] = kv;
      const float* vp = gp + 256;
#pragma unroll
      for (int i = 0; i < 8; ++i) Vt_lds[(d0 + i) * 72 + kr] = f2b(vp[i]);
    }
    __syncthreads();
    f32x4 s_frag[4];
#pragma unroll
    for (int s = 0; s < 4; ++s) {
      bf16x8 k_frag = *(const bf16x8*)&K_lds[(s * 16 + ql) * 40 + g * 8];
      s_frag[s] = __builtin_amdgcn_mfma_f32_16x16x32_bf16(k_frag, q_frag, zf, 0, 0, 0);
    }
    float sv[16];
#pragma unroll
    for (int s = 0; s < 4; ++s)
#pragma unroll
      for (int r = 0; r < 4; ++r) sv[s * 4 + r] = s_frag[s][r];
    float tmax = sv[0];
#pragma unroll
    for (int i = 1; i < 16; ++i) tmax = fmaxf(tmax, sv[i]);
    tmax = fmaxf(tmax, __shfl_xor(tmax, 16));
    tmax = fmaxf(tmax, __shfl_xor(tmax, 32));
    float mn = fmaxf(m, tmax);
    float corr = exp2f(m - mn);
    float psum = 0.f;
    unsigned short pb[16];
#pragma unroll
    for (int i = 0; i < 16; ++i) {
      float p = exp2f(sv[i] - mn);
      psum += p;
      pb[i] = f2b(p);
    }
    psum += __shfl_xor(psum, 16);
    psum += __shfl_xor(psum, 32);
    l = l * corr + psum;
    m = mn;
#pragma unroll
    for (int mt = 0; mt < 2; ++mt)
#pragma unroll
      for (int r = 0; r < 4; ++r) o_acc[mt][r] *= corr;
#pragma unroll
    for (int s = 0; s < 4; ++s) {
      ushort4v p4 = {pb[s * 4], pb[s * 4 + 1], pb[s * 4 + 2], pb[s * 4 + 3]};
      *(ushort4v*)&P_lds[w][ql * 72 + s * 16 + g * 4] = p4;
    }
#pragma unroll
    for (int c = 0; c < 2; ++c) {
      bf16x8 p_frag = *(const bf16x8*)&P_lds[w][ql * 72 + c * 32 + g * 8];
#pragma unroll
      for (int mt = 0; mt < 2; ++mt) {
        bf16x8 v_frag = *(const bf16x8*)&Vt_lds[(mt * 16 + ql) * 72 + c * 32 + g * 8];
        o_acc[mt] = __builtin_amdgcn_mfma_f32_16x16x32_bf16(v_frag, p_frag, o_acc[mt], 0, 0, 0);
      }
    }
  }
  float inv = 1.f / l;
  float* op = O + ((long)(b * N_ + qt * 64 + w * 16 + ql)) * C_ + h * HD_;
#pragma unroll
  for (int mt = 0; mt < 2; ++mt) {
    float4 o4 = make_float4(o_acc[mt][0] * inv, o_acc[mt][1] * inv,
                            o_acc[mt][2] * inv, o_acc[mt][3] * inv);
    *(float4*)(op + mt * 16 + g * 4) = o4;
  }
}

// ---------- K17: LN(lgn) + exact GELU -> (B,C,N) layout ----------
__global__ __launch_bounds__(256) void k_lngelu(const float* __restrict__ XO,
                                                const float* __restrict__ lw,
                                                const float* __restrict__ lb,
                                                float* __restrict__ XI) {
  __shared__ float red[8];
  int bn = blockIdx.x;
  int b = bn >> 10, n = bn & 1023;
  int c = threadIdx.x;
  float v = XO[(long)bn * C_ + c];
  float2 s = blockReduce2(v, v * v, red);
  float mu = s.x * (1.f / C_);
  float rs = rsqrtf(s.y * (1.f / C_) - mu * mu + 1e-5f);
  float x = (v - mu) * rs * lw[c] + lb[c];
  float ge = 0.5f * x * (1.f + erff(x * 0.70710678118654752f));
  XI[((long)b * C_ + c) * N_ + n] = ge;
}

// ---------- K18: ln over (H,W) per (b,c), in place, no affine ----------
__global__ __launch_bounds__(256) void k_lnhw(float* __restrict__ XI) {
  __shared__ float red[8];
  long base = (long)blockIdx.x * N_;  // b*C + c
  float a = 0.f, b2 = 0.f;
  for (int i = threadIdx.x; i < N_; i += 256) {
    float v = XI[base + i];
    a += v; b2 += v * v;
  }
  float2 s = blockReduce2(a, b2, red);
  float mu = s.x * (1.f / N_);
  float rs = rsqrtf(s.y * (1.f / N_) - mu * mu + 1e-5f);
  for (int i = threadIdx.x; i < N_; i += 256) XI[base + i] = (XI[base + i] - mu) * rs;
}

// ---------- K19: depthwise 3x3 conv on (B,C,32,32), pad 1 ----------
__global__ __launch_bounds__(256) void k_dwc(const float* __restrict__ XI,
                                             const float* __restrict__ w,
                                             const float* __restrict__ bias,
                                             float* __restrict__ XD) {
  long i = (long)blockIdx.x * 256 + threadIdx.x;  // B*C*1024
  int hw = i & 1023;
  int wq = hw & 31, hq = hw >> 5;
  int c = (int)((i >> 10) & 255);
  const float* p = XI + (i - hw);
  const float* wk = w + c * 9;
  float a = bias[c];
#pragma unroll
  for (int kh = 0; kh < 3; ++kh) {
    int h2 = hq + kh - 1;
    if (h2 < 0 || h2 >= 32) continue;
#pragma unroll
    for (int kw = 0; kw < 3; ++kw) {
      int w2 = wq + kw - 1;
      if (w2 < 0 || w2 >= 32) continue;
      a += wk[kh * 3 + kw] * p[h2 * 32 + w2];
    }
  }
  XD[i] = a;
}

extern "C" void kernel_launch(void* const* d_in, const int* in_sizes, int n_in,
                              void* d_out, int out_size, void* d_ws, size_t ws_size,
                              hipStream_t stream) {
  const float* x        = (const float*)d_in[0];
  const float* norm_w   = (const float*)d_in[1];
  const float* norm_b   = (const float*)d_in[2];
  const float* skip     = (const float*)d_in[3];
  const float* m_inw    = (const float*)d_in[4];
  const float* m_convw  = (const float*)d_in[5];
  const float* m_convb  = (const float*)d_in[6];
  const float* m_xpw    = (const float*)d_in[7];
  const float* m_dtw    = (const float*)d_in[8];
  const float* m_dtb    = (const float*)d_in[9];
  const float* m_alog   = (const float*)d_in[10];
  const float* m_d      = (const float*)d_in[11];
  const float* m_outw   = (const float*)d_in[12];
  const float* qdw_w    = (const float*)d_in[13];
  const float* qdw_b    = (const float*)d_in[14];
  const float* qpw_w    = (const float*)d_in[15];
  const float* qpw_b    = (const float*)d_in[16];
  const float* rdw_w    = (const float*)d_in[17];
  const float* rdw_b    = (const float*)d_in[18];
  const float* rpw_w    = (const float*)d_in[19];
  const float* rpw_b    = (const float*)d_in[20];
  const float* fdw_w    = (const float*)d_in[21];
  const float* fdw_b    = (const float*)d_in[22];
  const float* fpw_w    = (const float*)d_in[23];
  const float* fpw_b    = (const float*)d_in[24];
  const float* lc_w     = (const float*)d_in[25];
  const float* lc_b     = (const float*)d_in[26];
  const float* attn_inw = (const float*)d_in[27];
  const float* attn_inb = (const float*)d_in[28];
  const float* attn_outw= (const float*)d_in[29];
  const float* attn_outb= (const float*)d_in[30];
  const float* lgn_w    = (const float*)d_in[31];
  const float* lgn_b    = (const float*)d_in[32];
  const float* fc_w     = (const float*)d_in[33];
  const float* fc_b     = (const float*)d_in[34];
  const float* dwc_w    = (const float*)d_in[35];
  const float* dwc_b    = (const float*)d_in[36];
  const float* proj_w   = (const float*)d_in[37];
  const float* proj_b   = (const float*)d_in[38];
  float* out = (float*)d_out;

  float* ws = (float*)d_ws;
  const size_t F = 1048576;  // B*N*C
  float* XS  = ws + 0 * F;
  float* XN  = ws + 1 * F;
  float* U   = ws + 2 * F;
  float* Z   = ws + 4 * F;
  float* DT  = ws + 6 * F;
  float* BM  = ws + 8 * F;
  float* CM  = ws + 8 * F + F / 4;
  float* XMC = ws + 8 * F + F / 2;
  float* SC_APROD = ws + 8 * F + F / 2;            // scan scratch (XMC region, dead then)
  float* SC_HEND  = ws + 9 * F;
  float* G   = ws + 1 * F;
  float* XG  = ws + 2 * F;
  float* RD  = ws + 3 * F;
  float* RB  = ws + 4 * F;
  float* XM2 = ws + 5 * F;
  float* YDW = ws + 6 * F;
  float* XL  = ws + 0 * F;
  float* QKV = ws + 1 * F;
  float* O   = ws + 4 * F;
  float* XGL = ws + 6 * F;
  float* XO  = ws + 7 * F;
  float* XI  = ws + 8 * F;
  float* XD  = ws + 5 * F;
  float* LNF = ws + 0 * F;
  (void)ws_size; (void)in_sizes; (void)n_in; (void)out_size;

  k_ln_t<<<4096, 256, 0, stream>>>(x, norm_w, norm_b, XN, XS);
  k_inproj<<<dim3(64, 4), 256, 0, stream>>>(XN, m_inw, U, Z);
  k_causal<<<2048, 256, 0, stream>>>(U, m_convw, m_convb);
  k_xdbc<<<2048, 128, 0, stream>>>(U, m_xpw, m_dtw, m_dtb, DT, BM, CM);
  k_scanA<<<512, 256, 0, stream>>>(DT, U, BM, m_alog, SC_APROD, SC_HEND);
  k_scanB<<<128, 256, 0, stream>>>(SC_APROD, SC_HEND);
  k_scanC<<<512, 256, 0, stream>>>(DT, U, BM, CM, m_alog, m_d, SC_APROD);
  k_outproj<<<1024, 256, 0, stream>>>(DT, Z, m_outw, XN, skip, XMC);
  k_gate<<<256, 256, 0, stream>>>(XMC, qdw_w, qdw_b, qpw_w, qpw_b, G);
  k_xg<<<4096, 256, 0, stream>>>(XMC, G, XG);
  k_dw3<<<4096, 256, 0, stream>>>(XG, rdw_w, rdw_b, RD, 256);
  k_gemm_cm<256><<<dim3(64, 4), 256, 0, stream>>>(RD, rpw_w, rpw_b, XG, nullptr, RB, nullptr);
  k_fdw<<<8192, 256, 0, stream>>>(XS, RB, fdw_w, fdw_b, YDW);
  k_gemm_cm<512><<<dim3(64, 4), 256, 0, stream>>>(YDW, fpw_w, fpw_b, nullptr, XS, nullptr, XM2);
  k_lc<<<4096, 256, 0, stream>>>(XM2, lc_w, lc_b, XL);
  k_gemm_rm<256, false><<<dim3(64, 12), 256, 0, stream>>>(XM2, nullptr, attn_inw, attn_inb, QKV, 768, 256);
  k_attn_mfma<<<512, 256, 0, stream>>>(QKV, O);
  k_gemm_rm<256, false><<<dim3(64, 4), 256, 0, stream>>>(O, nullptr, attn_outw, attn_outb, XGL, 256, 256);
  k_gemm_rm<512, false><<<dim3(64, 4), 256, 0, stream>>>(XL, XGL, fc_w, fc_b, XO, 256, 256);
  k_lngelu<<<4096, 256, 0, stream>>>(XO, lgn_w, lgn_b, XI);
  k_lnhw<<<1024, 256, 0, stream>>>(XI);
  k_dwc<<<4096, 256, 0, stream>>>(XI, dwc_w, dwc_b, XD);
  k_ln_t<<<4096, 256, 0, stream>>>(XD, norm_w, norm_b, LNF, nullptr);
  k_gemm_rm<256, true><<<dim3(64, 4), 256, 0, stream>>>(LNF, nullptr, proj_w, proj_b, out, 256, 256);
}

// Round 7
// 269.403 us; speedup vs baseline: 4.3289x; 1.1652x over previous
//
#include <hip/hip_runtime.h>
#include <math.h>

// MambaLiteUNet — round 6: coalescing pass. LDS-tile LN transpose (x2), k_fdw reads x
// directly, out-of-place causal conv, full-lane xdbc, tiled k_xg transpose, tiled lngelu.

namespace {
constexpr int NB_ = 4, DM_ = 64, DIN_ = 128, DS_ = 16, DTR_ = 4;
constexpr int C_ = 256, N_ = 1024, B_ = 4, HD_ = 32;
constexpr int NCH = 16, LCH = 64;          // scan: 16 time-chunks of 64
constexpr int NSTATE = 16 * 128 * 16;      // nbb * DIN * DS = 32768
}

typedef __attribute__((ext_vector_type(8))) short bf16x8;
typedef __attribute__((ext_vector_type(4))) float f32x4;
typedef __attribute__((ext_vector_type(8))) unsigned short ushort8v;
typedef __attribute__((ext_vector_type(4))) unsigned short ushort4v;

// ---------- helpers ----------
__device__ __forceinline__ unsigned short f2b(float f) {  // fp32 -> bf16 RNE
  unsigned int u = __float_as_uint(f);
  unsigned int r = u + 0x7FFFu + ((u >> 16) & 1u);
  return (unsigned short)(r >> 16);
}

__device__ __forceinline__ float siluf(float x) { return x / (1.f + expf(-x)); }
__device__ __forceinline__ float sigmf(float x) { return 1.f / (1.f + expf(-x)); }
__device__ __forceinline__ float softplusf(float x) {
  return fmaxf(x, 0.f) + log1pf(expf(-fabsf(x)));
}

// ---------- K1/K20a: LN over C of (B,C,N) -> (B,N,C), coalesced LDS-tile version ----------
// grid: B * (N/16) = 256; block 256 (thread = c).
__global__ __launch_bounds__(256) void k_ln_t2(const float* __restrict__ in,
                                               const float* __restrict__ w,
                                               const float* __restrict__ bias,
                                               float* __restrict__ out_ln,
                                               float* __restrict__ out_copy) {
  __shared__ float tile[256][17];
  __shared__ float redp[16][16][2];
  __shared__ float stats[16][2];
  int bx = blockIdx.x;
  int b = bx >> 6, n0 = (bx & 63) * 16;
  int c = threadIdx.x;
  {
    const float* p = in + ((long)(b * C_ + c)) * N_ + n0;
#pragma unroll
    for (int j = 0; j < 16; ++j) tile[c][j] = p[j];
  }
  __syncthreads();
  {
    int n = c & 15, g = c >> 4;
    float a = 0.f, q = 0.f;
#pragma unroll
    for (int i = 0; i < 16; ++i) {
      float v = tile[g * 16 + i][n];
      a += v; q += v * v;
    }
    redp[g][n][0] = a; redp[g][n][1] = q;
  }
  __syncthreads();
  if (c < 16) {
    float a = 0.f, q = 0.f;
#pragma unroll
    for (int g2 = 0; g2 < 16; ++g2) { a += redp[g2][c][0]; q += redp[g2][c][1]; }
    float mu = a * (1.f / C_);
    float rs = rsqrtf(q * (1.f / C_) - mu * mu + 1e-5f);
    stats[c][0] = mu; stats[c][1] = rs;
  }
  __syncthreads();
  float wv = w[c], bv = bias[c];
#pragma unroll
  for (int j = 0; j < 16; ++j) {
    float v = tile[c][j];
    long o = ((long)(b * N_ + n0 + j)) * C_ + c;
    if (out_copy) out_copy[o] = v;
    out_ln[o] = (v - stats[j][0]) * stats[j][1] * wv + bv;
  }
}

// ---------- K2: mamba in-proj  xz = xn_block @ inw^T  -> u_pre, z ----------
__global__ __launch_bounds__(256) void k_inproj(const float* __restrict__ xn,
                                                const float* __restrict__ inw,
                                                float* __restrict__ UPRE, float* __restrict__ Z) {
  __shared__ float xrows[4][64];
  int nb = blockIdx.y;
  int j = threadIdx.x;                       // output col 0..255
  const float* wp = inw + ((long)nb * 2 * DIN_ + j) * DM_;
  float wreg[64];
#pragma unroll
  for (int m = 0; m < 64; ++m) wreg[m] = wp[m];
  int row0 = blockIdx.x * 64;                // over B*N = 4096 rows
  for (int r0 = 0; r0 < 64; r0 += 4) {
    __syncthreads();
    {
      int rr = threadIdx.x >> 6, m = threadIdx.x & 63;
      xrows[rr][m] = xn[(long)(row0 + r0 + rr) * C_ + nb * DM_ + m];
    }
    __syncthreads();
    for (int rr = 0; rr < 4; ++rr) {
      float acc = 0.f;
#pragma unroll
      for (int m = 0; m < 64; ++m) acc += xrows[rr][m] * wreg[m];
      long row = (long)nb * (B_ * N_) + row0 + r0 + rr;
      if (j < DIN_) UPRE[row * DIN_ + j] = acc;
      else          Z[row * DIN_ + (j - DIN_)] = acc;
    }
  }
}

// ---------- K3: causal depthwise conv (K=4) + silu, out-of-place, coalesced ----------
// grid: nbb(16) x nchunk(32) = 512; block 256 = 128 d x 2 n-halves.
__global__ __launch_bounds__(256) void k_causal(const float* __restrict__ Uin,
                                                float* __restrict__ Uout,
                                                const float* __restrict__ cw,
                                                const float* __restrict__ cb) {
  __shared__ float u_s[35][128];
  int bx = blockIdx.x;
  int nbb = bx >> 5, chk = bx & 31;
  int nb = nbb >> 2;
  int n0 = chk * 32;
  const float* ibase = Uin + (long)nbb * N_ * DIN_;
  float* obase = Uout + (long)nbb * N_ * DIN_;
  for (int i = threadIdx.x; i < 35 * 32; i += 256) {
    int row = i >> 5, q = i & 31;
    int n = n0 - 3 + row;
    float4 v = (n >= 0) ? *(const float4*)&ibase[(long)n * DIN_ + q * 4]
                        : make_float4(0.f, 0.f, 0.f, 0.f);
    *(float4*)&u_s[row][q * 4] = v;
  }
  __syncthreads();
  int d = threadIdx.x & 127, half = threadIdx.x >> 7;
  float w0 = cw[(nb * DIN_ + d) * 4 + 0], w1 = cw[(nb * DIN_ + d) * 4 + 1];
  float w2 = cw[(nb * DIN_ + d) * 4 + 2], w3 = cw[(nb * DIN_ + d) * 4 + 3];
  float bv = cb[nb * DIN_ + d];
#pragma unroll
  for (int j = 0; j < 16; ++j) {
    int nn = half * 16 + j;
    float acc = bv + w3 * u_s[nn + 3][d] + w2 * u_s[nn + 2][d] +
                w1 * u_s[nn + 1][d] + w0 * u_s[nn][d];
    obase[(long)(n0 + nn) * DIN_ + d] = siluf(acc);
  }
}

// ---------- K4: xdbc / dt / Bm / Cm — full-lane version ----------
// grid: 1024 blocks x 16 rows; block 256.
__global__ __launch_bounds__(256) void k_xdbc(const float* __restrict__ U,
                                              const float* __restrict__ xpw,
                                              const float* __restrict__ dtw,
                                              const float* __restrict__ dtb,
                                              float* __restrict__ DT,
                                              float* __restrict__ BMb, float* __restrict__ CMb) {
  __shared__ float wl[36][129];
  __shared__ float u16[16][129];
  __shared__ float xd_s[16][37];
  __shared__ float dtw_s[128][4];
  __shared__ float dtb_s[128];
  int t = threadIdx.x;
  long row0 = (long)blockIdx.x * 16;
  int nb = blockIdx.x >> 8;
  for (int i = t; i < 36 * 128; i += 256) wl[i >> 7][i & 127] = xpw[nb * 36 * 128 + i];
  for (int i = t; i < 16 * 128; i += 256) u16[i >> 7][i & 127] = U[(row0 + (i >> 7)) * DIN_ + (i & 127)];
  for (int i = t; i < 512; i += 256) dtw_s[i >> 2][i & 3] = dtw[nb * 512 + i];
  if (t < 128) dtb_s[t] = dtb[nb * DIN_ + t];
  __syncthreads();
  {
    int r = t >> 4, jl = t & 15;
    float a0 = 0.f, a1 = 0.f, a2 = 0.f;
    for (int k = 0; k < 128; ++k) {
      float uv = u16[r][k];
      a0 += uv * wl[jl][k];
      a1 += uv * wl[jl + 16][k];
      if (jl < 4) a2 += uv * wl[jl + 32][k];
    }
    xd_s[r][jl] = a0;
    xd_s[r][jl + 16] = a1;
    if (jl < 4) xd_s[r][jl + 32] = a2;
  }
  __syncthreads();
  {
    int r = t >> 4, s = t & 15;
    BMb[(row0 + r) * DS_ + s] = xd_s[r][4 + s];
    CMb[(row0 + r) * DS_ + s] = xd_s[r][20 + s];
  }
  {
    int r = t >> 4, dl = t & 15;
    float x0 = xd_s[r][0], x1 = xd_s[r][1], x2 = xd_s[r][2], x3 = xd_s[r][3];
#pragma unroll
    for (int dd = 0; dd < 8; ++dd) {
      int d = dl * 8 + dd;
      float a = dtb_s[d] + x0 * dtw_s[d][0] + x1 * dtw_s[d][1] +
                x2 * dtw_s[d][2] + x3 * dtw_s[d][3];
      DT[(row0 + r) * DIN_ + d] = softplusf(a);
    }
  }
}

// ---------- K5a: scan phase A — thread owns (d, 4 s-states) ----------
__global__ __launch_bounds__(256) void k_scanA(const float* __restrict__ DT,
                                               const float* __restrict__ U,
                                               const float* __restrict__ BMb,
                                               const float* __restrict__ alog,
                                               float* __restrict__ Aprod,
                                               float* __restrict__ Hend) {
  __shared__ float dt_s[64][64];
  __shared__ float u_s[64][64];
  __shared__ float bm_s[64][16];
  int bx = blockIdx.x;
  int chunk = bx >> 5, rem = bx & 31, nbb = rem >> 1, dh = rem & 1;
  int nb = nbb >> 2;
  int t = threadIdx.x;
  int dl = t >> 2, sg = t & 3;
  int d = dh * 64 + dl;
  long base = (long)nbb * N_ + chunk * LCH;
#pragma unroll
  for (int j = 0; j < 4; ++j) {
    int f = t + 256 * j;
    int tt = f >> 4, dq = (f & 15) * 4;
    long src = (base + tt) * DIN_ + dh * 64 + dq;
    *(float4*)&dt_s[tt][dq] = *(const float4*)&DT[src];
    *(float4*)&u_s[tt][dq]  = *(const float4*)&U[src];
  }
  {
    int tt = t >> 2, sq = (t & 3) * 4;
    *(float4*)&bm_s[tt][sq] = *(const float4*)&BMb[(base + tt) * DS_ + sq];
  }
  float A[4];
#pragma unroll
  for (int i = 0; i < 4; ++i)
    A[i] = -expf(alog[(nb * DIN_ + d) * DS_ + sg * 4 + i]);
  __syncthreads();
  float h[4] = {0.f, 0.f, 0.f, 0.f};
  float ap[4] = {1.f, 1.f, 1.f, 1.f};
  for (int tt = 0; tt < LCH; ++tt) {
    float dtv = dt_s[tt][dl];
    float uv  = u_s[tt][dl];
    float cc = dtv * uv;
    float4 bm4 = *(const float4*)&bm_s[tt][sg * 4];
    float bmv[4] = {bm4.x, bm4.y, bm4.z, bm4.w};
#pragma unroll
    for (int i = 0; i < 4; ++i) {
      float dA = __expf(dtv * A[i]);
      h[i] = dA * h[i] + cc * bmv[i];
      ap[i] *= dA;
    }
  }
  long st = (long)chunk * NSTATE + ((nbb << 7) + d) * 16 + sg * 4;
  *(float4*)&Aprod[st] = make_float4(ap[0], ap[1], ap[2], ap[3]);
  *(float4*)&Hend[st]  = make_float4(h[0], h[1], h[2], h[3]);
}

// ---------- K5b: scan phase B ----------
__global__ __launch_bounds__(256) void k_scanB(float* __restrict__ Aprod,
                                               const float* __restrict__ Hend) {
  int state = blockIdx.x * 256 + threadIdx.x;
  float H = 0.f;
#pragma unroll
  for (int c = 0; c < NCH; ++c) {
    long idx = (long)c * NSTATE + state;
    float a = Aprod[idx];
    float e = Hend[idx];
    Aprod[idx] = H;            // Hin for chunk c
    H = e + a * H;
  }
}

// ---------- K5c: scan phase C ----------
__global__ __launch_bounds__(256) void k_scanC(float* __restrict__ DT,
                                               const float* __restrict__ U,
                                               const float* __restrict__ BMb,
                                               const float* __restrict__ CMb,
                                               const float* __restrict__ alog,
                                               const float* __restrict__ Dp,
                                               const float* __restrict__ Hin) {
  __shared__ float dt_s[64][64];
  __shared__ float u_s[64][64];
  __shared__ float bm_s[64][16];
  __shared__ float cm_s[64][16];
  int bx = blockIdx.x;
  int chunk = bx >> 5, rem = bx & 31, nbb = rem >> 1, dh = rem & 1;
  int nb = nbb >> 2;
  int t = threadIdx.x;
  int dl = t >> 2, sg = t & 3;
  int d = dh * 64 + dl;
  long base = (long)nbb * N_ + chunk * LCH;
#pragma unroll
  for (int j = 0; j < 4; ++j) {
    int f = t + 256 * j;
    int tt = f >> 4, dq = (f & 15) * 4;
    long src = (base + tt) * DIN_ + dh * 64 + dq;
    *(float4*)&dt_s[tt][dq] = *(const float4*)&DT[src];
    *(float4*)&u_s[tt][dq]  = *(const float4*)&U[src];
  }
  {
    int tt = t >> 2, sq = (t & 3) * 4;
    *(float4*)&bm_s[tt][sq] = *(const float4*)&BMb[(base + tt) * DS_ + sq];
    *(float4*)&cm_s[tt][sq] = *(const float4*)&CMb[(base + tt) * DS_ + sq];
  }
  float A[4];
#pragma unroll
  for (int i = 0; i < 4; ++i)
    A[i] = -expf(alog[(nb * DIN_ + d) * DS_ + sg * 4 + i]);
  float Dv = Dp[nb * DIN_ + d];
  float h[4];
  {
    long st = (long)chunk * NSTATE + ((nbb << 7) + d) * 16 + sg * 4;
    float4 h4 = *(const float4*)&Hin[st];
    h[0] = h4.x; h[1] = h4.y; h[2] = h4.z; h[3] = h4.w;
  }
  __syncthreads();
  for (int tt = 0; tt < LCH; ++tt) {
    float dtv = dt_s[tt][dl];
    float uv  = u_s[tt][dl];
    float cc = dtv * uv;
    float4 bm4 = *(const float4*)&bm_s[tt][sg * 4];
    float4 cm4 = *(const float4*)&cm_s[tt][sg * 4];
    float bmv[4] = {bm4.x, bm4.y, bm4.z, bm4.w};
    float cmv[4] = {cm4.x, cm4.y, cm4.z, cm4.w};
    float p = 0.f;
#pragma unroll
    for (int i = 0; i < 4; ++i) {
      float dA = __expf(dtv * A[i]);
      h[i] = dA * h[i] + cc * bmv[i];
      p += h[i] * cmv[i];
    }
    p += __shfl_xor(p, 1, 64);
    p += __shfl_xor(p, 2, 64);
    if (sg == 0) DT[(base + tt) * DIN_ + d] = p + Dv * uv;
  }
}

// ---------- K6: y2 = y*silu(z); xm = y2 @ outw^T + skip*xn -> (B,N,C) concat ----------
__global__ __launch_bounds__(256) void k_outproj(const float* __restrict__ Y,
                                                 const float* __restrict__ Z,
                                                 const float* __restrict__ outw,
                                                 const float* __restrict__ xn,
                                                 const float* __restrict__ skip,
                                                 float* __restrict__ XMC) {
  __shared__ float wL[64][129];
  __shared__ float y2r[16][128];
  int row0 = blockIdx.x * 16;                // over NB*B*N = 16384 rows
  int nb = row0 >> 12;
  for (int i = threadIdx.x; i < 64 * 128; i += 256) {
    int col = i >> 7, j = i & 127;
    wL[col][j] = outw[nb * DM_ * DIN_ + i];
  }
  for (int i = threadIdx.x; i < 16 * 128; i += 256) {
    int r = i >> 7, j = i & 127;
    long row = (long)row0 + r;
    float z = Z[row * DIN_ + j];
    y2r[r][j] = Y[row * DIN_ + j] * siluf(z);
  }
  __syncthreads();
  float sk = skip[0];
  int col = threadIdx.x & 63;
  int rbase = threadIdx.x >> 6;
  for (int ii = 0; ii < 4; ++ii) {
    int rr = rbase + ii * 4;
    float acc = 0.f;
#pragma unroll 8
    for (int j = 0; j < 128; ++j) acc += y2r[rr][j] * wL[col][j];
    int bn = (row0 + rr) & 4095;
    long oc = (long)bn * C_ + nb * DM_ + col;
    XMC[oc] = acc + sk * xn[oc];
  }
}

// ---------- K7: gate ----------
__global__ __launch_bounds__(256) void k_gate(const float* __restrict__ XMC,
                                              const float* __restrict__ qdw_w,
                                              const float* __restrict__ qdw_b,
                                              const float* __restrict__ qpw_w,
                                              const float* __restrict__ qpw_b,
                                              float* __restrict__ G) {
  int t = threadIdx.x;
  int gid = (blockIdx.x * 256 + t) >> 4;     // b*N + n
  int cq = t & 3, p = (t >> 2) & 3;
  int b = gid >> 10, n = gid & 1023;
  float a = 0.f;
#pragma unroll
  for (int k = 0; k < 3; ++k) {
    int nn = n + k - 1;
    if (nn < 0 || nn >= N_) continue;
    const float* xr = XMC + ((long)b * N_ + nn) * C_ + p * 64 + cq * 16;
    const float* wr = qdw_w + (p * 64 + cq * 16) * 3 + k;
#pragma unroll
    for (int i = 0; i < 16; ++i) a += xr[i] * wr[i * 3];
  }
  a += __shfl_xor(a, 1, 64);
  a += __shfl_xor(a, 2, 64);
  float q1 = a + qdw_b[p];
  int lane = t & 63;
  float q1g[4];
#pragma unroll
  for (int pp = 0; pp < 4; ++pp) q1g[pp] = __shfl(q1, (lane & ~12) | (pp << 2), 64);
  int o = p;
  float r = qpw_b[o];
#pragma unroll
  for (int pp = 0; pp < 4; ++pp) r += qpw_w[o * 4 + pp] * q1g[pp];
  if (cq == 0) G[((long)b * 4 + o) * N_ + n] = sigmf(r);
}

// ---------- K8: xg (B,C,N) = g * xm — LDS tile transpose ----------
// grid: b(4) x ct(4) x nt(16) = 256; block 256.
__global__ __launch_bounds__(256) void k_xg(const float* __restrict__ XMC,
                                            const float* __restrict__ G,
                                            float* __restrict__ XG) {
  __shared__ float tile[64][65];
  int bx = blockIdx.x;
  int b = bx >> 6, ct = (bx >> 4) & 3, nt = bx & 15;
  int c0 = ct * 64, n0 = nt * 64;
  int t = threadIdx.x;
  {
    int cc = t & 63, nq = t >> 6;
#pragma unroll
    for (int j = 0; j < 16; ++j) {
      int nn = nq * 16 + j;
      tile[cc][nn] = XMC[((long)(b * N_ + n0 + nn)) * C_ + c0 + cc];
    }
  }
  __syncthreads();
  {
    int nl = t & 63, cq = t >> 6;
    float g = G[((long)(b * 4 + ct)) * N_ + n0 + nl];
#pragma unroll
    for (int j = 0; j < 16; ++j) {
      int cl = cq * 16 + j;
      XG[((long)(b * C_ + c0 + cl)) * N_ + n0 + nl] = g * tile[cl][nl];
    }
  }
}

// ---------- generic 3-tap depthwise conv over n, (B,nchan,N) layout ----------
__global__ __launch_bounds__(256) void k_dw3(const float* __restrict__ in,
                                             const float* __restrict__ w,
                                             const float* __restrict__ bias,
                                             float* __restrict__ out, int nchan) {
  long i = (long)blockIdx.x * 256 + threadIdx.x;
  if (i >= (long)B_ * nchan * N_) return;
  int n = i & 1023;
  int c = (int)((i >> 10) % nchan);
  const float* r = in + (i - n);
  float a = bias[c] + w[c * 3 + 1] * r[n];
  if (n > 0)      a += w[c * 3 + 0] * r[n - 1];
  if (n < N_ - 1) a += w[c * 3 + 2] * r[n + 1];
  out[i] = a;
}

// ---------- K10: depthwise conv over virtual cat = [x ; R] (B,512,N), reads x directly ----------
__global__ __launch_bounds__(256) void k_fdw(const float* __restrict__ Xraw,
                                             const float* __restrict__ RB,
                                             const float* __restrict__ w,
                                             const float* __restrict__ bias,
                                             float* __restrict__ YDW) {
  long i = (long)blockIdx.x * 256 + threadIdx.x;  // B*512*N
  int n = i & 1023;
  long bc = i >> 10;
  int cc = bc & 511, b = (int)(bc >> 9);
  const float* p = (cc < C_) ? (Xraw + ((long)(b * C_ + cc)) * N_)
                             : (RB + ((long)(b * C_ + cc - C_)) * N_);
  float a = bias[cc] + w[cc * 3 + 1] * p[n];
  if (n > 0)      a += w[cc * 3 + 0] * p[n - 1];
  if (n < N_ - 1) a += w[cc * 3 + 2] * p[n + 1];
  YDW[i] = a;
}

// ---------- K12: x_local depthwise over n in (B,N,C) layout ----------
__global__ __launch_bounds__(256) void k_lc(const float* __restrict__ XM2,
                                            const float* __restrict__ w,
                                            const float* __restrict__ bias,
                                            float* __restrict__ XL) {
  long i = (long)blockIdx.x * 256 + threadIdx.x;  // B*N*C, c fastest
  int c = i & 255;
  long bn = i >> 8;
  int n = bn & 1023, b = (int)(bn >> 10);
  const float* p = XM2 + (long)b * N_ * C_ + c;
  float a = bias[c] + w[c * 3 + 1] * p[(long)n * C_];
  if (n > 0)      a += w[c * 3 + 0] * p[(long)(n - 1) * C_];
  if (n < N_ - 1) a += w[c * 3 + 2] * p[(long)(n + 1) * C_];
  XL[i] = a;
}

// ---------- MFMA GEMM, row-major activations ----------
template <int KD, bool TOUT>
__global__ __launch_bounds__(256) void k_gemm_rm(const float* __restrict__ inA,
                                                 const float* __restrict__ inB,
                                                 const float* __restrict__ w,
                                                 const float* __restrict__ bias,
                                                 float* __restrict__ out,
                                                 int Cout, int lda) {
  __shared__ unsigned short xa[64][72];
  __shared__ unsigned short wb[64][72];
  __shared__ float tt[TOUT ? 64 : 1][TOUT ? 68 : 1];
  int r0 = blockIdx.x * 64;
  int c0 = blockIdx.y * 64;
  int t = threadIdx.x;
  int wv = t >> 6, lane = t & 63, g = lane >> 4, ql = lane & 15;
  const f32x4 zf = {0.f, 0.f, 0.f, 0.f};
  f32x4 acc[4] = {zf, zf, zf, zf};
  int rr = t >> 2, kq = (t & 3) * 16;
  for (int k0 = 0; k0 < KD; k0 += 64) {
    __syncthreads();
    int kk = k0 + kq;
    const float* xsrc = (inB != nullptr && kk >= KD / 2)
                            ? inB + (long)(r0 + rr) * lda + (kk - KD / 2)
                            : inA + (long)(r0 + rr) * lda + kk;
#pragma unroll
    for (int j = 0; j < 4; ++j) {
      float4 v = *(const float4*)(xsrc + 4 * j);
      ushort4v u = {f2b(v.x), f2b(v.y), f2b(v.z), f2b(v.w)};
      *(ushort4v*)&xa[rr][kq + 4 * j] = u;
    }
    const float* wsrc = w + (long)(c0 + rr) * KD + kk;
#pragma unroll
    for (int j = 0; j < 4; ++j) {
      float4 v = *(const float4*)(wsrc + 4 * j);
      ushort4v u = {f2b(v.x), f2b(v.y), f2b(v.z), f2b(v.w)};
      *(ushort4v*)&wb[rr][kq + 4 * j] = u;
    }
    __syncthreads();
#pragma unroll
    for (int ks = 0; ks < 2; ++ks) {
      bf16x8 a = *(const bf16x8*)&xa[wv * 16 + ql][ks * 32 + g * 8];
#pragma unroll
      for (int ct = 0; ct < 4; ++ct) {
        bf16x8 b = *(const bf16x8*)&wb[ct * 16 + ql][ks * 32 + g * 8];
        acc[ct] = __builtin_amdgcn_mfma_f32_16x16x32_bf16(a, b, acc[ct], 0, 0, 0);
      }
    }
  }
  if constexpr (!TOUT) {
#pragma unroll
    for (int ct = 0; ct < 4; ++ct) {
      int col = c0 + ct * 16 + ql;
      float bv = bias[col];
#pragma unroll
      for (int reg = 0; reg < 4; ++reg) {
        long row = r0 + wv * 16 + g * 4 + reg;
        out[row * Cout + col] = acc[ct][reg] + bv;
      }
    }
  } else {
#pragma unroll
    for (int ct = 0; ct < 4; ++ct) {
      int col = ct * 16 + ql;
      float bv = bias[c0 + col];
#pragma unroll
      for (int reg = 0; reg < 4; ++reg)
        tt[col][wv * 16 + g * 4 + reg] = acc[ct][reg] + bv;
    }
    __syncthreads();
    int b = r0 >> 10, n0 = r0 & 1023;
    int col = t >> 2, nq = (t & 3) * 16;
    float* op = out + ((long)(b * 256 + c0 + col)) * 1024 + n0 + nq;
#pragma unroll
    for (int j = 0; j < 4; ++j) {
      float4 v = make_float4(tt[col][nq + 4 * j], tt[col][nq + 4 * j + 1],
                             tt[col][nq + 4 * j + 2], tt[col][nq + 4 * j + 3]);
      *(float4*)(op + 4 * j) = v;
    }
  }
}

// ---------- MFMA GEMM, channel-major activations (B, KD, 1024) ----------
template <int KD>
__global__ __launch_bounds__(256) void k_gemm_cm(const float* __restrict__ in,
                                                 const float* __restrict__ w,
                                                 const float* __restrict__ bias,
                                                 const float* __restrict__ residCM,
                                                 const float* __restrict__ residRM,
                                                 float* __restrict__ outCM,
                                                 float* __restrict__ outRM) {
  __shared__ unsigned short xa[64][72];  // [n][k]
  __shared__ unsigned short wb[64][72];  // [cout][k]
  int rb = blockIdx.x;
  int b = rb >> 4, n0 = (rb & 15) * 64;
  int c0 = blockIdx.y * 64;
  int t = threadIdx.x;
  int wv = t >> 6, lane = t & 63, g = lane >> 4, ql = lane & 15;
  const f32x4 zf = {0.f, 0.f, 0.f, 0.f};
  f32x4 acc[4] = {zf, zf, zf, zf};
  int rr = t >> 2, kq = (t & 3) * 16;
  for (int k0 = 0; k0 < KD; k0 += 64) {
    __syncthreads();
    {
      const float* src = in + ((long)(b * KD + k0 + rr)) * 1024 + n0 + kq;
#pragma unroll
      for (int j = 0; j < 4; ++j) {
        float4 v = *(const float4*)(src + 4 * j);
        xa[kq + 4 * j + 0][rr] = f2b(v.x);
        xa[kq + 4 * j + 1][rr] = f2b(v.y);
        xa[kq + 4 * j + 2][rr] = f2b(v.z);
        xa[kq + 4 * j + 3][rr] = f2b(v.w);
      }
    }
    const float* wsrc = w + (long)(c0 + rr) * KD + k0 + kq;
#pragma unroll
    for (int j = 0; j < 4; ++j) {
      float4 v = *(const float4*)(wsrc + 4 * j);
      ushort4v u = {f2b(v.x), f2b(v.y), f2b(v.z), f2b(v.w)};
      *(ushort4v*)&wb[rr][kq + 4 * j] = u;
    }
    __syncthreads();
#pragma unroll
    for (int ks = 0; ks < 2; ++ks) {
      bf16x8 a = *(const bf16x8*)&xa[wv * 16 + ql][ks * 32 + g * 8];
#pragma unroll
      for (int ct = 0; ct < 4; ++ct) {
        bf16x8 bfr = *(const bf16x8*)&wb[ct * 16 + ql][ks * 32 + g * 8];
        acc[ct] = __builtin_amdgcn_mfma_f32_16x16x32_bf16(a, bfr, acc[ct], 0, 0, 0);
      }
    }
  }
#pragma unroll
  for (int ct = 0; ct < 4; ++ct) {
    int col = c0 + ct * 16 + ql;
    float bv = bias[col];
    if (outCM) {
      long base = ((long)(b * 256 + col)) * 1024 + n0 + wv * 16 + g * 4;
      float4 r4 = *(const float4*)(residCM + base);
      float4 o = make_float4(acc[ct][0] + bv + r4.x, acc[ct][1] + bv + r4.y,
                             acc[ct][2] + bv + r4.z, acc[ct][3] + bv + r4.w);
      *(float4*)(outCM + base) = o;
    } else {
#pragma unroll
      for (int reg = 0; reg < 4; ++reg) {
        long row = (long)b * 1024 + n0 + wv * 16 + g * 4 + reg;
        long idx = row * 256 + col;
        outRM[idx] = acc[ct][reg] + bv + residRM[idx];
      }
    }
  }
}

// ---------- K14: MFMA bf16 flash attention ----------
__global__ __launch_bounds__(256) void k_attn_mfma(const float* __restrict__ qkv,
                                                   float* __restrict__ O) {
  __shared__ unsigned short K_lds[64 * 40];       // [64 keys][32+8 dims]
  __shared__ unsigned short Vt_lds[32 * 72];      // [32 dims][64+8 keys]
  __shared__ unsigned short P_lds[4][16 * 72];    // per wave: [16 q][64+8 keys]
  int bx = blockIdx.x;
  int bh = bx >> 4, qt = bx & 15;
  int b = bh >> 3, h = bh & 7;
  int t = threadIdx.x;
  int w = t >> 6, lane = t & 63;
  int g = lane >> 4, ql = lane & 15;
  const float qscale = 0.17677669529663687f * 1.44269504088896341f;

  bf16x8 q_frag;
  {
    const float* qp = qkv + ((long)(b * N_ + qt * 64 + w * 16 + ql)) * 768 + h * HD_ + g * 8;
#pragma unroll
    for (int i = 0; i < 8; ++i) q_frag[i] = (short)f2b(qp[i] * qscale);
  }
  float m = -1e30f, l = 0.f;
  f32x4 o_acc[2];
  const f32x4 zf = {0.f, 0.f, 0.f, 0.f};
  o_acc[0] = zf; o_acc[1] = zf;

  for (int kt = 0; kt < 16; ++kt) {
    __syncthreads();
    {
      int kr = t >> 2, d0 = (t & 3) * 8;
      const float* gp = qkv + ((long)(b * N_ + kt * 64 + kr)) * 768 + 256 + h * HD_ + d0;
      ushort8v kv;
#pragma unroll
      for (int i = 0; i < 8; ++i) kv[i] = f2b(gp[i]);
      *(ushort8v*)&K_lds[kr * 40 + d0] = kv;
      const float* vp = gp + 256;
#pragma unroll
      for (int i = 0; i < 8; ++i) Vt_lds[(d0 + i) * 72 + kr] = f2b(vp[i]);
    }
    __syncthreads();
    f32x4 s_frag[4];
#pragma unroll
    for (int s = 0; s < 4; ++s) {
      bf16x8 k_frag = *(const bf16x8*)&K_lds[(s * 16 + ql) * 40 + g * 8];
      s_frag[s] = __builtin_amdgcn_mfma_f32_16x16x32_bf16(k_frag, q_frag, zf, 0, 0, 0);
    }
    float sv[16];
#pragma unroll
    for (int s = 0; s < 4; ++s)
#pragma unroll
      for (int r = 0; r < 4; ++r) sv[s * 4 + r] = s_frag[s][r];
    float tmax = sv[0];
#pragma unroll
    for (int i = 1; i < 16; ++i) tmax = fmaxf(tmax, sv[i]);
    tmax = fmaxf(tmax, __shfl_xor(tmax, 16));
    tmax = fmaxf(tmax, __shfl_xor(tmax, 32));
    float mn = fmaxf(m, tmax);
    float corr = exp2f(m - mn);
    float psum = 0.f;
    unsigned short pb[16];
#pragma unroll
    for (int i = 0; i < 16; ++i) {
      float p = exp2f(sv[i] - mn);
      psum += p;
      pb[i] = f2b(p);
    }
    psum += __shfl_xor(psum, 16);
    psum += __shfl_xor(psum, 32);
    l = l * corr + psum;
    m = mn;
#pragma unroll
    for (int mt = 0; mt < 2; ++mt)
#pragma unroll
      for (int r = 0; r < 4; ++r) o_acc[mt][r] *= corr;
#pragma unroll
    for (int s = 0; s < 4; ++s) {
      ushort4v p4 = {pb[s * 4], pb[s * 4 + 1], pb[s * 4 + 2], pb[s * 4 + 3]};
      *(ushort4v*)&P_lds[w][ql * 72 + s * 16 + g * 4] = p4;
    }
#pragma unroll
    for (int c = 0; c < 2; ++c) {
      bf16x8 p_frag = *(const bf16x8*)&P_lds[w][ql * 72 + c * 32 + g * 8];
#pragma unroll
      for (int mt = 0; mt < 2; ++mt) {
        bf16x8 v_frag = *(const bf16x8*)&Vt_lds[(mt * 16 + ql) * 72 + c * 32 + g * 8];
        o_acc[mt] = __builtin_amdgcn_mfma_f32_16x16x32_bf16(v_frag, p_frag, o_acc[mt], 0, 0, 0);
      }
    }
  }
  float inv = 1.f / l;
  float* op = O + ((long)(b * N_ + qt * 64 + w * 16 + ql)) * C_ + h * HD_;
#pragma unroll
  for (int mt = 0; mt < 2; ++mt) {
    float4 o4 = make_float4(o_acc[mt][0] * inv, o_acc[mt][1] * inv,
                            o_acc[mt][2] * inv, o_acc[mt][3] * inv);
    *(float4*)(op + mt * 16 + g * 4) = o4;
  }
}

// ---------- K17: LN(lgn) + exact GELU -> (B,C,N), tiled coalesced ----------
// grid: B*(N/16) = 256; block 256 (thread = c).
__global__ __launch_bounds__(256) void k_lngelu(const float* __restrict__ XO,
                                                const float* __restrict__ lw,
                                                const float* __restrict__ lb,
                                                float* __restrict__ XI) {
  __shared__ float tile[256][17];
  __shared__ float redp[16][16][2];
  __shared__ float stats[16][2];
  int bx = blockIdx.x;
  int b = bx >> 6, n0 = (bx & 63) * 16;
  int c = threadIdx.x;
#pragma unroll
  for (int j = 0; j < 16; ++j)
    tile[c][j] = XO[((long)(b * N_ + n0 + j)) * C_ + c];
  __syncthreads();
  {
    int n = c & 15, g = c >> 4;
    float a = 0.f, q = 0.f;
#pragma unroll
    for (int i = 0; i < 16; ++i) {
      float v = tile[g * 16 + i][n];
      a += v; q += v * v;
    }
    redp[g][n][0] = a; redp[g][n][1] = q;
  }
  __syncthreads();
  if (c < 16) {
    float a = 0.f, q = 0.f;
#pragma unroll
    for (int g2 = 0; g2 < 16; ++g2) { a += redp[g2][c][0]; q += redp[g2][c][1]; }
    float mu = a * (1.f / C_);
    float rs = rsqrtf(q * (1.f / C_) - mu * mu + 1e-5f);
    stats[c][0] = mu; stats[c][1] = rs;
  }
  __syncthreads();
  float wv = lw[c], bv = lb[c];
  float o[16];
#pragma unroll
  for (int j = 0; j < 16; ++j) {
    float x = (tile[c][j] - stats[j][0]) * stats[j][1] * wv + bv;
    o[j] = 0.5f * x * (1.f + erff(x * 0.70710678118654752f));
  }
  float* dst = &XI[((long)(b * C_ + c)) * N_ + n0];
#pragma unroll
  for (int j4 = 0; j4 < 4; ++j4)
    *(float4*)(dst + j4 * 4) = make_float4(o[4 * j4], o[4 * j4 + 1], o[4 * j4 + 2], o[4 * j4 + 3]);
}

// ---------- K18: ln over (H,W) per (b,c), in place, no affine ----------
__global__ __launch_bounds__(256) void k_lnhw(float* __restrict__ XI) {
  __shared__ float red[8];
  long base = (long)blockIdx.x * N_;  // b*C + c
  float a = 0.f, b2 = 0.f;
  for (int i = threadIdx.x; i < N_; i += 256) {
    float v = XI[base + i];
    a += v; b2 += v * v;
  }
#pragma unroll
  for (int m = 1; m < 64; m <<= 1) {
    a += __shfl_xor(a, m, 64);
    b2 += __shfl_xor(b2, m, 64);
  }
  int w = threadIdx.x >> 6;
  if ((threadIdx.x & 63) == 0) { red[2 * w] = a; red[2 * w + 1] = b2; }
  __syncthreads();
  float sa = red[0] + red[2] + red[4] + red[6];
  float sq = red[1] + red[3] + red[5] + red[7];
  float mu = sa * (1.f / N_);
  float rs = rsqrtf(sq * (1.f / N_) - mu * mu + 1e-5f);
  for (int i = threadIdx.x; i < N_; i += 256) XI[base + i] = (XI[base + i] - mu) * rs;
}

// ---------- K19: depthwise 3x3 conv on (B,C,32,32), pad 1 ----------
__global__ __launch_bounds__(256) void k_dwc(const float* __restrict__ XI,
                                             const float* __restrict__ w,
                                             const float* __restrict__ bias,
                                             float* __restrict__ XD) {
  long i = (long)blockIdx.x * 256 + threadIdx.x;  // B*C*1024
  int hw = i & 1023;
  int wq = hw & 31, hq = hw >> 5;
  int c = (int)((i >> 10) & 255);
  const float* p = XI + (i - hw);
  const float* wk = w + c * 9;
  float a = bias[c];
#pragma unroll
  for (int kh = 0; kh < 3; ++kh) {
    int h2 = hq + kh - 1;
    if (h2 < 0 || h2 >= 32) continue;
#pragma unroll
    for (int kw = 0; kw < 3; ++kw) {
      int w2 = wq + kw - 1;
      if (w2 < 0 || w2 >= 32) continue;
      a += wk[kh * 3 + kw] * p[h2 * 32 + w2];
    }
  }
  XD[i] = a;
}

extern "C" void kernel_launch(void* const* d_in, const int* in_sizes, int n_in,
                              void* d_out, int out_size, void* d_ws, size_t ws_size,
                              hipStream_t stream) {
  const float* x        = (const float*)d_in[0];
  const float* norm_w   = (const float*)d_in[1];
  const float* norm_b   = (const float*)d_in[2];
  const float* skip     = (const float*)d_in[3];
  const float* m_inw    = (const float*)d_in[4];
  const float* m_convw  = (const float*)d_in[5];
  const float* m_convb  = (const float*)d_in[6];
  const float* m_xpw    = (const float*)d_in[7];
  const float* m_dtw    = (const float*)d_in[8];
  const float* m_dtb    = (const float*)d_in[9];
  const float* m_alog   = (const float*)d_in[10];
  const float* m_d      = (const float*)d_in[11];
  const float* m_outw   = (const float*)d_in[12];
  const float* qdw_w    = (const float*)d_in[13];
  const float* qdw_b    = (const float*)d_in[14];
  const float* qpw_w    = (const float*)d_in[15];
  const float* qpw_b    = (const float*)d_in[16];
  const float* rdw_w    = (const float*)d_in[17];
  const float* rdw_b    = (const float*)d_in[18];
  const float* rpw_w    = (const float*)d_in[19];
  const float* rpw_b    = (const float*)d_in[20];
  const float* fdw_w    = (const float*)d_in[21];
  const float* fdw_b    = (const float*)d_in[22];
  const float* fpw_w    = (const float*)d_in[23];
  const float* fpw_b    = (const float*)d_in[24];
  const float* lc_w     = (const float*)d_in[25];
  const float* lc_b     = (const float*)d_in[26];
  const float* attn_inw = (const float*)d_in[27];
  const float* attn_inb = (const float*)d_in[28];
  const float* attn_outw= (const float*)d_in[29];
  const float* attn_outb= (const float*)d_in[30];
  const float* lgn_w    = (const float*)d_in[31];
  const float* lgn_b    = (const float*)d_in[32];
  const float* fc_w     = (const float*)d_in[33];
  const float* fc_b     = (const float*)d_in[34];
  const float* dwc_w    = (const float*)d_in[35];
  const float* dwc_b    = (const float*)d_in[36];
  const float* proj_w   = (const float*)d_in[37];
  const float* proj_b   = (const float*)d_in[38];
  float* out = (float*)d_out;

  float* ws = (float*)d_ws;
  const size_t F = 1048576;  // B*N*C
  float* XS  = ws + 0 * F;
  float* XN  = ws + 1 * F;
  float* U   = ws + 2 * F;   // conv output (written by k_causal)
  float* Z   = ws + 4 * F;
  float* UPRE= ws + 6 * F;   // pre-conv u from in-proj; later overwritten by DT
  float* DT  = ws + 6 * F;   // dt / y (aliases UPRE — sequenced: xdbc consumes U, writes DT)
  float* BM  = ws + 8 * F;
  float* CM  = ws + 8 * F + F / 4;
  float* XMC = ws + 8 * F + F / 2;
  float* SC_APROD = ws + 8 * F + F / 2;            // scan scratch (XMC region, dead then)
  float* SC_HEND  = ws + 9 * F;
  float* G   = ws + 1 * F;
  float* XG  = ws + 2 * F;
  float* RD  = ws + 3 * F;
  float* RB  = ws + 4 * F;
  float* XM2 = ws + 5 * F;
  float* YDW = ws + 6 * F;
  float* XL  = ws + 0 * F;
  float* QKV = ws + 1 * F;
  float* O   = ws + 4 * F;
  float* XGL = ws + 6 * F;
  float* XO  = ws + 7 * F;
  float* XI  = ws + 8 * F;
  float* XD  = ws + 5 * F;
  float* LNF = ws + 0 * F;
  (void)ws_size; (void)in_sizes; (void)n_in; (void)out_size;

  k_ln_t2<<<256, 256, 0, stream>>>(x, norm_w, norm_b, XN, XS);
  k_inproj<<<dim3(64, 4), 256, 0, stream>>>(XN, m_inw, UPRE, Z);
  k_causal<<<512, 256, 0, stream>>>(UPRE, U, m_convw, m_convb);
  k_xdbc<<<1024, 256, 0, stream>>>(U, m_xpw, m_dtw, m_dtb, DT, BM, CM);
  k_scanA<<<512, 256, 0, stream>>>(DT, U, BM, m_alog, SC_APROD, SC_HEND);
  k_scanB<<<128, 256, 0, stream>>>(SC_APROD, SC_HEND);
  k_scanC<<<512, 256, 0, stream>>>(DT, U, BM, CM, m_alog, m_d, SC_APROD);
  k_outproj<<<1024, 256, 0, stream>>>(DT, Z, m_outw, XN, skip, XMC);
  k_gate<<<256, 256, 0, stream>>>(XMC, qdw_w, qdw_b, qpw_w, qpw_b, G);
  k_xg<<<256, 256, 0, stream>>>(XMC, G, XG);
  k_dw3<<<4096, 256, 0, stream>>>(XG, rdw_w, rdw_b, RD, 256);
  k_gemm_cm<256><<<dim3(64, 4), 256, 0, stream>>>(RD, rpw_w, rpw_b, XG, nullptr, RB, nullptr);
  k_fdw<<<8192, 256, 0, stream>>>(x, RB, fdw_w, fdw_b, YDW);
  k_gemm_cm<512><<<dim3(64, 4), 256, 0, stream>>>(YDW, fpw_w, fpw_b, nullptr, XS, nullptr, XM2);
  k_lc<<<4096, 256, 0, stream>>>(XM2, lc_w, lc_b, XL);
  k_gemm_rm<256, false><<<dim3(64, 12), 256, 0, stream>>>(XM2, nullptr, attn_inw, attn_inb, QKV, 768, 256);
  k_attn_mfma<<<512, 256, 0, stream>>>(QKV, O);
  k_gemm_rm<256, false><<<dim3(64, 4), 256, 0, stream>>>(O, nullptr, attn_outw, attn_outb, XGL, 256, 256);
  k_gemm_rm<512, false><<<dim3(64, 4), 256, 0, stream>>>(XL, XGL, fc_w, fc_b, XO, 256, 256);
  k_lngelu<<<256, 256, 0, stream>>>(XO, lgn_w, lgn_b, XI);
  k_lnhw<<<1024, 256, 0, stream>>>(XI);
  k_dwc<<<4096, 256, 0, stream>>>(XI, dwc_w, dwc_b, XD);
  k_ln_t2<<<256, 256, 0, stream>>>(XD, norm_w, norm_b, LNF, nullptr);
  k_gemm_rm<256, true><<<dim3(64, 4), 256, 0, stream>>>(LNF, nullptr, proj_w, proj_b, out, 256, 256);
}

// Round 8
// 224.825 us; speedup vs baseline: 5.1873x; 1.1983x over previous
//
#include <hip/hip_runtime.h>
#include <math.h>

// MambaLiteUNet — round 7: MFMA mamba in/out-proj; depthwise convs fused into
// GEMM staging (dw3/fdw/lc eliminated); 22 -> 19 kernels.

namespace {
constexpr int NB_ = 4, DM_ = 64, DIN_ = 128, DS_ = 16, DTR_ = 4;
constexpr int C_ = 256, N_ = 1024, B_ = 4, HD_ = 32;
constexpr int NCH = 16, LCH = 64;          // scan: 16 time-chunks of 64
constexpr int NSTATE = 16 * 128 * 16;      // nbb * DIN * DS = 32768
}

typedef __attribute__((ext_vector_type(8))) short bf16x8;
typedef __attribute__((ext_vector_type(4))) float f32x4;
typedef __attribute__((ext_vector_type(8))) unsigned short ushort8v;
typedef __attribute__((ext_vector_type(4))) unsigned short ushort4v;

// ---------- helpers ----------
__device__ __forceinline__ unsigned short f2b(float f) {  // fp32 -> bf16 RNE
  unsigned int u = __float_as_uint(f);
  unsigned int r = u + 0x7FFFu + ((u >> 16) & 1u);
  return (unsigned short)(r >> 16);
}

__device__ __forceinline__ float siluf(float x) { return x / (1.f + expf(-x)); }
__device__ __forceinline__ float sigmf(float x) { return 1.f / (1.f + expf(-x)); }
__device__ __forceinline__ float softplusf(float x) {
  return fmaxf(x, 0.f) + log1pf(expf(-fabsf(x)));
}

// ---------- K1/K20a: LN over C of (B,C,N) -> (B,N,C), coalesced LDS-tile ----------
__global__ __launch_bounds__(256) void k_ln_t2(const float* __restrict__ in,
                                               const float* __restrict__ w,
                                               const float* __restrict__ bias,
                                               float* __restrict__ out_ln,
                                               float* __restrict__ out_copy) {
  __shared__ float tile[256][17];
  __shared__ float redp[16][16][2];
  __shared__ float stats[16][2];
  int bx = blockIdx.x;
  int b = bx >> 6, n0 = (bx & 63) * 16;
  int c = threadIdx.x;
  {
    const float* p = in + ((long)(b * C_ + c)) * N_ + n0;
#pragma unroll
    for (int j = 0; j < 16; ++j) tile[c][j] = p[j];
  }
  __syncthreads();
  {
    int n = c & 15, g = c >> 4;
    float a = 0.f, q = 0.f;
#pragma unroll
    for (int i = 0; i < 16; ++i) {
      float v = tile[g * 16 + i][n];
      a += v; q += v * v;
    }
    redp[g][n][0] = a; redp[g][n][1] = q;
  }
  __syncthreads();
  if (c < 16) {
    float a = 0.f, q = 0.f;
#pragma unroll
    for (int g2 = 0; g2 < 16; ++g2) { a += redp[g2][c][0]; q += redp[g2][c][1]; }
    float mu = a * (1.f / C_);
    float rs = rsqrtf(q * (1.f / C_) - mu * mu + 1e-5f);
    stats[c][0] = mu; stats[c][1] = rs;
  }
  __syncthreads();
  float wv = w[c], bv = bias[c];
#pragma unroll
  for (int j = 0; j < 16; ++j) {
    float v = tile[c][j];
    long o = ((long)(b * N_ + n0 + j)) * C_ + c;
    if (out_copy) out_copy[o] = v;
    out_ln[o] = (v - stats[j][0]) * stats[j][1] * wv + bv;
  }
}

// ---------- K2: mamba in-proj (MFMA) — grid dim3(64, 16): rowtile x (nb*4+ct4) ----------
__global__ __launch_bounds__(256) void k_inproj_mfma(const float* __restrict__ xn,
                                                     const float* __restrict__ inw,
                                                     float* __restrict__ UPRE,
                                                     float* __restrict__ Z) {
  __shared__ unsigned short xa[64][72];
  __shared__ unsigned short wb[64][72];
  int r0 = blockIdx.x * 64;                 // row within B*N
  int nb = blockIdx.y >> 2, c0 = (blockIdx.y & 3) * 64;
  int t = threadIdx.x;
  int wv = t >> 6, lane = t & 63, g = lane >> 4, ql = lane & 15;
  const f32x4 zf = {0.f, 0.f, 0.f, 0.f};
  f32x4 acc[4] = {zf, zf, zf, zf};
  int rr = t >> 2, kq = (t & 3) * 16;
  {
    const float* xsrc = xn + (long)(r0 + rr) * C_ + nb * 64 + kq;
#pragma unroll
    for (int j = 0; j < 4; ++j) {
      float4 v = *(const float4*)(xsrc + 4 * j);
      ushort4v u = {f2b(v.x), f2b(v.y), f2b(v.z), f2b(v.w)};
      *(ushort4v*)&xa[rr][kq + 4 * j] = u;
    }
    const float* wsrc = inw + ((long)nb * 256 + c0 + rr) * 64 + kq;
#pragma unroll
    for (int j = 0; j < 4; ++j) {
      float4 v = *(const float4*)(wsrc + 4 * j);
      ushort4v u = {f2b(v.x), f2b(v.y), f2b(v.z), f2b(v.w)};
      *(ushort4v*)&wb[rr][kq + 4 * j] = u;
    }
  }
  __syncthreads();
#pragma unroll
  for (int ks = 0; ks < 2; ++ks) {
    bf16x8 a = *(const bf16x8*)&xa[wv * 16 + ql][ks * 32 + g * 8];
#pragma unroll
    for (int ct = 0; ct < 4; ++ct) {
      bf16x8 b = *(const bf16x8*)&wb[ct * 16 + ql][ks * 32 + g * 8];
      acc[ct] = __builtin_amdgcn_mfma_f32_16x16x32_bf16(a, b, acc[ct], 0, 0, 0);
    }
  }
#pragma unroll
  for (int ct = 0; ct < 4; ++ct) {
    int col = c0 + ct * 16 + ql;
#pragma unroll
    for (int reg = 0; reg < 4; ++reg) {
      long row = (long)nb * 4096 + r0 + wv * 16 + g * 4 + reg;
      if (col < 128) UPRE[row * DIN_ + col] = acc[ct][reg];
      else           Z[row * DIN_ + col - 128] = acc[ct][reg];
    }
  }
}

// ---------- K3: causal depthwise conv (K=4) + silu, out-of-place, coalesced ----------
__global__ __launch_bounds__(256) void k_causal(const float* __restrict__ Uin,
                                                float* __restrict__ Uout,
                                                const float* __restrict__ cw,
                                                const float* __restrict__ cb) {
  __shared__ float u_s[35][128];
  int bx = blockIdx.x;
  int nbb = bx >> 5, chk = bx & 31;
  int nb = nbb >> 2;
  int n0 = chk * 32;
  const float* ibase = Uin + (long)nbb * N_ * DIN_;
  float* obase = Uout + (long)nbb * N_ * DIN_;
  for (int i = threadIdx.x; i < 35 * 32; i += 256) {
    int row = i >> 5, q = i & 31;
    int n = n0 - 3 + row;
    float4 v = (n >= 0) ? *(const float4*)&ibase[(long)n * DIN_ + q * 4]
                        : make_float4(0.f, 0.f, 0.f, 0.f);
    *(float4*)&u_s[row][q * 4] = v;
  }
  __syncthreads();
  int d = threadIdx.x & 127, half = threadIdx.x >> 7;
  float w0 = cw[(nb * DIN_ + d) * 4 + 0], w1 = cw[(nb * DIN_ + d) * 4 + 1];
  float w2 = cw[(nb * DIN_ + d) * 4 + 2], w3 = cw[(nb * DIN_ + d) * 4 + 3];
  float bv = cb[nb * DIN_ + d];
#pragma unroll
  for (int j = 0; j < 16; ++j) {
    int nn = half * 16 + j;
    float acc = bv + w3 * u_s[nn + 3][d] + w2 * u_s[nn + 2][d] +
                w1 * u_s[nn + 1][d] + w0 * u_s[nn][d];
    obase[(long)(n0 + nn) * DIN_ + d] = siluf(acc);
  }
}

// ---------- K4: xdbc / dt / Bm / Cm — full-lane version ----------
__global__ __launch_bounds__(256) void k_xdbc(const float* __restrict__ U,
                                              const float* __restrict__ xpw,
                                              const float* __restrict__ dtw,
                                              const float* __restrict__ dtb,
                                              float* __restrict__ DT,
                                              float* __restrict__ BMb, float* __restrict__ CMb) {
  __shared__ float wl[36][129];
  __shared__ float u16[16][129];
  __shared__ float xd_s[16][37];
  __shared__ float dtw_s[128][4];
  __shared__ float dtb_s[128];
  int t = threadIdx.x;
  long row0 = (long)blockIdx.x * 16;
  int nb = blockIdx.x >> 8;
  for (int i = t; i < 36 * 128; i += 256) wl[i >> 7][i & 127] = xpw[nb * 36 * 128 + i];
  for (int i = t; i < 16 * 128; i += 256) u16[i >> 7][i & 127] = U[(row0 + (i >> 7)) * DIN_ + (i & 127)];
  for (int i = t; i < 512; i += 256) dtw_s[i >> 2][i & 3] = dtw[nb * 512 + i];
  if (t < 128) dtb_s[t] = dtb[nb * DIN_ + t];
  __syncthreads();
  {
    int r = t >> 4, jl = t & 15;
    float a0 = 0.f, a1 = 0.f, a2 = 0.f;
    for (int k = 0; k < 128; ++k) {
      float uv = u16[r][k];
      a0 += uv * wl[jl][k];
      a1 += uv * wl[jl + 16][k];
      if (jl < 4) a2 += uv * wl[jl + 32][k];
    }
    xd_s[r][jl] = a0;
    xd_s[r][jl + 16] = a1;
    if (jl < 4) xd_s[r][jl + 32] = a2;
  }
  __syncthreads();
  {
    int r = t >> 4, s = t & 15;
    BMb[(row0 + r) * DS_ + s] = xd_s[r][4 + s];
    CMb[(row0 + r) * DS_ + s] = xd_s[r][20 + s];
  }
  {
    int r = t >> 4, dl = t & 15;
    float x0 = xd_s[r][0], x1 = xd_s[r][1], x2 = xd_s[r][2], x3 = xd_s[r][3];
#pragma unroll
    for (int dd = 0; dd < 8; ++dd) {
      int d = dl * 8 + dd;
      float a = dtb_s[d] + x0 * dtw_s[d][0] + x1 * dtw_s[d][1] +
                x2 * dtw_s[d][2] + x3 * dtw_s[d][3];
      DT[(row0 + r) * DIN_ + d] = softplusf(a);
    }
  }
}

// ---------- K5a: scan phase A — thread owns (d, 4 s-states) ----------
__global__ __launch_bounds__(256) void k_scanA(const float* __restrict__ DT,
                                               const float* __restrict__ U,
                                               const float* __restrict__ BMb,
                                               const float* __restrict__ alog,
                                               float* __restrict__ Aprod,
                                               float* __restrict__ Hend) {
  __shared__ float dt_s[64][64];
  __shared__ float u_s[64][64];
  __shared__ float bm_s[64][16];
  int bx = blockIdx.x;
  int chunk = bx >> 5, rem = bx & 31, nbb = rem >> 1, dh = rem & 1;
  int nb = nbb >> 2;
  int t = threadIdx.x;
  int dl = t >> 2, sg = t & 3;
  int d = dh * 64 + dl;
  long base = (long)nbb * N_ + chunk * LCH;
#pragma unroll
  for (int j = 0; j < 4; ++j) {
    int f = t + 256 * j;
    int tt = f >> 4, dq = (f & 15) * 4;
    long src = (base + tt) * DIN_ + dh * 64 + dq;
    *(float4*)&dt_s[tt][dq] = *(const float4*)&DT[src];
    *(float4*)&u_s[tt][dq]  = *(const float4*)&U[src];
  }
  {
    int tt = t >> 2, sq = (t & 3) * 4;
    *(float4*)&bm_s[tt][sq] = *(const float4*)&BMb[(base + tt) * DS_ + sq];
  }
  float A[4];
#pragma unroll
  for (int i = 0; i < 4; ++i)
    A[i] = -expf(alog[(nb * DIN_ + d) * DS_ + sg * 4 + i]);
  __syncthreads();
  float h[4] = {0.f, 0.f, 0.f, 0.f};
  float ap[4] = {1.f, 1.f, 1.f, 1.f};
  for (int tt = 0; tt < LCH; ++tt) {
    float dtv = dt_s[tt][dl];
    float uv  = u_s[tt][dl];
    float cc = dtv * uv;
    float4 bm4 = *(const float4*)&bm_s[tt][sg * 4];
    float bmv[4] = {bm4.x, bm4.y, bm4.z, bm4.w};
#pragma unroll
    for (int i = 0; i < 4; ++i) {
      float dA = __expf(dtv * A[i]);
      h[i] = dA * h[i] + cc * bmv[i];
      ap[i] *= dA;
    }
  }
  long st = (long)chunk * NSTATE + ((nbb << 7) + d) * 16 + sg * 4;
  *(float4*)&Aprod[st] = make_float4(ap[0], ap[1], ap[2], ap[3]);
  *(float4*)&Hend[st]  = make_float4(h[0], h[1], h[2], h[3]);
}

// ---------- K5b: scan phase B ----------
__global__ __launch_bounds__(256) void k_scanB(float* __restrict__ Aprod,
                                               const float* __restrict__ Hend) {
  int state = blockIdx.x * 256 + threadIdx.x;
  float H = 0.f;
#pragma unroll
  for (int c = 0; c < NCH; ++c) {
    long idx = (long)c * NSTATE + state;
    float a = Aprod[idx];
    float e = Hend[idx];
    Aprod[idx] = H;            // Hin for chunk c
    H = e + a * H;
  }
}

// ---------- K5c: scan phase C ----------
__global__ __launch_bounds__(256) void k_scanC(float* __restrict__ DT,
                                               const float* __restrict__ U,
                                               const float* __restrict__ BMb,
                                               const float* __restrict__ CMb,
                                               const float* __restrict__ alog,
                                               const float* __restrict__ Dp,
                                               const float* __restrict__ Hin) {
  __shared__ float dt_s[64][64];
  __shared__ float u_s[64][64];
  __shared__ float bm_s[64][16];
  __shared__ float cm_s[64][16];
  int bx = blockIdx.x;
  int chunk = bx >> 5, rem = bx & 31, nbb = rem >> 1, dh = rem & 1;
  int nb = nbb >> 2;
  int t = threadIdx.x;
  int dl = t >> 2, sg = t & 3;
  int d = dh * 64 + dl;
  long base = (long)nbb * N_ + chunk * LCH;
#pragma unroll
  for (int j = 0; j < 4; ++j) {
    int f = t + 256 * j;
    int tt = f >> 4, dq = (f & 15) * 4;
    long src = (base + tt) * DIN_ + dh * 64 + dq;
    *(float4*)&dt_s[tt][dq] = *(const float4*)&DT[src];
    *(float4*)&u_s[tt][dq]  = *(const float4*)&U[src];
  }
  {
    int tt = t >> 2, sq = (t & 3) * 4;
    *(float4*)&bm_s[tt][sq] = *(const float4*)&BMb[(base + tt) * DS_ + sq];
    *(float4*)&cm_s[tt][sq] = *(const float4*)&CMb[(base + tt) * DS_ + sq];
  }
  float A[4];
#pragma unroll
  for (int i = 0; i < 4; ++i)
    A[i] = -expf(alog[(nb * DIN_ + d) * DS_ + sg * 4 + i]);
  float Dv = Dp[nb * DIN_ + d];
  float h[4];
  {
    long st = (long)chunk * NSTATE + ((nbb << 7) + d) * 16 + sg * 4;
    float4 h4 = *(const float4*)&Hin[st];
    h[0] = h4.x; h[1] = h4.y; h[2] = h4.z; h[3] = h4.w;
  }
  __syncthreads();
  for (int tt = 0; tt < LCH; ++tt) {
    float dtv = dt_s[tt][dl];
    float uv  = u_s[tt][dl];
    float cc = dtv * uv;
    float4 bm4 = *(const float4*)&bm_s[tt][sg * 4];
    float4 cm4 = *(const float4*)&cm_s[tt][sg * 4];
    float bmv[4] = {bm4.x, bm4.y, bm4.z, bm4.w};
    float cmv[4] = {cm4.x, cm4.y, cm4.z, cm4.w};
    float p = 0.f;
#pragma unroll
    for (int i = 0; i < 4; ++i) {
      float dA = __expf(dtv * A[i]);
      h[i] = dA * h[i] + cc * bmv[i];
      p += h[i] * cmv[i];
    }
    p += __shfl_xor(p, 1, 64);
    p += __shfl_xor(p, 2, 64);
    if (sg == 0) DT[(base + tt) * DIN_ + d] = p + Dv * uv;
  }
}

// ---------- K6: out-proj (MFMA): xm = (y*silu(z)) @ outw^T + skip*xn ----------
// grid dim3(64, 4): rowtile x nb. cols=64, K=128.
__global__ __launch_bounds__(256) void k_outproj_mfma(const float* __restrict__ Y,
                                                      const float* __restrict__ Zb,
                                                      const float* __restrict__ outw,
                                                      const float* __restrict__ xn,
                                                      const float* __restrict__ skip,
                                                      float* __restrict__ XMC) {
  __shared__ unsigned short xa[64][72];
  __shared__ unsigned short wb[64][72];
  int r0 = blockIdx.x * 64;
  int nb = blockIdx.y;
  int t = threadIdx.x;
  int wv = t >> 6, lane = t & 63, g = lane >> 4, ql = lane & 15;
  const f32x4 zf = {0.f, 0.f, 0.f, 0.f};
  f32x4 acc[4] = {zf, zf, zf, zf};
  int rr = t >> 2, kq = (t & 3) * 16;
  for (int k0 = 0; k0 < 128; k0 += 64) {
    __syncthreads();
    long row = (long)nb * 4096 + r0 + rr;
    const float* ysrc = Y + row * DIN_ + k0 + kq;
    const float* zsrc = Zb + row * DIN_ + k0 + kq;
#pragma unroll
    for (int j = 0; j < 4; ++j) {
      float4 yv = *(const float4*)(ysrc + 4 * j);
      float4 zv = *(const float4*)(zsrc + 4 * j);
      ushort4v u = {f2b(yv.x * siluf(zv.x)), f2b(yv.y * siluf(zv.y)),
                    f2b(yv.z * siluf(zv.z)), f2b(yv.w * siluf(zv.w))};
      *(ushort4v*)&xa[rr][kq + 4 * j] = u;
    }
    const float* wsrc = outw + ((long)nb * 64 + rr) * 128 + k0 + kq;
#pragma unroll
    for (int j = 0; j < 4; ++j) {
      float4 v = *(const float4*)(wsrc + 4 * j);
      ushort4v u = {f2b(v.x), f2b(v.y), f2b(v.z), f2b(v.w)};
      *(ushort4v*)&wb[rr][kq + 4 * j] = u;
    }
    __syncthreads();
#pragma unroll
    for (int ks = 0; ks < 2; ++ks) {
      bf16x8 a = *(const bf16x8*)&xa[wv * 16 + ql][ks * 32 + g * 8];
#pragma unroll
      for (int ct = 0; ct < 4; ++ct) {
        bf16x8 b = *(const bf16x8*)&wb[ct * 16 + ql][ks * 32 + g * 8];
        acc[ct] = __builtin_amdgcn_mfma_f32_16x16x32_bf16(a, b, acc[ct], 0, 0, 0);
      }
    }
  }
  float sk = skip[0];
#pragma unroll
  for (int ct = 0; ct < 4; ++ct) {
    int col = ct * 16 + ql;
#pragma unroll
    for (int reg = 0; reg < 4; ++reg) {
      int bn = r0 + wv * 16 + g * 4 + reg;
      long oc = (long)bn * C_ + nb * 64 + col;
      XMC[oc] = acc[ct][reg] + sk * xn[oc];
    }
  }
}

// ---------- K7: gate ----------
__global__ __launch_bounds__(256) void k_gate(const float* __restrict__ XMC,
                                              const float* __restrict__ qdw_w,
                                              const float* __restrict__ qdw_b,
                                              const float* __restrict__ qpw_w,
                                              const float* __restrict__ qpw_b,
                                              float* __restrict__ G) {
  int t = threadIdx.x;
  int gid = (blockIdx.x * 256 + t) >> 4;     // b*N + n
  int cq = t & 3, p = (t >> 2) & 3;
  int b = gid >> 10, n = gid & 1023;
  float a = 0.f;
#pragma unroll
  for (int k = 0; k < 3; ++k) {
    int nn = n + k - 1;
    if (nn < 0 || nn >= N_) continue;
    const float* xr = XMC + ((long)b * N_ + nn) * C_ + p * 64 + cq * 16;
    const float* wr = qdw_w + (p * 64 + cq * 16) * 3 + k;
#pragma unroll
    for (int i = 0; i < 16; ++i) a += xr[i] * wr[i * 3];
  }
  a += __shfl_xor(a, 1, 64);
  a += __shfl_xor(a, 2, 64);
  float q1 = a + qdw_b[p];
  int lane = t & 63;
  float q1g[4];
#pragma unroll
  for (int pp = 0; pp < 4; ++pp) q1g[pp] = __shfl(q1, (lane & ~12) | (pp << 2), 64);
  int o = p;
  float r = qpw_b[o];
#pragma unroll
  for (int pp = 0; pp < 4; ++pp) r += qpw_w[o * 4 + pp] * q1g[pp];
  if (cq == 0) G[((long)b * 4 + o) * N_ + n] = sigmf(r);
}

// ---------- K8: xg (B,C,N) = g * xm — LDS tile transpose ----------
__global__ __launch_bounds__(256) void k_xg(const float* __restrict__ XMC,
                                            const float* __restrict__ G,
                                            float* __restrict__ XG) {
  __shared__ float tile[64][65];
  int bx = blockIdx.x;
  int b = bx >> 6, ct = (bx >> 4) & 3, nt = bx & 15;
  int c0 = ct * 64, n0 = nt * 64;
  int t = threadIdx.x;
  {
    int cc = t & 63, nq = t >> 6;
#pragma unroll
    for (int j = 0; j < 16; ++j) {
      int nn = nq * 16 + j;
      tile[cc][nn] = XMC[((long)(b * N_ + n0 + nn)) * C_ + c0 + cc];
    }
  }
  __syncthreads();
  {
    int nl = t & 63, cq = t >> 6;
    float g = G[((long)(b * 4 + ct)) * N_ + n0 + nl];
#pragma unroll
    for (int j = 0; j < 16; ++j) {
      int cl = cq * 16 + j;
      XG[((long)(b * C_ + c0 + cl)) * N_ + n0 + nl] = g * tile[cl][nl];
    }
  }
}

// ---------- MFMA GEMM, channel-major, 3-tap depthwise conv fused into staging ----------
// virtual input chan k: k<256 -> inA chan k, else inB chan k-256; conv weights dww/dwb (KD chans).
template <int KD>
__global__ __launch_bounds__(256) void k_gemm_cm_dw(const float* __restrict__ inA,
                                                    const float* __restrict__ inB,
                                                    const float* __restrict__ dww,
                                                    const float* __restrict__ dwb,
                                                    const float* __restrict__ w,
                                                    const float* __restrict__ bias,
                                                    const float* __restrict__ residCM,
                                                    const float* __restrict__ residRM,
                                                    float* __restrict__ outCM,
                                                    float* __restrict__ outRM) {
  __shared__ unsigned short xa[64][72];  // [n][k]
  __shared__ unsigned short wb[64][72];  // [cout][k]
  int rb = blockIdx.x;
  int b = rb >> 4, n0 = (rb & 15) * 64;
  int c0 = blockIdx.y * 64;
  int t = threadIdx.x;
  int wv = t >> 6, lane = t & 63, g = lane >> 4, ql = lane & 15;
  const f32x4 zf = {0.f, 0.f, 0.f, 0.f};
  f32x4 acc[4] = {zf, zf, zf, zf};
  int rr = t >> 2, kq = (t & 3) * 16;
  for (int k0 = 0; k0 < KD; k0 += 64) {
    __syncthreads();
    {
      int k = k0 + rr;                      // virtual channel
      const float* src = (inB != nullptr && k >= 256)
                             ? inB + ((long)(b * 256 + k - 256)) * 1024
                             : inA + ((long)(b * 256 + k)) * 1024;
      float w0 = dww[k * 3], w1 = dww[k * 3 + 1], w2 = dww[k * 3 + 2], bv = dwb[k];
#pragma unroll
      for (int j = 0; j < 4; ++j) {
        int nb4 = n0 + kq + 4 * j;
        float4 v = *(const float4*)&src[nb4];
        float vm1 = (nb4 > 0) ? src[nb4 - 1] : 0.f;
        float vp4 = (nb4 + 4 < 1024) ? src[nb4 + 4] : 0.f;
        xa[kq + 4 * j + 0][rr] = f2b(bv + w0 * vm1 + w1 * v.x + w2 * v.y);
        xa[kq + 4 * j + 1][rr] = f2b(bv + w0 * v.x + w1 * v.y + w2 * v.z);
        xa[kq + 4 * j + 2][rr] = f2b(bv + w0 * v.y + w1 * v.z + w2 * v.w);
        xa[kq + 4 * j + 3][rr] = f2b(bv + w0 * v.z + w1 * v.w + w2 * vp4);
      }
    }
    const float* wsrc = w + (long)(c0 + rr) * KD + k0 + kq;
#pragma unroll
    for (int j = 0; j < 4; ++j) {
      float4 v = *(const float4*)(wsrc + 4 * j);
      ushort4v u = {f2b(v.x), f2b(v.y), f2b(v.z), f2b(v.w)};
      *(ushort4v*)&wb[rr][kq + 4 * j] = u;
    }
    __syncthreads();
#pragma unroll
    for (int ks = 0; ks < 2; ++ks) {
      bf16x8 a = *(const bf16x8*)&xa[wv * 16 + ql][ks * 32 + g * 8];
#pragma unroll
      for (int ct = 0; ct < 4; ++ct) {
        bf16x8 bfr = *(const bf16x8*)&wb[ct * 16 + ql][ks * 32 + g * 8];
        acc[ct] = __builtin_amdgcn_mfma_f32_16x16x32_bf16(a, bfr, acc[ct], 0, 0, 0);
      }
    }
  }
#pragma unroll
  for (int ct = 0; ct < 4; ++ct) {
    int col = c0 + ct * 16 + ql;
    float bv = bias[col];
    if (outCM) {
      long base = ((long)(b * 256 + col)) * 1024 + n0 + wv * 16 + g * 4;
      float4 r4 = *(const float4*)(residCM + base);
      float4 o = make_float4(acc[ct][0] + bv + r4.x, acc[ct][1] + bv + r4.y,
                             acc[ct][2] + bv + r4.z, acc[ct][3] + bv + r4.w);
      *(float4*)(outCM + base) = o;
    } else {
#pragma unroll
      for (int reg = 0; reg < 4; ++reg) {
        long row = (long)b * 1024 + n0 + wv * 16 + g * 4 + reg;
        long idx = row * 256 + col;
        outRM[idx] = acc[ct][reg] + bv + residRM[idx];
      }
    }
  }
}

// ---------- MFMA GEMM, row-major activations (QKV / attn-out / final proj) ----------
template <int KD, bool TOUT>
__global__ __launch_bounds__(256) void k_gemm_rm(const float* __restrict__ inA,
                                                 const float* __restrict__ inB,
                                                 const float* __restrict__ w,
                                                 const float* __restrict__ bias,
                                                 float* __restrict__ out,
                                                 int Cout, int lda) {
  __shared__ unsigned short xa[64][72];
  __shared__ unsigned short wb[64][72];
  __shared__ float tt[TOUT ? 64 : 1][TOUT ? 68 : 1];
  int r0 = blockIdx.x * 64;
  int c0 = blockIdx.y * 64;
  int t = threadIdx.x;
  int wv = t >> 6, lane = t & 63, g = lane >> 4, ql = lane & 15;
  const f32x4 zf = {0.f, 0.f, 0.f, 0.f};
  f32x4 acc[4] = {zf, zf, zf, zf};
  int rr = t >> 2, kq = (t & 3) * 16;
  for (int k0 = 0; k0 < KD; k0 += 64) {
    __syncthreads();
    int kk = k0 + kq;
    const float* xsrc = (inB != nullptr && kk >= KD / 2)
                            ? inB + (long)(r0 + rr) * lda + (kk - KD / 2)
                            : inA + (long)(r0 + rr) * lda + kk;
#pragma unroll
    for (int j = 0; j < 4; ++j) {
      float4 v = *(const float4*)(xsrc + 4 * j);
      ushort4v u = {f2b(v.x), f2b(v.y), f2b(v.z), f2b(v.w)};
      *(ushort4v*)&xa[rr][kq + 4 * j] = u;
    }
    const float* wsrc = w + (long)(c0 + rr) * KD + kk;
#pragma unroll
    for (int j = 0; j < 4; ++j) {
      float4 v = *(const float4*)(wsrc + 4 * j);
      ushort4v u = {f2b(v.x), f2b(v.y), f2b(v.z), f2b(v.w)};
      *(ushort4v*)&wb[rr][kq + 4 * j] = u;
    }
    __syncthreads();
#pragma unroll
    for (int ks = 0; ks < 2; ++ks) {
      bf16x8 a = *(const bf16x8*)&xa[wv * 16 + ql][ks * 32 + g * 8];
#pragma unroll
      for (int ct = 0; ct < 4; ++ct) {
        bf16x8 b = *(const bf16x8*)&wb[ct * 16 + ql][ks * 32 + g * 8];
        acc[ct] = __builtin_amdgcn_mfma_f32_16x16x32_bf16(a, b, acc[ct], 0, 0, 0);
      }
    }
  }
  if constexpr (!TOUT) {
#pragma unroll
    for (int ct = 0; ct < 4; ++ct) {
      int col = c0 + ct * 16 + ql;
      float bv = bias[col];
#pragma unroll
      for (int reg = 0; reg < 4; ++reg) {
        long row = r0 + wv * 16 + g * 4 + reg;
        out[row * Cout + col] = acc[ct][reg] + bv;
      }
    }
  } else {
#pragma unroll
    for (int ct = 0; ct < 4; ++ct) {
      int col = ct * 16 + ql;
      float bv = bias[c0 + col];
#pragma unroll
      for (int reg = 0; reg < 4; ++reg)
        tt[col][wv * 16 + g * 4 + reg] = acc[ct][reg] + bv;
    }
    __syncthreads();
    int b = r0 >> 10, n0 = r0 & 1023;
    int col = t >> 2, nq = (t & 3) * 16;
    float* op = out + ((long)(b * 256 + c0 + col)) * 1024 + n0 + nq;
#pragma unroll
    for (int j = 0; j < 4; ++j) {
      float4 v = make_float4(tt[col][nq + 4 * j], tt[col][nq + 4 * j + 1],
                             tt[col][nq + 4 * j + 2], tt[col][nq + 4 * j + 3]);
      *(float4*)(op + 4 * j) = v;
    }
  }
}

// ---------- K16: fc GEMM with x_local row-conv fused (K=512: [lc(XM2) ; XGL]) ----------
__global__ __launch_bounds__(256) void k_gemm_fc(const float* __restrict__ XM2,
                                                 const float* __restrict__ XGL,
                                                 const float* __restrict__ lcw,
                                                 const float* __restrict__ lcb,
                                                 const float* __restrict__ w,
                                                 const float* __restrict__ bias,
                                                 float* __restrict__ out) {
  __shared__ unsigned short xa[64][72];
  __shared__ unsigned short wb[64][72];
  int r0 = blockIdx.x * 64;
  int c0 = blockIdx.y * 64;
  int t = threadIdx.x;
  int wv = t >> 6, lane = t & 63, g = lane >> 4, ql = lane & 15;
  const f32x4 zf = {0.f, 0.f, 0.f, 0.f};
  f32x4 acc[4] = {zf, zf, zf, zf};
  int rr = t >> 2, kq = (t & 3) * 16;
  for (int k0 = 0; k0 < 512; k0 += 64) {
    __syncthreads();
    int kk = k0 + kq;
    long row = r0 + rr;
    if (kk < 256) {
      int n = (int)(row & 1023);
      const float* pc = XM2 + row * 256 + kk;
      bool hm = n > 0, hp = n < 1023;
#pragma unroll
      for (int j = 0; j < 4; ++j) {
        float4 v = *(const float4*)(pc + 4 * j);
        float4 vm = hm ? *(const float4*)(pc - 256 + 4 * j) : make_float4(0.f, 0.f, 0.f, 0.f);
        float4 vp = hp ? *(const float4*)(pc + 256 + 4 * j) : make_float4(0.f, 0.f, 0.f, 0.f);
        int c = kk + 4 * j;
        xa[rr][kq + 4 * j + 0] = f2b(lcb[c + 0] + lcw[(c + 0) * 3] * vm.x + lcw[(c + 0) * 3 + 1] * v.x + lcw[(c + 0) * 3 + 2] * vp.x);
        xa[rr][kq + 4 * j + 1] = f2b(lcb[c + 1] + lcw[(c + 1) * 3] * vm.y + lcw[(c + 1) * 3 + 1] * v.y + lcw[(c + 1) * 3 + 2] * vp.y);
        xa[rr][kq + 4 * j + 2] = f2b(lcb[c + 2] + lcw[(c + 2) * 3] * vm.z + lcw[(c + 2) * 3 + 1] * v.z + lcw[(c + 2) * 3 + 2] * vp.z);
        xa[rr][kq + 4 * j + 3] = f2b(lcb[c + 3] + lcw[(c + 3) * 3] * vm.w + lcw[(c + 3) * 3 + 1] * v.w + lcw[(c + 3) * 3 + 2] * vp.w);
      }
    } else {
      const float* xsrc = XGL + row * 256 + (kk - 256);
#pragma unroll
      for (int j = 0; j < 4; ++j) {
        float4 v = *(const float4*)(xsrc + 4 * j);
        ushort4v u = {f2b(v.x), f2b(v.y), f2b(v.z), f2b(v.w)};
        *(ushort4v*)&xa[rr][kq + 4 * j] = u;
      }
    }
    const float* wsrc = w + (long)(c0 + rr) * 512 + kk;
#pragma unroll
    for (int j = 0; j < 4; ++j) {
      float4 v = *(const float4*)(wsrc + 4 * j);
      ushort4v u = {f2b(v.x), f2b(v.y), f2b(v.z), f2b(v.w)};
      *(ushort4v*)&wb[rr][kq + 4 * j] = u;
    }
    __syncthreads();
#pragma unroll
    for (int ks = 0; ks < 2; ++ks) {
      bf16x8 a = *(const bf16x8*)&xa[wv * 16 + ql][ks * 32 + g * 8];
#pragma unroll
      for (int ct = 0; ct < 4; ++ct) {
        bf16x8 b = *(const bf16x8*)&wb[ct * 16 + ql][ks * 32 + g * 8];
        acc[ct] = __builtin_amdgcn_mfma_f32_16x16x32_bf16(a, b, acc[ct], 0, 0, 0);
      }
    }
  }
#pragma unroll
  for (int ct = 0; ct < 4; ++ct) {
    int col = c0 + ct * 16 + ql;
    float bv = bias[col];
#pragma unroll
    for (int reg = 0; reg < 4; ++reg) {
      long row = r0 + wv * 16 + g * 4 + reg;
      out[row * 256 + col] = acc[ct][reg] + bv;
    }
  }
}

// ---------- K14: MFMA bf16 flash attention ----------
__global__ __launch_bounds__(256) void k_attn_mfma(const float* __restrict__ qkv,
                                                   float* __restrict__ O) {
  __shared__ unsigned short K_lds[64 * 40];
  __shared__ unsigned short Vt_lds[32 * 72];
  __shared__ unsigned short P_lds[4][16 * 72];
  int bx = blockIdx.x;
  int bh = bx >> 4, qt = bx & 15;
  int b = bh >> 3, h = bh & 7;
  int t = threadIdx.x;
  int w = t >> 6, lane = t & 63;
  int g = lane >> 4, ql = lane & 15;
  const float qscale = 0.17677669529663687f * 1.44269504088896341f;

  bf16x8 q_frag;
  {
    const float* qp = qkv + ((long)(b * N_ + qt * 64 + w * 16 + ql)) * 768 + h * HD_ + g * 8;
#pragma unroll
    for (int i = 0; i < 8; ++i) q_frag[i] = (short)f2b(qp[i] * qscale);
  }
  float m = -1e30f, l = 0.f;
  f32x4 o_acc[2];
  const f32x4 zf = {0.f, 0.f, 0.f, 0.f};
  o_acc[0] = zf; o_acc[1] = zf;

  for (int kt = 0; kt < 16; ++kt) {
    __syncthreads();
    {
      int kr = t >> 2, d0 = (t & 3) * 8;
      const float* gp = qkv + ((long)(b * N_ + kt * 64 + kr)) * 768 + 256 + h * HD_ + d0;
      ushort8v kv;
#pragma unroll
      for (int i = 0; i < 8; ++i) kv[i] = f2b(gp[i]);
      *(ushort8v*)&K_lds[kr * 40 + d0] = kv;
      const float* vp = gp + 256;
#pragma unroll
      for (int i = 0; i < 8; ++i) Vt_lds[(d0 + i) * 72 + kr] = f2b(vp[i]);
    }
    __syncthreads();
    f32x4 s_frag[4];
#pragma unroll
    for (int s = 0; s < 4; ++s) {
      bf16x8 k_frag = *(const bf16x8*)&K_lds[(s * 16 + ql) * 40 + g * 8];
      s_frag[s] = __builtin_amdgcn_mfma_f32_16x16x32_bf16(k_frag, q_frag, zf, 0, 0, 0);
    }
    float sv[16];
#pragma unroll
    for (int s = 0; s < 4; ++s)
#pragma unroll
      for (int r = 0; r < 4; ++r) sv[s * 4 + r] = s_frag[s][r];
    float tmax = sv[0];
#pragma unroll
    for (int i = 1; i < 16; ++i) tmax = fmaxf(tmax, sv[i]);
    tmax = fmaxf(tmax, __shfl_xor(tmax, 16));
    tmax = fmaxf(tmax, __shfl_xor(tmax, 32));
    float mn = fmaxf(m, tmax);
    float corr = exp2f(m - mn);
    float psum = 0.f;
    unsigned short pb[16];
#pragma unroll
    for (int i = 0; i < 16; ++i) {
      float p = exp2f(sv[i] - mn);
      psum += p;
      pb[i] = f2b(p);
    }
    psum += __shfl_xor(psum, 16);
    psum += __shfl_xor(psum, 32);
    l = l * corr + psum;
    m = mn;
#pragma unroll
    for (int mt = 0; mt < 2; ++mt)
#pragma unroll
      for (int r = 0; r < 4; ++r) o_acc[mt][r] *= corr;
#pragma unroll
    for (int s = 0; s < 4; ++s) {
      ushort4v p4 = {pb[s * 4], pb[s * 4 + 1], pb[s * 4 + 2], pb[s * 4 + 3]};
      *(ushort4v*)&P_lds[w][ql * 72 + s * 16 + g * 4] = p4;
    }
#pragma unroll
    for (int c = 0; c < 2; ++c) {
      bf16x8 p_frag = *(const bf16x8*)&P_lds[w][ql * 72 + c * 32 + g * 8];
#pragma unroll
      for (int mt = 0; mt < 2; ++mt) {
        bf16x8 v_frag = *(const bf16x8*)&Vt_lds[(mt * 16 + ql) * 72 + c * 32 + g * 8];
        o_acc[mt] = __builtin_amdgcn_mfma_f32_16x16x32_bf16(v_frag, p_frag, o_acc[mt], 0, 0, 0);
      }
    }
  }
  float inv = 1.f / l;
  float* op = O + ((long)(b * N_ + qt * 64 + w * 16 + ql)) * C_ + h * HD_;
#pragma unroll
  for (int mt = 0; mt < 2; ++mt) {
    float4 o4 = make_float4(o_acc[mt][0] * inv, o_acc[mt][1] * inv,
                            o_acc[mt][2] * inv, o_acc[mt][3] * inv);
    *(float4*)(op + mt * 16 + g * 4) = o4;
  }
}

// ---------- K17: LN(lgn) + exact GELU -> (B,C,N), tiled coalesced ----------
__global__ __launch_bounds__(256) void k_lngelu(const float* __restrict__ XO,
                                                const float* __restrict__ lw,
                                                const float* __restrict__ lb,
                                                float* __restrict__ XI) {
  __shared__ float tile[256][17];
  __shared__ float redp[16][16][2];
  __shared__ float stats[16][2];
  int bx = blockIdx.x;
  int b = bx >> 6, n0 = (bx & 63) * 16;
  int c = threadIdx.x;
#pragma unroll
  for (int j = 0; j < 16; ++j)
    tile[c][j] = XO[((long)(b * N_ + n0 + j)) * C_ + c];
  __syncthreads();
  {
    int n = c & 15, g = c >> 4;
    float a = 0.f, q = 0.f;
#pragma unroll
    for (int i = 0; i < 16; ++i) {
      float v = tile[g * 16 + i][n];
      a += v; q += v * v;
    }
    redp[g][n][0] = a; redp[g][n][1] = q;
  }
  __syncthreads();
  if (c < 16) {
    float a = 0.f, q = 0.f;
#pragma unroll
    for (int g2 = 0; g2 < 16; ++g2) { a += redp[g2][c][0]; q += redp[g2][c][1]; }
    float mu = a * (1.f / C_);
    float rs = rsqrtf(q * (1.f / C_) - mu * mu + 1e-5f);
    stats[c][0] = mu; stats[c][1] = rs;
  }
  __syncthreads();
  float wv = lw[c], bv = lb[c];
  float o[16];
#pragma unroll
  for (int j = 0; j < 16; ++j) {
    float x = (tile[c][j] - stats[j][0]) * stats[j][1] * wv + bv;
    o[j] = 0.5f * x * (1.f + erff(x * 0.70710678118654752f));
  }
  float* dst = &XI[((long)(b * C_ + c)) * N_ + n0];
#pragma unroll
  for (int j4 = 0; j4 < 4; ++j4)
    *(float4*)(dst + j4 * 4) = make_float4(o[4 * j4], o[4 * j4 + 1], o[4 * j4 + 2], o[4 * j4 + 3]);
}

// ---------- K18: ln over (H,W) per (b,c), in place, no affine ----------
__global__ __launch_bounds__(256) void k_lnhw(float* __restrict__ XI) {
  __shared__ float red[8];
  long base = (long)blockIdx.x * N_;
  float a = 0.f, b2 = 0.f;
  for (int i = threadIdx.x; i < N_; i += 256) {
    float v = XI[base + i];
    a += v; b2 += v * v;
  }
#pragma unroll
  for (int m = 1; m < 64; m <<= 1) {
    a += __shfl_xor(a, m, 64);
    b2 += __shfl_xor(b2, m, 64);
  }
  int w = threadIdx.x >> 6;
  if ((threadIdx.x & 63) == 0) { red[2 * w] = a; red[2 * w + 1] = b2; }
  __syncthreads();
  float sa = red[0] + red[2] + red[4] + red[6];
  float sq = red[1] + red[3] + red[5] + red[7];
  float mu = sa * (1.f / N_);
  float rs = rsqrtf(sq * (1.f / N_) - mu * mu + 1e-5f);
  for (int i = threadIdx.x; i < N_; i += 256) XI[base + i] = (XI[base + i] - mu) * rs;
}

// ---------- K19: depthwise 3x3 conv on (B,C,32,32), pad 1 ----------
__global__ __launch_bounds__(256) void k_dwc(const float* __restrict__ XI,
                                             const float* __restrict__ w,
                                             const float* __restrict__ bias,
                                             float* __restrict__ XD) {
  long i = (long)blockIdx.x * 256 + threadIdx.x;
  int hw = i & 1023;
  int wq = hw & 31, hq = hw >> 5;
  int c = (int)((i >> 10) & 255);
  const float* p = XI + (i - hw);
  const float* wk = w + c * 9;
  float a = bias[c];
#pragma unroll
  for (int kh = 0; kh < 3; ++kh) {
    int h2 = hq + kh - 1;
    if (h2 < 0 || h2 >= 32) continue;
#pragma unroll
    for (int kw = 0; kw < 3; ++kw) {
      int w2 = wq + kw - 1;
      if (w2 < 0 || w2 >= 32) continue;
      a += wk[kh * 3 + kw] * p[h2 * 32 + w2];
    }
  }
  XD[i] = a;
}

extern "C" void kernel_launch(void* const* d_in, const int* in_sizes, int n_in,
                              void* d_out, int out_size, void* d_ws, size_t ws_size,
                              hipStream_t stream) {
  const float* x        = (const float*)d_in[0];
  const float* norm_w   = (const float*)d_in[1];
  const float* norm_b   = (const float*)d_in[2];
  const float* skip     = (const float*)d_in[3];
  const float* m_inw    = (const float*)d_in[4];
  const float* m_convw  = (const float*)d_in[5];
  const float* m_convb  = (const float*)d_in[6];
  const float* m_xpw    = (const float*)d_in[7];
  const float* m_dtw    = (const float*)d_in[8];
  const float* m_dtb    = (const float*)d_in[9];
  const float* m_alog   = (const float*)d_in[10];
  const float* m_d      = (const float*)d_in[11];
  const float* m_outw   = (const float*)d_in[12];
  const float* qdw_w    = (const float*)d_in[13];
  const float* qdw_b    = (const float*)d_in[14];
  const float* qpw_w    = (const float*)d_in[15];
  const float* qpw_b    = (const float*)d_in[16];
  const float* rdw_w    = (const float*)d_in[17];
  const float* rdw_b    = (const float*)d_in[18];
  const float* rpw_w    = (const float*)d_in[19];
  const float* rpw_b    = (const float*)d_in[20];
  const float* fdw_w    = (const float*)d_in[21];
  const float* fdw_b    = (const float*)d_in[22];
  const float* fpw_w    = (const float*)d_in[23];
  const float* fpw_b    = (const float*)d_in[24];
  const float* lc_w     = (const float*)d_in[25];
  const float* lc_b     = (const float*)d_in[26];
  const float* attn_inw = (const float*)d_in[27];
  const float* attn_inb = (const float*)d_in[28];
  const float* attn_outw= (const float*)d_in[29];
  const float* attn_outb= (const float*)d_in[30];
  const float* lgn_w    = (const float*)d_in[31];
  const float* lgn_b    = (const float*)d_in[32];
  const float* fc_w     = (const float*)d_in[33];
  const float* fc_b     = (const float*)d_in[34];
  const float* dwc_w    = (const float*)d_in[35];
  const float* dwc_b    = (const float*)d_in[36];
  const float* proj_w   = (const float*)d_in[37];
  const float* proj_b   = (const float*)d_in[38];
  float* out = (float*)d_out;

  float* ws = (float*)d_ws;
  const size_t F = 1048576;  // B*N*C
  float* XS  = ws + 0 * F;
  float* XN  = ws + 1 * F;
  float* U   = ws + 2 * F;
  float* Z   = ws + 4 * F;
  float* UPRE= ws + 6 * F;
  float* DT  = ws + 6 * F;
  float* BM  = ws + 8 * F;
  float* CM  = ws + 8 * F + F / 4;
  float* XMC = ws + 8 * F + F / 2;
  float* SC_APROD = ws + 8 * F + F / 2;
  float* SC_HEND  = ws + 9 * F;
  float* G   = ws + 1 * F;
  float* XG  = ws + 2 * F;
  float* RB  = ws + 4 * F;
  float* XM2 = ws + 5 * F;
  float* QKV = ws + 1 * F;
  float* O   = ws + 4 * F;
  float* XGL = ws + 6 * F;
  float* XO  = ws + 7 * F;
  float* XI  = ws + 8 * F;
  float* XD  = ws + 5 * F;
  float* LNF = ws + 0 * F;
  (void)ws_size; (void)in_sizes; (void)n_in; (void)out_size;

  k_ln_t2<<<256, 256, 0, stream>>>(x, norm_w, norm_b, XN, XS);
  k_inproj_mfma<<<dim3(64, 16), 256, 0, stream>>>(XN, m_inw, UPRE, Z);
  k_causal<<<512, 256, 0, stream>>>(UPRE, U, m_convw, m_convb);
  k_xdbc<<<1024, 256, 0, stream>>>(U, m_xpw, m_dtw, m_dtb, DT, BM, CM);
  k_scanA<<<512, 256, 0, stream>>>(DT, U, BM, m_alog, SC_APROD, SC_HEND);
  k_scanB<<<128, 256, 0, stream>>>(SC_APROD, SC_HEND);
  k_scanC<<<512, 256, 0, stream>>>(DT, U, BM, CM, m_alog, m_d, SC_APROD);
  k_outproj_mfma<<<dim3(64, 4), 256, 0, stream>>>(DT, Z, m_outw, XN, skip, XMC);
  k_gate<<<256, 256, 0, stream>>>(XMC, qdw_w, qdw_b, qpw_w, qpw_b, G);
  k_xg<<<256, 256, 0, stream>>>(XMC, G, XG);
  // RB = rpw(rdw(XG)) + XG   (dw fused into staging)
  k_gemm_cm_dw<256><<<dim3(64, 4), 256, 0, stream>>>(XG, nullptr, rdw_w, rdw_b,
                                                     rpw_w, rpw_b, XG, nullptr, RB, nullptr);
  // XM2 = fpw(fdw([x ; RB])) + xs   (dw fused into staging)
  k_gemm_cm_dw<512><<<dim3(64, 4), 256, 0, stream>>>(x, RB, fdw_w, fdw_b,
                                                     fpw_w, fpw_b, nullptr, XS, nullptr, XM2);
  k_gemm_rm<256, false><<<dim3(64, 12), 256, 0, stream>>>(XM2, nullptr, attn_inw, attn_inb, QKV, 768, 256);
  k_attn_mfma<<<512, 256, 0, stream>>>(QKV, O);
  k_gemm_rm<256, false><<<dim3(64, 4), 256, 0, stream>>>(O, nullptr, attn_outw, attn_outb, XGL, 256, 256);
  // XO = fc([lc(XM2) ; XGL])   (lc row-conv fused into staging)
  k_gemm_fc<<<dim3(64, 4), 256, 0, stream>>>(XM2, XGL, lc_w, lc_b, fc_w, fc_b, XO);
  k_lngelu<<<256, 256, 0, stream>>>(XO, lgn_w, lgn_b, XI);
  k_lnhw<<<1024, 256, 0, stream>>>(XI);
  k_dwc<<<4096, 256, 0, stream>>>(XI, dwc_w, dwc_b, XD);
  k_ln_t2<<<256, 256, 0, stream>>>(XD, norm_w, norm_b, LNF, nullptr);
  k_gemm_rm<256, true><<<dim3(64, 4), 256, 0, stream>>>(LNF, nullptr, proj_w, proj_b, out, 256, 256);
}